// Round 12
// baseline (607.907 us; speedup 1.0000x reference)
//
#include <hip/hip_runtime.h>

#define N_NODES 100000
#define N_EDGES 1200000
#define NCLS 81   // 65 deg classes + 16 lab classes
#define NBKT 196  // dst>>9 buckets (512 nodes each)
#define NCHK 293  // ceil(N_EDGES/4096)

typedef unsigned short u16;
typedef unsigned char u8;
typedef unsigned int u32;
typedef unsigned long long u64;
typedef short bf16x8 __attribute__((ext_vector_type(8)));
typedef float f32x4 __attribute__((ext_vector_type(4)));

__device__ __forceinline__ float b2f(u16 u) {
  union { u32 i; float f; } v; v.i = ((u32)u) << 16; return v.f;
}
__device__ __forceinline__ u16 f2b(float f) {
  union { float f; u32 i; } v; v.f = f;
  u32 x = v.i;
  return (u16)((x + 0x7fffu + ((x >> 16) & 1u)) >> 16);
}
__device__ __forceinline__ u32 pk2(float lo, float hi) {
  return (u32)f2b(lo) | ((u32)f2b(hi) << 16);
}
__device__ __forceinline__ void up2(u32 w, float& lo, float& hi) {
  union { u32 u; float f; } a, b;
  a.u = w << 16; b.u = w & 0xffff0000u;
  lo = a.f; hi = b.f;
}
__device__ __forceinline__ float lrelu(float x) { return x > 0.f ? x : 0.01f * x; }

// ---- fp32 param block offsets ----
#define P_EMBD 0       // 4160
#define P_EMBL 4160    // 1024
#define P_W1A  5184    // 16384  l0_w1 (128x128)
#define P_B1A  21568   // 128
#define P_W2A  21696   // 8192   l0_w2 (128x64)
#define P_B2A  29888   // 64
#define P_EPS0 29952   // 1
#define P_G0   29953   // 64
#define P_BB0  30017   // 64
#define P_LW1  30081   // 4096   l1_w1 (64x64)
#define P_LB1  34177   // 64
#define P_LW2  34241   // 4096   l1_w2 (64x64)
#define P_LB2  38337   // 64
#define P_EPS1 38401   // 1
#define P_G1   38402   // 64
#define P_BB1  38466   // 64
#define P_FW1  38530   // 16384  fc_w1 (256x64)
#define P_FB1  54914   // 64
#define P_FG   54978   // 64
#define P_FBB  55042   // 64
#define P_FW2  55106   // 64
#define P_FB2  55170   // 1
#define P_TOT  55171

// ---------------- dtype detection ----------------
__global__ void k_detect(const u16* __restrict__ e, u32* __restrict__ flag) {
  u32 t = 0;
  for (int k = threadIdx.x; k < 4096; k += 256) {
    u32 ex = (e[k] >> 7) & 0xFF;
    if (ex >= 0x90) t = 1;
  }
  if (t) atomicOr(flag, 1u);
}

// ---------------- convert all float params to fp32 block ----------------
struct CvtAll {
  const void* src[22];
  int cnt[22];
  int off[22];
};

__global__ void k_cvtall(CvtAll a, const u32* __restrict__ flag, float* __restrict__ P) {
  int seg = blockIdx.y;
  int i = blockIdx.x * 256 + threadIdx.x;
  if (i >= a.cnt[seg]) return;
  float v;
  if (*flag) v = ((const float*)a.src[seg])[i];
  else       v = b2f(((const u16*)a.src[seg])[i]);
  P[a.off[seg] + i] = v;
}

// ---------------- merged preprocessing: W1p, Efc, MFMA B-pack ----------------
__global__ void k_prep(const float* __restrict__ P, float* __restrict__ W1p,
                       float* __restrict__ Efc, u16* __restrict__ bp) {
  int idx = blockIdx.x * 256 + threadIdx.x;
  if (idx < NCLS * 128) {
    int c = idx >> 7, h = idx & 127;
    const float* w1 = P + P_W1A;
    float s = 0.f;
    if (c < 65) {
      const float* em = P + P_EMBD + c * 64;
      for (int k = 0; k < 64; ++k) s = fmaf(em[k], w1[k * 128 + h], s);
    } else {
      const float* em = P + P_EMBL + (c - 65) * 64;
      for (int k = 0; k < 64; ++k) s = fmaf(em[k], w1[(64 + k) * 128 + h], s);
    }
    W1p[idx] = s;
    return;
  }
  if (idx < NCLS * 128 + NCLS * 64) {
    int r = idx - NCLS * 128;
    int c = r >> 6, o = r & 63;
    const float* fw = P + P_FW1;
    float s = 0.f;
    if (c < 65) {
      const float* em = P + P_EMBD + c * 64;
      for (int k = 0; k < 64; ++k) s = fmaf(em[k], fw[k * 64 + o], s);
    } else {
      const float* em = P + P_EMBL + (c - 65) * 64;
      for (int k = 0; k < 64; ++k) s = fmaf(em[k], fw[(64 + k) * 64 + o], s);
    }
    Efc[r] = s;
    return;
  }
  int pidx = idx - (NCLS * 128 + NCLS * 64);
  if (pidx >= 24576) return;
  int seg, rel;
  if (pidx < 8192)       { seg = 0; rel = pidx; }
  else if (pidx < 12288) { seg = 1; rel = pidx - 8192; }
  else if (pidx < 16384) { seg = 2; rel = pidx - 12288; }
  else                   { seg = 3; rel = pidx - 16384; }
  const int srcoff[4] = {P_W2A, P_LW1, P_LW2, P_FW1 + 128 * 64};
  const int KBs[4] = {4, 2, 2, 4};
  int j = rel & 7, lane = (rel >> 3) & 63, rest = rel >> 9;
  int kb = rest % KBs[seg], nt = rest / KBs[seg];
  int k = kb * 32 + (lane >> 4) * 8 + j;
  int n = nt * 16 + (lane & 15);
  bp[pidx] = f2b(P[srcoff[seg] + k * 64 + n]);
}

// ---------------- pack W1p into K=96 MFMA B-frag table (zero-pad rows 81..95) -------
__global__ void k_prep2(const float* __restrict__ W1p, u16* __restrict__ wpB) {
  int idx = blockIdx.x * 256 + threadIdx.x;
  if (idx >= 12288) return;
  int j = idx & 7, lane = (idx >> 3) & 63, rest = idx >> 9;
  int kb = rest % 3, nt = rest / 3;
  int c = kb * 32 + (lane >> 4) * 8 + j;
  int n = nt * 16 + (lane & 15);
  wpB[idx] = (c < NCLS) ? f2b(W1p[c * 128 + n]) : 0;
}

// ---------------- bucket counting-sort of edges by dst>>9 ----------------
__global__ __launch_bounds__(256) void k_bc(const int* __restrict__ edge, u32* __restrict__ tcnt) {
  __shared__ u32 c[NBKT];
  for (int i = threadIdx.x; i < NBKT; i += 256) c[i] = 0;
  __syncthreads();
  int base = blockIdx.x * 4096;
  for (int i = threadIdx.x; i < 4096; i += 256) {
    int e = base + i;
    if (e < N_EDGES) atomicAdd(&c[(u32)edge[N_EDGES + e] >> 9], 1u);
  }
  __syncthreads();
  for (int i = threadIdx.x; i < NBKT; i += 256)
    if (c[i]) atomicAdd(&tcnt[i], c[i]);
}

__global__ void k_bscan(const u32* __restrict__ tcnt, u32* __restrict__ gcur) {
  __shared__ u32 l[256];
  int tid = threadIdx.x;
  u32 v = (tid < NBKT) ? tcnt[tid] : 0u;
  l[tid] = v;
  __syncthreads();
  for (int off = 1; off < 256; off <<= 1) {
    u32 a = (tid >= off) ? l[tid - off] : 0u;
    __syncthreads();
    l[tid] += a;
    __syncthreads();
  }
  if (tid < NBKT) gcur[tid] = l[tid] - v;
}

__global__ __launch_bounds__(256) void k_bsort(const int* __restrict__ edge,
                                               const int* __restrict__ ndeg,
                                               const int* __restrict__ nlab,
                                               u32* __restrict__ gcur,
                                               u64* __restrict__ e2) {
  __shared__ u32 cnt[NBKT], rbase[NBKT];
  __shared__ u32 slo[4096], shi[4096];
  for (int i = threadIdx.x; i < NBKT; i += 256) cnt[i] = 0;
  __syncthreads();
  int base = blockIdx.x * 4096;
  for (int i = threadIdx.x; i < 4096; i += 256) {
    int e = base + i;
    if (e < N_EDGES) {
      int s = edge[e], d = edge[N_EDGES + e];
      slo[i] = ((u32)s << 11) | ((u32)ndeg[s] << 4) | (u32)nlab[s];
      shi[i] = (u32)d;
      atomicAdd(&cnt[(u32)d >> 9], 1u);
    } else shi[i] = 0xFFFFFFFFu;
  }
  __syncthreads();
  for (int i = threadIdx.x; i < NBKT; i += 256) {
    u32 c = cnt[i];
    rbase[i] = c ? atomicAdd(&gcur[i], c) : 0u;
    cnt[i] = 0;
  }
  __syncthreads();
  for (int i = threadIdx.x; i < 4096; i += 256) {
    u32 d = shi[i];
    if (d == 0xFFFFFFFFu) continue;
    u32 b = d >> 9;
    u32 pos = rbase[b] + atomicAdd(&cnt[b], 1u);
    e2[pos] = ((u64)d << 32) | (u64)slo[i];
  }
}

// ---------------- in-degree over dst-sorted edges ----------------
__global__ void k_deg2(const u64* __restrict__ e2, u32* __restrict__ deg) {
  int e = blockIdx.x * 256 + threadIdx.x;
  if (e >= N_EDGES) return;
  atomicAdd(&deg[(u32)(e2[e] >> 32)], 1u);
}

// ---------------- CSR scan ----------------
__global__ void k_scan1(const u32* __restrict__ deg, u32* __restrict__ row_ptr,
                        u32* __restrict__ bsum) {
  __shared__ u32 l[256];
  int tid = threadIdx.x;
  int i = blockIdx.x * 256 + tid;
  u32 v = (i < N_NODES) ? deg[i] : 0u;
  l[tid] = v;
  __syncthreads();
  for (int off = 1; off < 256; off <<= 1) {
    u32 a = (tid >= off) ? l[tid - off] : 0u;
    __syncthreads();
    l[tid] += a;
    __syncthreads();
  }
  if (i < N_NODES) row_ptr[i] = l[tid] - v;
  if (tid == 255) bsum[blockIdx.x] = l[255];
}

#define NBLK_SCAN 391

__global__ void k_scan2(u32* __restrict__ bsum) {
  __shared__ u32 l[512];
  int tid = threadIdx.x;
  u32 v = (tid < NBLK_SCAN) ? bsum[tid] : 0u;
  l[tid] = v;
  __syncthreads();
  for (int off = 1; off < 512; off <<= 1) {
    u32 a = (tid >= off) ? l[tid - off] : 0u;
    __syncthreads();
    l[tid] += a;
    __syncthreads();
  }
  if (tid < NBLK_SCAN) bsum[tid] = l[tid] - v;
}

// ---------------- CSR fill from sorted edges ----------------
__global__ void k_fill2(const u64* __restrict__ e2, u32* __restrict__ rp,
                        const u32* __restrict__ bsum, u32* __restrict__ einfo) {
  int e = blockIdx.x * 256 + threadIdx.x;
  if (e >= N_EDGES) return;
  u64 r = e2[e];
  u32 d = (u32)(r >> 32);
  u32 pos = atomicAdd(&rp[d], 1u) + bsum[d >> 8];
  einfo[pos] = (u32)r;
}

__device__ __forceinline__ u32 row_start(const u32* rp, const u32* bsum, int n) {
  return (n == 0) ? 0u : rp[n - 1] + bsum[(n - 1) >> 8];
}
__device__ __forceinline__ u32 row_end(const u32* rp, const u32* bsum, int n) {
  return rp[n] + bsum[n >> 8];
}

// ---------------- layer-0 class histogram: thread-per-node, private LDS ----------
__global__ __launch_bounds__(256) void k_hist(const u32* __restrict__ rp,
                                              const u32* __restrict__ bsum,
                                              const u32* __restrict__ einfo,
                                              u16* __restrict__ counts) {
  __shared__ u8 h[256 * 96];
  int tid = threadIdx.x;
  u32* hw = (u32*)h;
#pragma unroll
  for (int i = 0; i < 24; ++i) hw[tid * 24 + i] = 0;
  __syncthreads();
  int n = blockIdx.x * 256 + tid;
  if (n < N_NODES) {
    u32 st = row_start(rp, bsum, n), en = row_end(rp, bsum, n);
    u8* my = h + tid * 96;
    for (u32 e = st; e < en; ++e) {
      u32 q = einfo[e];
      ++my[(q >> 4) & 0x7Fu];
      ++my[65u + (q & 15u)];
    }
  }
  __syncthreads();
  int b0 = blockIdx.x * 256;
  for (int idx = tid; idx < 256 * 96; idx += 256) {
    int nl = idx / 96;
    if (b0 + nl < N_NODES) counts[(size_t)(b0 + nl) * 96 + (idx - nl * 96)] = f2b((float)h[idx]);
  }
}

// ---------------- layer-0 MFMA GEMM: hmid = lrelu(counts@W1p + b1 + onep*self) -----
__global__ __launch_bounds__(256) void k_gemm0h(const u16* __restrict__ counts,
                                                const u16* __restrict__ wpB,
                                                const float* __restrict__ W1p,
                                                const float* __restrict__ P,
                                                const int* __restrict__ ndeg,
                                                const int* __restrict__ nlab,
                                                u16* __restrict__ hmid) {
  int wid = threadIdx.x >> 6, lane = threadIdx.x & 63;
  int m0 = (blockIdx.x * 4 + wid) * 16;
  if (m0 >= N_NODES) return;
  int row = lane & 15, q = lane >> 4;
  float onep = 1.f + P[P_EPS0];
  const u16* ap = counts + (size_t)(m0 + row) * 96 + q * 8;
  const bf16x8* bp = (const bf16x8*)wpB;
  f32x4 acc[8];
#pragma unroll
  for (int nt = 0; nt < 8; ++nt) {
    float b = P[P_B1A + nt * 16 + row];
    acc[nt][0] = b; acc[nt][1] = b; acc[nt][2] = b; acc[nt][3] = b;
  }
#pragma unroll
  for (int kb = 0; kb < 3; ++kb) {
    bf16x8 af = *(const bf16x8*)(ap + kb * 32);
#pragma unroll
    for (int nt = 0; nt < 8; ++nt) {
      bf16x8 bf = bp[(nt * 3 + kb) * 64 + lane];
      acc[nt] = __builtin_amdgcn_mfma_f32_16x16x32_bf16(af, bf, acc[nt], 0, 0, 0);
    }
  }
#pragma unroll
  for (int r = 0; r < 4; ++r) {
    int m = m0 + q * 4 + r;
    const float* wd = W1p + ndeg[m] * 128;
    const float* wl = W1p + (65 + nlab[m]) * 128;
#pragma unroll
    for (int nt = 0; nt < 8; ++nt) {
      int cc = nt * 16 + row;
      float v = acc[nt][r] + onep * (wd[cc] + wl[cc]);
      hmid[(size_t)m * 128 + cc] = f2b(lrelu(v));
    }
  }
}

// ---------------- MFMA GEMM (plain A) + fused BN-stats reduction ----------------
template <int KB, int LDA, int BIASOFF>
__global__ __launch_bounds__(256) void k_gemm(const u16* __restrict__ A,
                                              const u16* __restrict__ Bp,
                                              const float* __restrict__ P,
                                              float* __restrict__ statsOut,
                                              u16* __restrict__ C) {
  __shared__ float lsum[4][64], lsq[4][64];
  int wid = threadIdx.x >> 6, lane = threadIdx.x & 63;
  int m0 = (blockIdx.x * 4 + wid) * 16;
  bool act = m0 < N_NODES;
  int row = lane & 15, q = lane >> 4;
  float ss[4] = {0.f, 0.f, 0.f, 0.f}, qq[4] = {0.f, 0.f, 0.f, 0.f};
  if (act) {
    const u16* ap = A + (size_t)(m0 + row) * LDA + q * 8;
    const bf16x8* bp = (const bf16x8*)Bp;
    f32x4 acc[4];
#pragma unroll
    for (int nt = 0; nt < 4; ++nt) {
      float b = (BIASOFF >= 0) ? P[BIASOFF + nt * 16 + row] : 0.f;
      acc[nt][0] = b; acc[nt][1] = b; acc[nt][2] = b; acc[nt][3] = b;
    }
#pragma unroll
    for (int kb = 0; kb < KB; ++kb) {
      bf16x8 af = *(const bf16x8*)(ap + kb * 32);
#pragma unroll
      for (int nt = 0; nt < 4; ++nt) {
        bf16x8 bf = bp[(nt * KB + kb) * 64 + lane];
        acc[nt] = __builtin_amdgcn_mfma_f32_16x16x32_bf16(af, bf, acc[nt], 0, 0, 0);
      }
    }
#pragma unroll
    for (int nt = 0; nt < 4; ++nt) {
      float s = 0.f, z = 0.f;
#pragma unroll
      for (int r = 0; r < 4; ++r) {
        int m = m0 + q * 4 + r;
        u16 bv = f2b(acc[nt][r]);
        C[(size_t)m * 64 + nt * 16 + row] = bv;
        float v = b2f(bv);
        s += v; z = fmaf(v, v, z);
      }
      s += __shfl_xor(s, 16, 64); s += __shfl_xor(s, 32, 64);
      z += __shfl_xor(z, 16, 64); z += __shfl_xor(z, 32, 64);
      ss[nt] = s; qq[nt] = z;
    }
  }
  if (lane < 16) {
#pragma unroll
    for (int nt = 0; nt < 4; ++nt) {
      lsum[wid][nt * 16 + lane] = ss[nt];
      lsq[wid][nt * 16 + lane] = qq[nt];
    }
  }
  __syncthreads();
  int tid = threadIdx.x;
  if (tid < 64) atomicAdd(&statsOut[tid], lsum[0][tid] + lsum[1][tid] + lsum[2][tid] + lsum[3][tid]);
  else if (tid < 128) {
    int c = tid - 64;
    atomicAdd(&statsOut[64 + c], lsq[0][c] + lsq[1][c] + lsq[2][c] + lsq[3][c]);
  }
}

// ---------------- MFMA GEMM with fused BN+lrelu on A (K=64) -> blocked g1 ----------
__global__ __launch_bounds__(256) void k_gemm_bn(const u16* __restrict__ A,
                                                 const u16* __restrict__ Bp,
                                                 const float* __restrict__ P,
                                                 const float* __restrict__ stats,
                                                 u16* __restrict__ g1b) {
  int wid = threadIdx.x >> 6, lane = threadIdx.x & 63;
  int m0 = (blockIdx.x * 4 + wid) * 16;
  if (m0 >= N_NODES) return;
  int row = lane & 15, q = lane >> 4;
  const float invN = 1.f / (float)N_NODES;
  float sc[16], sh[16];
#pragma unroll
  for (int kb = 0; kb < 2; ++kb)
#pragma unroll
    for (int j = 0; j < 8; ++j) {
      int f = kb * 32 + q * 8 + j;
      float mm = stats[f] * invN;
      float var = fmaxf(stats[64 + f] * invN - mm * mm, 0.f);
      float inv = rsqrtf(var + 1e-5f);
      float s = inv * P[P_G0 + f];
      sc[kb * 8 + j] = s;
      sh[kb * 8 + j] = P[P_BB0 + f] - mm * s;
    }
  const u16* ap = A + (size_t)(m0 + row) * 64 + q * 8;
  const bf16x8* bp = (const bf16x8*)Bp;
  f32x4 acc[4];
#pragma unroll
  for (int nt = 0; nt < 4; ++nt) {
    acc[nt][0] = 0.f; acc[nt][1] = 0.f; acc[nt][2] = 0.f; acc[nt][3] = 0.f;
  }
#pragma unroll
  for (int kb = 0; kb < 2; ++kb) {
    uint4 raw = *(const uint4*)(ap + kb * 32);
    u32 rw[4] = {raw.x, raw.y, raw.z, raw.w};
    bf16x8 af;
#pragma unroll
    for (int p = 0; p < 4; ++p) {
      float lo, hi;
      up2(rw[p], lo, hi);
      float y0 = lrelu(fmaf(sc[kb * 8 + 2 * p], lo, sh[kb * 8 + 2 * p]));
      float y1 = lrelu(fmaf(sc[kb * 8 + 2 * p + 1], hi, sh[kb * 8 + 2 * p + 1]));
      af[2 * p] = (short)f2b(y0);
      af[2 * p + 1] = (short)f2b(y1);
    }
#pragma unroll
    for (int nt = 0; nt < 4; ++nt) {
      bf16x8 bf = bp[(nt * 2 + kb) * 64 + lane];
      acc[nt] = __builtin_amdgcn_mfma_f32_16x16x32_bf16(af, bf, acc[nt], 0, 0, 0);
    }
  }
  // blocked write: pass = nt>>1, col32 = (nt&1)*16 + row
#pragma unroll
  for (int nt = 0; nt < 4; ++nt) {
    u16* base = g1b + (size_t)(nt >> 1) * N_NODES * 32;
    int c32 = (nt & 1) * 16 + row;
#pragma unroll
    for (int r = 0; r < 4; ++r) {
      int m = m0 + q * 4 + r;
      base[(size_t)m * 32 + c32] = f2b(acc[nt][r]);
    }
  }
}

// ---------------- layer-1 aggregation: 2-pass feature-blocked (64-B rows) ----------
#define AGG1B_NB 25000
__global__ __launch_bounds__(256) void k_agg1b(const u32* __restrict__ rp,
                                               const u32* __restrict__ bsum,
                                               const u32* __restrict__ einfo,
                                               const u16* __restrict__ g1b,
                                               const float* __restrict__ P,
                                               u16* __restrict__ abuf) {
  int pass = blockIdx.x / AGG1B_NB;
  int nb = blockIdx.x - pass * AGG1B_NB;
  int wv = threadIdx.x >> 6, lane = threadIdx.x & 63;
  int f = lane & 31, es = lane >> 5;
  int n = nb * 4 + wv;  // < 100000 always (25000*4)
  u32 st = row_start(rp, bsum, n), en = row_end(rp, bsum, n);
  u32 m = en - st;
  const u16* gp = g1b + (size_t)pass * N_NODES * 32;
  float aA = 0.f, aB = 0.f, aC = 0.f, aD = 0.f;
  u32 k = 0;
  for (; k + 16 <= m; k += 16) {
    u32 s0 = einfo[st + k + es] >> 11;
    u32 s1 = einfo[st + k + 2 + es] >> 11;
    u32 s2 = einfo[st + k + 4 + es] >> 11;
    u32 s3 = einfo[st + k + 6 + es] >> 11;
    u32 s4 = einfo[st + k + 8 + es] >> 11;
    u32 s5 = einfo[st + k + 10 + es] >> 11;
    u32 s6 = einfo[st + k + 12 + es] >> 11;
    u32 s7 = einfo[st + k + 14 + es] >> 11;
    float v0 = b2f(gp[(size_t)s0 * 32 + f]);
    float v1 = b2f(gp[(size_t)s1 * 32 + f]);
    float v2 = b2f(gp[(size_t)s2 * 32 + f]);
    float v3 = b2f(gp[(size_t)s3 * 32 + f]);
    float v4 = b2f(gp[(size_t)s4 * 32 + f]);
    float v5 = b2f(gp[(size_t)s5 * 32 + f]);
    float v6 = b2f(gp[(size_t)s6 * 32 + f]);
    float v7 = b2f(gp[(size_t)s7 * 32 + f]);
    aA += v0 + v1; aB += v2 + v3; aC += v4 + v5; aD += v6 + v7;
  }
  if (k + 8 <= m) {
    u32 s0 = einfo[st + k + es] >> 11;
    u32 s1 = einfo[st + k + 2 + es] >> 11;
    u32 s2 = einfo[st + k + 4 + es] >> 11;
    u32 s3 = einfo[st + k + 6 + es] >> 11;
    aA += b2f(gp[(size_t)s0 * 32 + f]);
    aB += b2f(gp[(size_t)s1 * 32 + f]);
    aC += b2f(gp[(size_t)s2 * 32 + f]);
    aD += b2f(gp[(size_t)s3 * 32 + f]);
    k += 8;
  }
  if (k + 4 <= m) {
    u32 s0 = einfo[st + k + es] >> 11;
    u32 s1 = einfo[st + k + 2 + es] >> 11;
    aA += b2f(gp[(size_t)s0 * 32 + f]);
    aB += b2f(gp[(size_t)s1 * 32 + f]);
    k += 4;
  }
  if (k + 2 <= m) {
    u32 s0 = einfo[st + k + es] >> 11;
    aC += b2f(gp[(size_t)s0 * 32 + f]);
    k += 2;
  }
  if (k < m && es == 0) {
    u32 s0 = einfo[st + k] >> 11;
    aD += b2f(gp[(size_t)s0 * 32 + f]);
  }
  float acc = (aA + aB) + (aC + aD);
  acc += __shfl_xor(acc, 32, 64);
  if (es == 0) {
    float onep = 1.f + P[P_EPS1];
    float self = b2f(gp[(size_t)n * 32 + f]);
    float a = P[P_LB1 + pass * 32 + f] + fmaf(onep, self, acc);
    abuf[(size_t)pass * N_NODES * 32 + (size_t)n * 32 + f] = f2b(lrelu(a));
  }
}

// ---------------- GEMM from blocked-A abuf (K=64) + fused stats -> t1 --------------
__global__ __launch_bounds__(256) void k_gemm_blkA(const u16* __restrict__ A,
                                                   const u16* __restrict__ Bp,
                                                   const float* __restrict__ P,
                                                   float* __restrict__ statsOut,
                                                   u16* __restrict__ C) {
  __shared__ float lsum[4][64], lsq[4][64];
  int wid = threadIdx.x >> 6, lane = threadIdx.x & 63;
  int m0 = (blockIdx.x * 4 + wid) * 16;
  bool act = m0 < N_NODES;
  int row = lane & 15, q = lane >> 4;
  float ss[4] = {0.f, 0.f, 0.f, 0.f}, qq[4] = {0.f, 0.f, 0.f, 0.f};
  if (act) {
    const bf16x8* bp = (const bf16x8*)Bp;
    f32x4 acc[4];
#pragma unroll
    for (int nt = 0; nt < 4; ++nt) {
      float b = P[P_LB2 + nt * 16 + row];
      acc[nt][0] = b; acc[nt][1] = b; acc[nt][2] = b; acc[nt][3] = b;
    }
#pragma unroll
    for (int kb = 0; kb < 2; ++kb) {
      const u16* ap = A + (size_t)kb * N_NODES * 32 + (size_t)(m0 + row) * 32 + q * 8;
      bf16x8 af = *(const bf16x8*)ap;
#pragma unroll
      for (int nt = 0; nt < 4; ++nt) {
        bf16x8 bf = bp[(nt * 2 + kb) * 64 + lane];
        acc[nt] = __builtin_amdgcn_mfma_f32_16x16x32_bf16(af, bf, acc[nt], 0, 0, 0);
      }
    }
#pragma unroll
    for (int nt = 0; nt < 4; ++nt) {
      float s = 0.f, z = 0.f;
#pragma unroll
      for (int r = 0; r < 4; ++r) {
        int m = m0 + q * 4 + r;
        u16 bv = f2b(acc[nt][r]);
        C[(size_t)m * 64 + nt * 16 + row] = bv;
        float v = b2f(bv);
        s += v; z = fmaf(v, v, z);
      }
      s += __shfl_xor(s, 16, 64); s += __shfl_xor(s, 32, 64);
      z += __shfl_xor(z, 16, 64); z += __shfl_xor(z, 32, 64);
      ss[nt] = s; qq[nt] = z;
    }
  }
  if (lane < 16) {
#pragma unroll
    for (int nt = 0; nt < 4; ++nt) {
      lsum[wid][nt * 16 + lane] = ss[nt];
      lsq[wid][nt * 16 + lane] = qq[nt];
    }
  }
  __syncthreads();
  int tid = threadIdx.x;
  if (tid < 64) atomicAdd(&statsOut[tid], lsum[0][tid] + lsum[1][tid] + lsum[2][tid] + lsum[3][tid]);
  else if (tid < 128) {
    int c = tid - 64;
    atomicAdd(&statsOut[64 + c], lsq[0][c] + lsq[1][c] + lsq[2][c] + lsq[3][c]);
  }
}

// ---------------- fc1 GEMM: A = [BN0(t0) | BN1(t1)] fused, + Efc epilogue + stats ---
__global__ __launch_bounds__(256) void k_gemm_fc1bn(const u16* __restrict__ t0,
                                                    const u16* __restrict__ t1,
                                                    const u16* __restrict__ Bp,
                                                    const float* __restrict__ P,
                                                    const float* __restrict__ stats,
                                                    float* __restrict__ statsOut,
                                                    const int* __restrict__ ndeg,
                                                    const int* __restrict__ nlab,
                                                    const float* __restrict__ Efc,
                                                    u16* __restrict__ C) {
  __shared__ float lsum[4][64], lsq[4][64];
  int wid = threadIdx.x >> 6, lane = threadIdx.x & 63;
  int m0 = (blockIdx.x * 4 + wid) * 16;
  bool act = m0 < N_NODES;
  int row = lane & 15, q = lane >> 4;
  float ss[4] = {0.f, 0.f, 0.f, 0.f}, qq[4] = {0.f, 0.f, 0.f, 0.f};
  if (act) {
    const float invN = 1.f / (float)N_NODES;
    float sc[32], sh[32];
#pragma unroll
    for (int h = 0; h < 2; ++h) {
      const float* st = stats + h * 128;
      int gof = h ? P_G1 : P_G0, bof = h ? P_BB1 : P_BB0;
#pragma unroll
      for (int kb = 0; kb < 2; ++kb)
#pragma unroll
        for (int j = 0; j < 8; ++j) {
          int f = kb * 32 + q * 8 + j;
          float mm = st[f] * invN;
          float var = fmaxf(st[64 + f] * invN - mm * mm, 0.f);
          float inv = rsqrtf(var + 1e-5f);
          float s = inv * P[gof + f];
          sc[h * 16 + kb * 8 + j] = s;
          sh[h * 16 + kb * 8 + j] = P[bof + f] - mm * s;
        }
    }
    const u16* a0 = t0 + (size_t)(m0 + row) * 64 + q * 8;
    const u16* a1 = t1 + (size_t)(m0 + row) * 64 + q * 8;
    const bf16x8* bp = (const bf16x8*)Bp;
    f32x4 acc[4];
#pragma unroll
    for (int nt = 0; nt < 4; ++nt) {
      float b = P[P_FB1 + nt * 16 + row];
      acc[nt][0] = b; acc[nt][1] = b; acc[nt][2] = b; acc[nt][3] = b;
    }
#pragma unroll
    for (int kb = 0; kb < 4; ++kb) {
      const u16* src = (kb < 2) ? (a0 + kb * 32) : (a1 + (kb - 2) * 32);
      int ci = (kb < 2) ? kb * 8 : 16 + (kb - 2) * 8;
      uint4 raw = *(const uint4*)src;
      u32 rw[4] = {raw.x, raw.y, raw.z, raw.w};
      bf16x8 af;
#pragma unroll
      for (int p = 0; p < 4; ++p) {
        float lo, hi;
        up2(rw[p], lo, hi);
        float y0 = lrelu(fmaf(sc[ci + 2 * p], lo, sh[ci + 2 * p]));
        float y1 = lrelu(fmaf(sc[ci + 2 * p + 1], hi, sh[ci + 2 * p + 1]));
        af[2 * p] = (short)f2b(y0);
        af[2 * p + 1] = (short)f2b(y1);
      }
#pragma unroll
      for (int nt = 0; nt < 4; ++nt) {
        bf16x8 bf = bp[(nt * 4 + kb) * 64 + lane];
        acc[nt] = __builtin_amdgcn_mfma_f32_16x16x32_bf16(af, bf, acc[nt], 0, 0, 0);
      }
    }
    float es[4][4];
#pragma unroll
    for (int r = 0; r < 4; ++r) {
      int m = m0 + q * 4 + r;
      int dn = ndeg[m], ln = 65 + nlab[m];
#pragma unroll
      for (int nt = 0; nt < 4; ++nt) {
        int cc = nt * 16 + row;
        es[r][nt] = acc[nt][r] + Efc[dn * 64 + cc] + Efc[ln * 64 + cc];
      }
    }
#pragma unroll
    for (int nt = 0; nt < 4; ++nt) {
      float s = 0.f, z = 0.f;
#pragma unroll
      for (int r = 0; r < 4; ++r) {
        int m = m0 + q * 4 + r;
        u16 bv = f2b(es[r][nt]);
        C[(size_t)m * 64 + nt * 16 + row] = bv;
        float v = b2f(bv);
        s += v; z = fmaf(v, v, z);
      }
      s += __shfl_xor(s, 16, 64); s += __shfl_xor(s, 32, 64);
      z += __shfl_xor(z, 16, 64); z += __shfl_xor(z, 32, 64);
      ss[nt] = s; qq[nt] = z;
    }
  }
  if (lane < 16) {
#pragma unroll
    for (int nt = 0; nt < 4; ++nt) {
      lsum[wid][nt * 16 + lane] = ss[nt];
      lsq[wid][nt * 16 + lane] = qq[nt];
    }
  }
  __syncthreads();
  int tid = threadIdx.x;
  if (tid < 64) atomicAdd(&statsOut[tid], lsum[0][tid] + lsum[1][tid] + lsum[2][tid] + lsum[3][tid]);
  else if (tid < 128) {
    int c = tid - 64;
    atomicAdd(&statsOut[64 + c], lsq[0][c] + lsq[1][c] + lsq[2][c] + lsq[3][c]);
  }
}

// ---------------- FC final: BN + lrelu + dot + sigmoid ----------------
__global__ void k_fc2(const u16* __restrict__ t, const float* __restrict__ stats,
                      const float* __restrict__ P, const u32* __restrict__ flag,
                      void* __restrict__ out) {
  int n = blockIdx.x * blockDim.x + threadIdx.x;
  if (n >= N_NODES) return;
  float z = P[P_FB2];
  const float invN = 1.f / (float)N_NODES;
  const u16* tn = t + (size_t)n * 64;
#pragma unroll 1
  for (int f = 0; f < 64; ++f) {
    float m = stats[f] * invN;
    float var = fmaxf(stats[64 + f] * invN - m * m, 0.f);
    float inv = rsqrtf(var + 1e-5f);
    float y = (b2f(tn[f]) - m) * inv * P[P_FG + f] + P[P_FBB + f];
    y = lrelu(y);
    z = fmaf(y, P[P_FW2 + f], z);
  }
  float s = 1.f / (1.f + expf(-z));
  if (!(fabsf(z) < 1e30f)) s = 0.25f;
  if (*flag) ((float*)out)[n] = s;
  else       ((u16*)out)[n] = f2b(s);
}

extern "C" void kernel_launch(void* const* d_in, const int* in_sizes, int n_in,
                              void* d_out, int out_size, void* d_ws, size_t ws_size,
                              hipStream_t stream) {
  const int* node_deg = (const int*)d_in[0];
  const int* node_lab = (const int*)d_in[1];
  const int* edge     = (const int*)d_in[2];
  (void)in_sizes; (void)n_in; (void)out_size; (void)ws_size;

  char* base = (char*)d_ws;
  size_t off = 0;
  auto alloc = [&](size_t bytes) -> void* {
    void* p = base + off;
    off += (bytes + 15) & ~(size_t)15;
    return p;
  };
  float* Pb    = (float*)alloc((size_t)P_TOT * 4);
  // contiguous zero region: flag | stats | deg | tcnt (one memset)
  u32* flag    = (u32*)alloc(16);
  float* stats = (float*)alloc(384 * 4);
  u32* deg     = (u32*)alloc((size_t)N_NODES * 4);
  u32* tcnt    = (u32*)alloc(NBKT * 4);
  float* W1p   = (float*)alloc(NCLS * 128 * 4);
  float* Efc   = (float*)alloc(NCLS * 64 * 4);
  u16* bpack   = (u16*)alloc(24576 * 2);
  u16* wpB     = (u16*)alloc(12288 * 2);
  u32* row_ptr = (u32*)alloc((size_t)(N_NODES + 1) * 4);
  u32* bsum    = (u32*)alloc(512 * 4);
  u32* gcur    = (u32*)alloc(NBKT * 4);
  u32* einfo   = (u32*)alloc((size_t)N_EDGES * 4);
  u64* e2      = (u64*)alloc((size_t)N_EDGES * 8);
  void* arena  = alloc((size_t)N_NODES * 128 * 2);  // hmid; later g1b+abuf
  u16* t0      = (u16*)alloc((size_t)N_NODES * 64 * 2);
  u16* t1      = (u16*)alloc((size_t)N_NODES * 64 * 2);
  u16* t2      = (u16*)alloc((size_t)N_NODES * 64 * 2);
  u16* hmid = (u16*)arena;
  u16* g1b  = (u16*)arena;                              // [2][N][32] blocked
  u16* abuf = (u16*)arena + (size_t)N_NODES * 64;       // [2][N][32] blocked
  u16* counts = t1;  // [N,96] bf16 overlays t1+t2 head; dead before t1/t2 written
  u16* Bp_w2a = bpack;           // 8192
  u16* Bp_lw1 = bpack + 8192;    // 4096
  u16* Bp_lw2 = bpack + 12288;   // 4096
  u16* Bp_fw1 = bpack + 16384;   // 8192

  hipMemsetAsync(flag, 0, 16 + 384 * 4 + (size_t)N_NODES * 4 + NBKT * 4, stream);

  k_detect<<<1, 256, 0, stream>>>((const u16*)d_in[3], flag);

  CvtAll ca;
  const int srcidx[22] = {3, 4, 5, 6, 7, 8, 9, 10, 11, 12, 13, 14, 15, 16, 17, 18, 19, 20, 21, 22, 23, 24};
  const int cnts[22]   = {4160, 1024, 16384, 128, 8192, 64, 1, 64, 64, 4096, 64, 4096, 64, 1, 64, 64, 16384, 64, 64, 64, 64, 1};
  const int offs[22]   = {P_EMBD, P_EMBL, P_W1A, P_B1A, P_W2A, P_B2A, P_EPS0, P_G0, P_BB0,
                          P_LW1, P_LB1, P_LW2, P_LB2, P_EPS1, P_G1, P_BB1,
                          P_FW1, P_FB1, P_FG, P_FBB, P_FW2, P_FB2};
  for (int i = 0; i < 22; ++i) { ca.src[i] = d_in[srcidx[i]]; ca.cnt[i] = cnts[i]; ca.off[i] = offs[i]; }
  k_cvtall<<<dim3(64, 22), 256, 0, stream>>>(ca, flag, Pb);

  k_prep<<<157, 256, 0, stream>>>(Pb, W1p, Efc, bpack);
  k_prep2<<<48, 256, 0, stream>>>(W1p, wpB);

  // edge bucket-sort (dst>>9), then CSR from sorted edges
  k_bc<<<NCHK, 256, 0, stream>>>(edge, tcnt);
  k_bscan<<<1, 256, 0, stream>>>(tcnt, gcur);
  k_bsort<<<NCHK, 256, 0, stream>>>(edge, node_deg, node_lab, gcur, e2);
  k_deg2<<<(N_EDGES + 255) / 256, 256, 0, stream>>>(e2, deg);
  k_scan1<<<NBLK_SCAN, 256, 0, stream>>>(deg, row_ptr, bsum);
  k_scan2<<<1, 512, 0, stream>>>(bsum);
  k_fill2<<<(N_EDGES + 255) / 256, 256, 0, stream>>>(e2, row_ptr, bsum, einfo);

  const int GEMM_GRID = (6250 + 3) / 4;

  // layer 0: histogram -> MFMA GEMM (K=96) -> t0 (stats fused)
  k_hist<<<(N_NODES + 255) / 256, 256, 0, stream>>>(row_ptr, bsum, einfo, counts);
  k_gemm0h<<<GEMM_GRID, 256, 0, stream>>>(counts, wpB, W1p, Pb, node_deg, node_lab, hmid);
  k_gemm<4, 128, P_B2A><<<GEMM_GRID, 256, 0, stream>>>(hmid, Bp_w2a, Pb, stats, t0);

  // layer 1: BN fused into GEMM A-load -> blocked g1; 2-pass gather; blkA GEMM
  k_gemm_bn<<<GEMM_GRID, 256, 0, stream>>>(t0, Bp_lw1, Pb, stats, g1b);
  k_agg1b<<<AGG1B_NB * 2, 256, 0, stream>>>(row_ptr, bsum, einfo, g1b, Pb, abuf);
  k_gemm_blkA<<<GEMM_GRID, 256, 0, stream>>>(abuf, Bp_lw2, Pb, stats + 128, t1);

  // FC head: BN0/BN1 fused into A-load, stats fused out
  k_gemm_fc1bn<<<GEMM_GRID, 256, 0, stream>>>(t0, t1, Bp_fw1, Pb, stats, stats + 256,
                                              node_deg, node_lab, Efc, t2);
  k_fc2<<<(N_NODES + 255) / 256, 256, 0, stream>>>(t2, stats + 256, Pb, flag, d_out);
}

// Round 13
// 483.556 us; speedup vs baseline: 1.2572x; 1.2572x over previous
//
#include <hip/hip_runtime.h>

#define N_NODES 100000
#define N_EDGES 1200000
#define NCLS 81   // 65 deg classes + 16 lab classes
#define NBKT 196  // dst>>9 buckets (512 nodes each)
#define NCHK 293  // ceil(N_EDGES/4096)
#define NSLOT 6252  // GEMM wave slots (1563 blocks x 4 waves)

typedef unsigned short u16;
typedef unsigned char u8;
typedef unsigned int u32;
typedef unsigned long long u64;
typedef short bf16x8 __attribute__((ext_vector_type(8)));
typedef float f32x4 __attribute__((ext_vector_type(4)));

__device__ __forceinline__ float b2f(u16 u) {
  union { u32 i; float f; } v; v.i = ((u32)u) << 16; return v.f;
}
__device__ __forceinline__ u16 f2b(float f) {
  union { float f; u32 i; } v; v.f = f;
  u32 x = v.i;
  return (u16)((x + 0x7fffu + ((x >> 16) & 1u)) >> 16);
}
__device__ __forceinline__ u32 pk2(float lo, float hi) {
  return (u32)f2b(lo) | ((u32)f2b(hi) << 16);
}
__device__ __forceinline__ void up2(u32 w, float& lo, float& hi) {
  union { u32 u; float f; } a, b;
  a.u = w << 16; b.u = w & 0xffff0000u;
  lo = a.f; hi = b.f;
}
__device__ __forceinline__ float lrelu(float x) { return x > 0.f ? x : 0.01f * x; }

// ---- fp32 param block offsets ----
#define P_EMBD 0       // 4160
#define P_EMBL 4160    // 1024
#define P_W1A  5184    // 16384  l0_w1 (128x128)
#define P_B1A  21568   // 128
#define P_W2A  21696   // 8192   l0_w2 (128x64)
#define P_B2A  29888   // 64
#define P_EPS0 29952   // 1
#define P_G0   29953   // 64
#define P_BB0  30017   // 64
#define P_LW1  30081   // 4096   l1_w1 (64x64)
#define P_LB1  34177   // 64
#define P_LW2  34241   // 4096   l1_w2 (64x64)
#define P_LB2  38337   // 64
#define P_EPS1 38401   // 1
#define P_G1   38402   // 64
#define P_BB1  38466   // 64
#define P_FW1  38530   // 16384  fc_w1 (256x64)
#define P_FB1  54914   // 64
#define P_FG   54978   // 64
#define P_FBB  55042   // 64
#define P_FW2  55106   // 64
#define P_FB2  55170   // 1
#define P_TOT  55171

// ---------------- dtype detection ----------------
__global__ void k_detect(const u16* __restrict__ e, u32* __restrict__ flag) {
  u32 t = 0;
  for (int k = threadIdx.x; k < 4096; k += 256) {
    u32 ex = (e[k] >> 7) & 0xFF;
    if (ex >= 0x90) t = 1;
  }
  if (t) atomicOr(flag, 1u);
}

// ---------------- convert all float params to fp32 block ----------------
struct CvtAll {
  const void* src[22];
  int cnt[22];
  int off[22];
};

__global__ void k_cvtall(CvtAll a, const u32* __restrict__ flag, float* __restrict__ P) {
  int seg = blockIdx.y;
  int i = blockIdx.x * 256 + threadIdx.x;
  if (i >= a.cnt[seg]) return;
  float v;
  if (*flag) v = ((const float*)a.src[seg])[i];
  else       v = b2f(((const u16*)a.src[seg])[i]);
  P[a.off[seg] + i] = v;
}

// ---------------- merged preprocessing: W1p, Efc, MFMA B-pack ----------------
__global__ void k_prep(const float* __restrict__ P, float* __restrict__ W1p,
                       float* __restrict__ Efc, u16* __restrict__ bp) {
  int idx = blockIdx.x * 256 + threadIdx.x;
  if (idx < NCLS * 128) {
    int c = idx >> 7, h = idx & 127;
    const float* w1 = P + P_W1A;
    float s = 0.f;
    if (c < 65) {
      const float* em = P + P_EMBD + c * 64;
      for (int k = 0; k < 64; ++k) s = fmaf(em[k], w1[k * 128 + h], s);
    } else {
      const float* em = P + P_EMBL + (c - 65) * 64;
      for (int k = 0; k < 64; ++k) s = fmaf(em[k], w1[(64 + k) * 128 + h], s);
    }
    W1p[idx] = s;
    return;
  }
  if (idx < NCLS * 128 + NCLS * 64) {
    int r = idx - NCLS * 128;
    int c = r >> 6, o = r & 63;
    const float* fw = P + P_FW1;
    float s = 0.f;
    if (c < 65) {
      const float* em = P + P_EMBD + c * 64;
      for (int k = 0; k < 64; ++k) s = fmaf(em[k], fw[k * 64 + o], s);
    } else {
      const float* em = P + P_EMBL + (c - 65) * 64;
      for (int k = 0; k < 64; ++k) s = fmaf(em[k], fw[(64 + k) * 64 + o], s);
    }
    Efc[r] = s;
    return;
  }
  int pidx = idx - (NCLS * 128 + NCLS * 64);
  if (pidx >= 24576) return;
  int seg, rel;
  if (pidx < 8192)       { seg = 0; rel = pidx; }
  else if (pidx < 12288) { seg = 1; rel = pidx - 8192; }
  else if (pidx < 16384) { seg = 2; rel = pidx - 12288; }
  else                   { seg = 3; rel = pidx - 16384; }
  const int srcoff[4] = {P_W2A, P_LW1, P_LW2, P_FW1 + 128 * 64};
  const int KBs[4] = {4, 2, 2, 4};
  int j = rel & 7, lane = (rel >> 3) & 63, rest = rel >> 9;
  int kb = rest % KBs[seg], nt = rest / KBs[seg];
  int k = kb * 32 + (lane >> 4) * 8 + j;
  int n = nt * 16 + (lane & 15);
  bp[pidx] = f2b(P[srcoff[seg] + k * 64 + n]);
}

// ---------------- pack W1p into K=96 MFMA B-frag table (zero-pad rows 81..95) -------
__global__ void k_prep2(const float* __restrict__ W1p, u16* __restrict__ wpB) {
  int idx = blockIdx.x * 256 + threadIdx.x;
  if (idx >= 12288) return;
  int j = idx & 7, lane = (idx >> 3) & 63, rest = idx >> 9;
  int kb = rest % 3, nt = rest / 3;
  int c = kb * 32 + (lane >> 4) * 8 + j;
  int n = nt * 16 + (lane & 15);
  wpB[idx] = (c < NCLS) ? f2b(W1p[c * 128 + n]) : 0;
}

// ---------------- bucket counting-sort of edges by dst>>9 ----------------
__global__ __launch_bounds__(256) void k_bc(const int* __restrict__ edge, u32* __restrict__ tcnt) {
  __shared__ u32 c[NBKT];
  for (int i = threadIdx.x; i < NBKT; i += 256) c[i] = 0;
  __syncthreads();
  int base = blockIdx.x * 4096;
  for (int i = threadIdx.x; i < 4096; i += 256) {
    int e = base + i;
    if (e < N_EDGES) atomicAdd(&c[(u32)edge[N_EDGES + e] >> 9], 1u);
  }
  __syncthreads();
  for (int i = threadIdx.x; i < NBKT; i += 256)
    if (c[i]) atomicAdd(&tcnt[i], c[i]);
}

__global__ void k_bscan(const u32* __restrict__ tcnt, u32* __restrict__ gcur) {
  __shared__ u32 l[256];
  int tid = threadIdx.x;
  u32 v = (tid < NBKT) ? tcnt[tid] : 0u;
  l[tid] = v;
  __syncthreads();
  for (int off = 1; off < 256; off <<= 1) {
    u32 a = (tid >= off) ? l[tid - off] : 0u;
    __syncthreads();
    l[tid] += a;
    __syncthreads();
  }
  if (tid < NBKT) gcur[tid] = l[tid] - v;
}

__global__ __launch_bounds__(256) void k_bsort(const int* __restrict__ edge,
                                               const int* __restrict__ ndeg,
                                               const int* __restrict__ nlab,
                                               u32* __restrict__ gcur,
                                               u64* __restrict__ e2) {
  __shared__ u32 cnt[NBKT], rbase[NBKT];
  __shared__ u32 slo[4096], shi[4096];
  for (int i = threadIdx.x; i < NBKT; i += 256) cnt[i] = 0;
  __syncthreads();
  int base = blockIdx.x * 4096;
  for (int i = threadIdx.x; i < 4096; i += 256) {
    int e = base + i;
    if (e < N_EDGES) {
      int s = edge[e], d = edge[N_EDGES + e];
      slo[i] = ((u32)s << 11) | ((u32)ndeg[s] << 4) | (u32)nlab[s];
      shi[i] = (u32)d;
      atomicAdd(&cnt[(u32)d >> 9], 1u);
    } else shi[i] = 0xFFFFFFFFu;
  }
  __syncthreads();
  for (int i = threadIdx.x; i < NBKT; i += 256) {
    u32 c = cnt[i];
    rbase[i] = c ? atomicAdd(&gcur[i], c) : 0u;
    cnt[i] = 0;
  }
  __syncthreads();
  for (int i = threadIdx.x; i < 4096; i += 256) {
    u32 d = shi[i];
    if (d == 0xFFFFFFFFu) continue;
    u32 b = d >> 9;
    u32 pos = rbase[b] + atomicAdd(&cnt[b], 1u);
    e2[pos] = ((u64)d << 32) | (u64)slo[i];
  }
}

// ---------------- in-degree over dst-sorted edges ----------------
__global__ void k_deg2(const u64* __restrict__ e2, u32* __restrict__ deg) {
  int e = blockIdx.x * 256 + threadIdx.x;
  if (e >= N_EDGES) return;
  atomicAdd(&deg[(u32)(e2[e] >> 32)], 1u);
}

// ---------------- CSR scan ----------------
__global__ void k_scan1(const u32* __restrict__ deg, u32* __restrict__ row_ptr,
                        u32* __restrict__ bsum) {
  __shared__ u32 l[256];
  int tid = threadIdx.x;
  int i = blockIdx.x * 256 + tid;
  u32 v = (i < N_NODES) ? deg[i] : 0u;
  l[tid] = v;
  __syncthreads();
  for (int off = 1; off < 256; off <<= 1) {
    u32 a = (tid >= off) ? l[tid - off] : 0u;
    __syncthreads();
    l[tid] += a;
    __syncthreads();
  }
  if (i < N_NODES) row_ptr[i] = l[tid] - v;
  if (tid == 255) bsum[blockIdx.x] = l[255];
}

#define NBLK_SCAN 391

__global__ void k_scan2(u32* __restrict__ bsum) {
  __shared__ u32 l[512];
  int tid = threadIdx.x;
  u32 v = (tid < NBLK_SCAN) ? bsum[tid] : 0u;
  l[tid] = v;
  __syncthreads();
  for (int off = 1; off < 512; off <<= 1) {
    u32 a = (tid >= off) ? l[tid - off] : 0u;
    __syncthreads();
    l[tid] += a;
    __syncthreads();
  }
  if (tid < NBLK_SCAN) bsum[tid] = l[tid] - v;
}

// ---------------- CSR fill from sorted edges ----------------
__global__ void k_fill2(const u64* __restrict__ e2, u32* __restrict__ rp,
                        const u32* __restrict__ bsum, u32* __restrict__ einfo) {
  int e = blockIdx.x * 256 + threadIdx.x;
  if (e >= N_EDGES) return;
  u64 r = e2[e];
  u32 d = (u32)(r >> 32);
  u32 pos = atomicAdd(&rp[d], 1u) + bsum[d >> 8];
  einfo[pos] = (u32)r;
}

__device__ __forceinline__ u32 row_start(const u32* rp, const u32* bsum, int n) {
  return (n == 0) ? 0u : rp[n - 1] + bsum[(n - 1) >> 8];
}
__device__ __forceinline__ u32 row_end(const u32* rp, const u32* bsum, int n) {
  return rp[n] + bsum[n >> 8];
}

// ---------------- layer-0 class histogram: thread-per-node, private LDS ----------
__global__ __launch_bounds__(256) void k_hist(const u32* __restrict__ rp,
                                              const u32* __restrict__ bsum,
                                              const u32* __restrict__ einfo,
                                              u16* __restrict__ counts) {
  __shared__ u8 h[256 * 96];
  int tid = threadIdx.x;
  u32* hw = (u32*)h;
#pragma unroll
  for (int i = 0; i < 24; ++i) hw[tid * 24 + i] = 0;
  __syncthreads();
  int n = blockIdx.x * 256 + tid;
  if (n < N_NODES) {
    u32 st = row_start(rp, bsum, n), en = row_end(rp, bsum, n);
    u8* my = h + tid * 96;
    for (u32 e = st; e < en; ++e) {
      u32 q = einfo[e];
      ++my[(q >> 4) & 0x7Fu];
      ++my[65u + (q & 15u)];
    }
  }
  __syncthreads();
  int b0 = blockIdx.x * 256;
  for (int idx = tid; idx < 256 * 96; idx += 256) {
    int nl = idx / 96;
    if (b0 + nl < N_NODES) counts[(size_t)(b0 + nl) * 96 + (idx - nl * 96)] = f2b((float)h[idx]);
  }
}

// ---------------- layer-0 MFMA GEMM: hmid = lrelu(counts@W1p + b1 + onep*self) -----
__global__ __launch_bounds__(256) void k_gemm0h(const u16* __restrict__ counts,
                                                const u16* __restrict__ wpB,
                                                const float* __restrict__ W1p,
                                                const float* __restrict__ P,
                                                const int* __restrict__ ndeg,
                                                const int* __restrict__ nlab,
                                                u16* __restrict__ hmid) {
  int wid = threadIdx.x >> 6, lane = threadIdx.x & 63;
  int m0 = (blockIdx.x * 4 + wid) * 16;
  if (m0 >= N_NODES) return;
  int row = lane & 15, q = lane >> 4;
  float onep = 1.f + P[P_EPS0];
  const u16* ap = counts + (size_t)(m0 + row) * 96 + q * 8;
  const bf16x8* bp = (const bf16x8*)wpB;
  f32x4 acc[8];
#pragma unroll
  for (int nt = 0; nt < 8; ++nt) {
    float b = P[P_B1A + nt * 16 + row];
    acc[nt][0] = b; acc[nt][1] = b; acc[nt][2] = b; acc[nt][3] = b;
  }
#pragma unroll
  for (int kb = 0; kb < 3; ++kb) {
    bf16x8 af = *(const bf16x8*)(ap + kb * 32);
#pragma unroll
    for (int nt = 0; nt < 8; ++nt) {
      bf16x8 bf = bp[(nt * 3 + kb) * 64 + lane];
      acc[nt] = __builtin_amdgcn_mfma_f32_16x16x32_bf16(af, bf, acc[nt], 0, 0, 0);
    }
  }
#pragma unroll
  for (int r = 0; r < 4; ++r) {
    int m = m0 + q * 4 + r;
    const float* wd = W1p + ndeg[m] * 128;
    const float* wl = W1p + (65 + nlab[m]) * 128;
#pragma unroll
    for (int nt = 0; nt < 8; ++nt) {
      int cc = nt * 16 + row;
      float v = acc[nt][r] + onep * (wd[cc] + wl[cc]);
      hmid[(size_t)m * 128 + cc] = f2b(lrelu(v));
    }
  }
}

// ---------------- stats partial reduction (no atomics anywhere) ----------------
// pbuf[slot][128]: per-wave-slot {sum[64] | sumsq[64]}
__global__ void k_sr1(const float* __restrict__ pbuf, float* __restrict__ p2) {
  int t = threadIdx.x, col = t & 127, half = t >> 7;
  int r0 = blockIdx.x * 2 + half;
  float acc = 0.f;
  for (int s = r0; s < NSLOT; s += 128) acc += pbuf[(size_t)s * 128 + col];
  p2[(size_t)r0 * 128 + col] = acc;
}

__global__ void k_sr2(const float* __restrict__ p2, float* __restrict__ statsOut) {
  int t = threadIdx.x;
  if (t >= 128) return;
  float acc = 0.f;
  for (int r = 0; r < 128; ++r) acc += p2[r * 128 + t];
  statsOut[t] = acc;
}

// ---------------- MFMA GEMM (plain A) + per-slot stats partials ----------------
template <int KB, int LDA, int BIASOFF>
__global__ __launch_bounds__(256) void k_gemm(const u16* __restrict__ A,
                                              const u16* __restrict__ Bp,
                                              const float* __restrict__ P,
                                              float* __restrict__ pbuf,
                                              u16* __restrict__ C) {
  int wid = threadIdx.x >> 6, lane = threadIdx.x & 63;
  int m0 = (blockIdx.x * 4 + wid) * 16;
  bool act = m0 < N_NODES;
  int row = lane & 15, q = lane >> 4;
  float ss[4] = {0.f, 0.f, 0.f, 0.f}, qq[4] = {0.f, 0.f, 0.f, 0.f};
  if (act) {
    const u16* ap = A + (size_t)(m0 + row) * LDA + q * 8;
    const bf16x8* bp = (const bf16x8*)Bp;
    f32x4 acc[4];
#pragma unroll
    for (int nt = 0; nt < 4; ++nt) {
      float b = (BIASOFF >= 0) ? P[BIASOFF + nt * 16 + row] : 0.f;
      acc[nt][0] = b; acc[nt][1] = b; acc[nt][2] = b; acc[nt][3] = b;
    }
#pragma unroll
    for (int kb = 0; kb < KB; ++kb) {
      bf16x8 af = *(const bf16x8*)(ap + kb * 32);
#pragma unroll
      for (int nt = 0; nt < 4; ++nt) {
        bf16x8 bf = bp[(nt * KB + kb) * 64 + lane];
        acc[nt] = __builtin_amdgcn_mfma_f32_16x16x32_bf16(af, bf, acc[nt], 0, 0, 0);
      }
    }
#pragma unroll
    for (int nt = 0; nt < 4; ++nt) {
      float s = 0.f, z = 0.f;
#pragma unroll
      for (int r = 0; r < 4; ++r) {
        int m = m0 + q * 4 + r;
        u16 bv = f2b(acc[nt][r]);
        C[(size_t)m * 64 + nt * 16 + row] = bv;
        float v = b2f(bv);
        s += v; z = fmaf(v, v, z);
      }
      s += __shfl_xor(s, 16, 64); s += __shfl_xor(s, 32, 64);
      z += __shfl_xor(z, 16, 64); z += __shfl_xor(z, 32, 64);
      ss[nt] = s; qq[nt] = z;
    }
  }
  if (lane < 16) {
    float* pb = pbuf + (size_t)(blockIdx.x * 4 + wid) * 128;
#pragma unroll
    for (int nt = 0; nt < 4; ++nt) {
      pb[nt * 16 + lane] = ss[nt];
      pb[64 + nt * 16 + lane] = qq[nt];
    }
  }
}

// ---------------- MFMA GEMM with fused BN+lrelu on A (K=64) -> blocked g1 ----------
__global__ __launch_bounds__(256) void k_gemm_bn(const u16* __restrict__ A,
                                                 const u16* __restrict__ Bp,
                                                 const float* __restrict__ P,
                                                 const float* __restrict__ stats,
                                                 u16* __restrict__ g1b) {
  int wid = threadIdx.x >> 6, lane = threadIdx.x & 63;
  int m0 = (blockIdx.x * 4 + wid) * 16;
  if (m0 >= N_NODES) return;
  int row = lane & 15, q = lane >> 4;
  const float invN = 1.f / (float)N_NODES;
  float sc[16], sh[16];
#pragma unroll
  for (int kb = 0; kb < 2; ++kb)
#pragma unroll
    for (int j = 0; j < 8; ++j) {
      int f = kb * 32 + q * 8 + j;
      float mm = stats[f] * invN;
      float var = fmaxf(stats[64 + f] * invN - mm * mm, 0.f);
      float inv = rsqrtf(var + 1e-5f);
      float s = inv * P[P_G0 + f];
      sc[kb * 8 + j] = s;
      sh[kb * 8 + j] = P[P_BB0 + f] - mm * s;
    }
  const u16* ap = A + (size_t)(m0 + row) * 64 + q * 8;
  const bf16x8* bp = (const bf16x8*)Bp;
  f32x4 acc[4];
#pragma unroll
  for (int nt = 0; nt < 4; ++nt) {
    acc[nt][0] = 0.f; acc[nt][1] = 0.f; acc[nt][2] = 0.f; acc[nt][3] = 0.f;
  }
#pragma unroll
  for (int kb = 0; kb < 2; ++kb) {
    uint4 raw = *(const uint4*)(ap + kb * 32);
    u32 rw[4] = {raw.x, raw.y, raw.z, raw.w};
    bf16x8 af;
#pragma unroll
    for (int p = 0; p < 4; ++p) {
      float lo, hi;
      up2(rw[p], lo, hi);
      float y0 = lrelu(fmaf(sc[kb * 8 + 2 * p], lo, sh[kb * 8 + 2 * p]));
      float y1 = lrelu(fmaf(sc[kb * 8 + 2 * p + 1], hi, sh[kb * 8 + 2 * p + 1]));
      af[2 * p] = (short)f2b(y0);
      af[2 * p + 1] = (short)f2b(y1);
    }
#pragma unroll
    for (int nt = 0; nt < 4; ++nt) {
      bf16x8 bf = bp[(nt * 2 + kb) * 64 + lane];
      acc[nt] = __builtin_amdgcn_mfma_f32_16x16x32_bf16(af, bf, acc[nt], 0, 0, 0);
    }
  }
#pragma unroll
  for (int nt = 0; nt < 4; ++nt) {
    u16* base = g1b + (size_t)(nt >> 1) * N_NODES * 32;
    int c32 = (nt & 1) * 16 + row;
#pragma unroll
    for (int r = 0; r < 4; ++r) {
      int m = m0 + q * 4 + r;
      base[(size_t)m * 32 + c32] = f2b(acc[nt][r]);
    }
  }
}

// ---------------- layer-1 aggregation: 2-pass feature-blocked (64-B rows) ----------
#define AGG1B_NB 25000
__global__ __launch_bounds__(256) void k_agg1b(const u32* __restrict__ rp,
                                               const u32* __restrict__ bsum,
                                               const u32* __restrict__ einfo,
                                               const u16* __restrict__ g1b,
                                               const float* __restrict__ P,
                                               u16* __restrict__ abuf) {
  int pass = blockIdx.x / AGG1B_NB;
  int nb = blockIdx.x - pass * AGG1B_NB;
  int wv = threadIdx.x >> 6, lane = threadIdx.x & 63;
  int f = lane & 31, es = lane >> 5;
  int n = nb * 4 + wv;
  u32 st = row_start(rp, bsum, n), en = row_end(rp, bsum, n);
  u32 m = en - st;
  const u16* gp = g1b + (size_t)pass * N_NODES * 32;
  float aA = 0.f, aB = 0.f, aC = 0.f, aD = 0.f;
  u32 k = 0;
  for (; k + 16 <= m; k += 16) {
    u32 s0 = einfo[st + k + es] >> 11;
    u32 s1 = einfo[st + k + 2 + es] >> 11;
    u32 s2 = einfo[st + k + 4 + es] >> 11;
    u32 s3 = einfo[st + k + 6 + es] >> 11;
    u32 s4 = einfo[st + k + 8 + es] >> 11;
    u32 s5 = einfo[st + k + 10 + es] >> 11;
    u32 s6 = einfo[st + k + 12 + es] >> 11;
    u32 s7 = einfo[st + k + 14 + es] >> 11;
    float v0 = b2f(gp[(size_t)s0 * 32 + f]);
    float v1 = b2f(gp[(size_t)s1 * 32 + f]);
    float v2 = b2f(gp[(size_t)s2 * 32 + f]);
    float v3 = b2f(gp[(size_t)s3 * 32 + f]);
    float v4 = b2f(gp[(size_t)s4 * 32 + f]);
    float v5 = b2f(gp[(size_t)s5 * 32 + f]);
    float v6 = b2f(gp[(size_t)s6 * 32 + f]);
    float v7 = b2f(gp[(size_t)s7 * 32 + f]);
    aA += v0 + v1; aB += v2 + v3; aC += v4 + v5; aD += v6 + v7;
  }
  if (k + 8 <= m) {
    u32 s0 = einfo[st + k + es] >> 11;
    u32 s1 = einfo[st + k + 2 + es] >> 11;
    u32 s2 = einfo[st + k + 4 + es] >> 11;
    u32 s3 = einfo[st + k + 6 + es] >> 11;
    aA += b2f(gp[(size_t)s0 * 32 + f]);
    aB += b2f(gp[(size_t)s1 * 32 + f]);
    aC += b2f(gp[(size_t)s2 * 32 + f]);
    aD += b2f(gp[(size_t)s3 * 32 + f]);
    k += 8;
  }
  if (k + 4 <= m) {
    u32 s0 = einfo[st + k + es] >> 11;
    u32 s1 = einfo[st + k + 2 + es] >> 11;
    aA += b2f(gp[(size_t)s0 * 32 + f]);
    aB += b2f(gp[(size_t)s1 * 32 + f]);
    k += 4;
  }
  if (k + 2 <= m) {
    u32 s0 = einfo[st + k + es] >> 11;
    aC += b2f(gp[(size_t)s0 * 32 + f]);
    k += 2;
  }
  if (k < m && es == 0) {
    u32 s0 = einfo[st + k] >> 11;
    aD += b2f(gp[(size_t)s0 * 32 + f]);
  }
  float acc = (aA + aB) + (aC + aD);
  acc += __shfl_xor(acc, 32, 64);
  if (es == 0) {
    float onep = 1.f + P[P_EPS1];
    float self = b2f(gp[(size_t)n * 32 + f]);
    float a = P[P_LB1 + pass * 32 + f] + fmaf(onep, self, acc);
    abuf[(size_t)pass * N_NODES * 32 + (size_t)n * 32 + f] = f2b(lrelu(a));
  }
}

// ---------------- GEMM from blocked-A abuf (K=64) + stats partials -> t1 -----------
__global__ __launch_bounds__(256) void k_gemm_blkA(const u16* __restrict__ A,
                                                   const u16* __restrict__ Bp,
                                                   const float* __restrict__ P,
                                                   float* __restrict__ pbuf,
                                                   u16* __restrict__ C) {
  int wid = threadIdx.x >> 6, lane = threadIdx.x & 63;
  int m0 = (blockIdx.x * 4 + wid) * 16;
  bool act = m0 < N_NODES;
  int row = lane & 15, q = lane >> 4;
  float ss[4] = {0.f, 0.f, 0.f, 0.f}, qq[4] = {0.f, 0.f, 0.f, 0.f};
  if (act) {
    const bf16x8* bp = (const bf16x8*)Bp;
    f32x4 acc[4];
#pragma unroll
    for (int nt = 0; nt < 4; ++nt) {
      float b = P[P_LB2 + nt * 16 + row];
      acc[nt][0] = b; acc[nt][1] = b; acc[nt][2] = b; acc[nt][3] = b;
    }
#pragma unroll
    for (int kb = 0; kb < 2; ++kb) {
      const u16* ap = A + (size_t)kb * N_NODES * 32 + (size_t)(m0 + row) * 32 + q * 8;
      bf16x8 af = *(const bf16x8*)ap;
#pragma unroll
      for (int nt = 0; nt < 4; ++nt) {
        bf16x8 bf = bp[(nt * 2 + kb) * 64 + lane];
        acc[nt] = __builtin_amdgcn_mfma_f32_16x16x32_bf16(af, bf, acc[nt], 0, 0, 0);
      }
    }
#pragma unroll
    for (int nt = 0; nt < 4; ++nt) {
      float s = 0.f, z = 0.f;
#pragma unroll
      for (int r = 0; r < 4; ++r) {
        int m = m0 + q * 4 + r;
        u16 bv = f2b(acc[nt][r]);
        C[(size_t)m * 64 + nt * 16 + row] = bv;
        float v = b2f(bv);
        s += v; z = fmaf(v, v, z);
      }
      s += __shfl_xor(s, 16, 64); s += __shfl_xor(s, 32, 64);
      z += __shfl_xor(z, 16, 64); z += __shfl_xor(z, 32, 64);
      ss[nt] = s; qq[nt] = z;
    }
  }
  if (lane < 16) {
    float* pb = pbuf + (size_t)(blockIdx.x * 4 + wid) * 128;
#pragma unroll
    for (int nt = 0; nt < 4; ++nt) {
      pb[nt * 16 + lane] = ss[nt];
      pb[64 + nt * 16 + lane] = qq[nt];
    }
  }
}

// ---------------- fc1 GEMM: A = [BN0(t0) | BN1(t1)] fused, + Efc + stats partials ---
__global__ __launch_bounds__(256) void k_gemm_fc1bn(const u16* __restrict__ t0,
                                                    const u16* __restrict__ t1,
                                                    const u16* __restrict__ Bp,
                                                    const float* __restrict__ P,
                                                    const float* __restrict__ stats,
                                                    float* __restrict__ pbuf,
                                                    const int* __restrict__ ndeg,
                                                    const int* __restrict__ nlab,
                                                    const float* __restrict__ Efc,
                                                    u16* __restrict__ C) {
  int wid = threadIdx.x >> 6, lane = threadIdx.x & 63;
  int m0 = (blockIdx.x * 4 + wid) * 16;
  bool act = m0 < N_NODES;
  int row = lane & 15, q = lane >> 4;
  float ss[4] = {0.f, 0.f, 0.f, 0.f}, qq[4] = {0.f, 0.f, 0.f, 0.f};
  if (act) {
    const float invN = 1.f / (float)N_NODES;
    float sc[32], sh[32];
#pragma unroll
    for (int h = 0; h < 2; ++h) {
      const float* st = stats + h * 128;
      int gof = h ? P_G1 : P_G0, bof = h ? P_BB1 : P_BB0;
#pragma unroll
      for (int kb = 0; kb < 2; ++kb)
#pragma unroll
        for (int j = 0; j < 8; ++j) {
          int f = kb * 32 + q * 8 + j;
          float mm = st[f] * invN;
          float var = fmaxf(st[64 + f] * invN - mm * mm, 0.f);
          float inv = rsqrtf(var + 1e-5f);
          float s = inv * P[gof + f];
          sc[h * 16 + kb * 8 + j] = s;
          sh[h * 16 + kb * 8 + j] = P[bof + f] - mm * s;
        }
    }
    const u16* a0 = t0 + (size_t)(m0 + row) * 64 + q * 8;
    const u16* a1 = t1 + (size_t)(m0 + row) * 64 + q * 8;
    const bf16x8* bp = (const bf16x8*)Bp;
    f32x4 acc[4];
#pragma unroll
    for (int nt = 0; nt < 4; ++nt) {
      float b = P[P_FB1 + nt * 16 + row];
      acc[nt][0] = b; acc[nt][1] = b; acc[nt][2] = b; acc[nt][3] = b;
    }
#pragma unroll
    for (int kb = 0; kb < 4; ++kb) {
      const u16* src = (kb < 2) ? (a0 + kb * 32) : (a1 + (kb - 2) * 32);
      int ci = (kb < 2) ? kb * 8 : 16 + (kb - 2) * 8;
      uint4 raw = *(const uint4*)src;
      u32 rw[4] = {raw.x, raw.y, raw.z, raw.w};
      bf16x8 af;
#pragma unroll
      for (int p = 0; p < 4; ++p) {
        float lo, hi;
        up2(rw[p], lo, hi);
        float y0 = lrelu(fmaf(sc[ci + 2 * p], lo, sh[ci + 2 * p]));
        float y1 = lrelu(fmaf(sc[ci + 2 * p + 1], hi, sh[ci + 2 * p + 1]));
        af[2 * p] = (short)f2b(y0);
        af[2 * p + 1] = (short)f2b(y1);
      }
#pragma unroll
      for (int nt = 0; nt < 4; ++nt) {
        bf16x8 bf = bp[(nt * 4 + kb) * 64 + lane];
        acc[nt] = __builtin_amdgcn_mfma_f32_16x16x32_bf16(af, bf, acc[nt], 0, 0, 0);
      }
    }
    float es[4][4];
#pragma unroll
    for (int r = 0; r < 4; ++r) {
      int m = m0 + q * 4 + r;
      int dn = ndeg[m], ln = 65 + nlab[m];
#pragma unroll
      for (int nt = 0; nt < 4; ++nt) {
        int cc = nt * 16 + row;
        es[r][nt] = acc[nt][r] + Efc[dn * 64 + cc] + Efc[ln * 64 + cc];
      }
    }
#pragma unroll
    for (int nt = 0; nt < 4; ++nt) {
      float s = 0.f, z = 0.f;
#pragma unroll
      for (int r = 0; r < 4; ++r) {
        int m = m0 + q * 4 + r;
        u16 bv = f2b(es[r][nt]);
        C[(size_t)m * 64 + nt * 16 + row] = bv;
        float v = b2f(bv);
        s += v; z = fmaf(v, v, z);
      }
      s += __shfl_xor(s, 16, 64); s += __shfl_xor(s, 32, 64);
      z += __shfl_xor(z, 16, 64); z += __shfl_xor(z, 32, 64);
      ss[nt] = s; qq[nt] = z;
    }
  }
  if (lane < 16) {
    float* pb = pbuf + (size_t)(blockIdx.x * 4 + wid) * 128;
#pragma unroll
    for (int nt = 0; nt < 4; ++nt) {
      pb[nt * 16 + lane] = ss[nt];
      pb[64 + nt * 16 + lane] = qq[nt];
    }
  }
}

// ---------------- FC final: BN + lrelu + dot + sigmoid ----------------
__global__ void k_fc2(const u16* __restrict__ t, const float* __restrict__ stats,
                      const float* __restrict__ P, const u32* __restrict__ flag,
                      void* __restrict__ out) {
  int n = blockIdx.x * blockDim.x + threadIdx.x;
  if (n >= N_NODES) return;
  float z = P[P_FB2];
  const float invN = 1.f / (float)N_NODES;
  const u16* tn = t + (size_t)n * 64;
#pragma unroll 1
  for (int f = 0; f < 64; ++f) {
    float m = stats[f] * invN;
    float var = fmaxf(stats[64 + f] * invN - m * m, 0.f);
    float inv = rsqrtf(var + 1e-5f);
    float y = (b2f(tn[f]) - m) * inv * P[P_FG + f] + P[P_FBB + f];
    y = lrelu(y);
    z = fmaf(y, P[P_FW2 + f], z);
  }
  float s = 1.f / (1.f + expf(-z));
  if (!(fabsf(z) < 1e30f)) s = 0.25f;
  if (*flag) ((float*)out)[n] = s;
  else       ((u16*)out)[n] = f2b(s);
}

extern "C" void kernel_launch(void* const* d_in, const int* in_sizes, int n_in,
                              void* d_out, int out_size, void* d_ws, size_t ws_size,
                              hipStream_t stream) {
  const int* node_deg = (const int*)d_in[0];
  const int* node_lab = (const int*)d_in[1];
  const int* edge     = (const int*)d_in[2];
  (void)in_sizes; (void)n_in; (void)out_size; (void)ws_size;

  char* base = (char*)d_ws;
  size_t off = 0;
  auto alloc = [&](size_t bytes) -> void* {
    void* p = base + off;
    off += (bytes + 15) & ~(size_t)15;
    return p;
  };
  float* Pb    = (float*)alloc((size_t)P_TOT * 4);
  // contiguous zero region: flag | stats | deg | tcnt (one memset)
  u32* flag    = (u32*)alloc(16);
  float* stats = (float*)alloc(384 * 4);
  u32* deg     = (u32*)alloc((size_t)N_NODES * 4);
  u32* tcnt    = (u32*)alloc(NBKT * 4);
  float* W1p   = (float*)alloc(NCLS * 128 * 4);
  float* Efc   = (float*)alloc(NCLS * 64 * 4);
  u16* bpack   = (u16*)alloc(24576 * 2);
  u16* wpB     = (u16*)alloc(12288 * 2);
  u32* row_ptr = (u32*)alloc((size_t)(N_NODES + 1) * 4);
  u32* bsum    = (u32*)alloc(512 * 4);
  u32* gcur    = (u32*)alloc(NBKT * 4);
  float* pbuf  = (float*)alloc((size_t)NSLOT * 128 * 4);  // 3.2 MB stats partials
  float* p2    = (float*)alloc(128 * 128 * 4);
  u32* einfo   = (u32*)alloc((size_t)N_EDGES * 4);
  u64* e2      = (u64*)alloc((size_t)N_EDGES * 8);
  void* arena  = alloc((size_t)N_NODES * 128 * 2);  // hmid; later g1b+abuf
  u16* t0      = (u16*)alloc((size_t)N_NODES * 64 * 2);
  u16* t1      = (u16*)alloc((size_t)N_NODES * 64 * 2);
  u16* t2      = (u16*)alloc((size_t)N_NODES * 64 * 2);
  u16* hmid = (u16*)arena;
  u16* g1b  = (u16*)arena;                              // [2][N][32] blocked
  u16* abuf = (u16*)arena + (size_t)N_NODES * 64;       // [2][N][32] blocked
  u16* counts = t1;  // [N,96] bf16 overlays t1+t2 head; dead before t1/t2 written
  u16* Bp_w2a = bpack;           // 8192
  u16* Bp_lw1 = bpack + 8192;    // 4096
  u16* Bp_lw2 = bpack + 12288;   // 4096
  u16* Bp_fw1 = bpack + 16384;   // 8192

  hipMemsetAsync(flag, 0, 16 + 384 * 4 + (size_t)N_NODES * 4 + NBKT * 4, stream);

  k_detect<<<1, 256, 0, stream>>>((const u16*)d_in[3], flag);

  CvtAll ca;
  const int srcidx[22] = {3, 4, 5, 6, 7, 8, 9, 10, 11, 12, 13, 14, 15, 16, 17, 18, 19, 20, 21, 22, 23, 24};
  const int cnts[22]   = {4160, 1024, 16384, 128, 8192, 64, 1, 64, 64, 4096, 64, 4096, 64, 1, 64, 64, 16384, 64, 64, 64, 64, 1};
  const int offs[22]   = {P_EMBD, P_EMBL, P_W1A, P_B1A, P_W2A, P_B2A, P_EPS0, P_G0, P_BB0,
                          P_LW1, P_LB1, P_LW2, P_LB2, P_EPS1, P_G1, P_BB1,
                          P_FW1, P_FB1, P_FG, P_FBB, P_FW2, P_FB2};
  for (int i = 0; i < 22; ++i) { ca.src[i] = d_in[srcidx[i]]; ca.cnt[i] = cnts[i]; ca.off[i] = offs[i]; }
  k_cvtall<<<dim3(64, 22), 256, 0, stream>>>(ca, flag, Pb);

  k_prep<<<157, 256, 0, stream>>>(Pb, W1p, Efc, bpack);
  k_prep2<<<48, 256, 0, stream>>>(W1p, wpB);

  // edge bucket-sort (dst>>9), then CSR from sorted edges
  k_bc<<<NCHK, 256, 0, stream>>>(edge, tcnt);
  k_bscan<<<1, 256, 0, stream>>>(tcnt, gcur);
  k_bsort<<<NCHK, 256, 0, stream>>>(edge, node_deg, node_lab, gcur, e2);
  k_deg2<<<(N_EDGES + 255) / 256, 256, 0, stream>>>(e2, deg);
  k_scan1<<<NBLK_SCAN, 256, 0, stream>>>(deg, row_ptr, bsum);
  k_scan2<<<1, 512, 0, stream>>>(bsum);
  k_fill2<<<(N_EDGES + 255) / 256, 256, 0, stream>>>(e2, row_ptr, bsum, einfo);

  const int GEMM_GRID = (6250 + 3) / 4;  // 1563 blocks -> NSLOT=6252 wave slots

  // layer 0: histogram -> MFMA GEMM (K=96) -> t0 (stats via partials, no atomics)
  k_hist<<<(N_NODES + 255) / 256, 256, 0, stream>>>(row_ptr, bsum, einfo, counts);
  k_gemm0h<<<GEMM_GRID, 256, 0, stream>>>(counts, wpB, W1p, Pb, node_deg, node_lab, hmid);
  k_gemm<4, 128, P_B2A><<<GEMM_GRID, 256, 0, stream>>>(hmid, Bp_w2a, Pb, pbuf, t0);
  k_sr1<<<64, 256, 0, stream>>>(pbuf, p2);
  k_sr2<<<1, 128, 0, stream>>>(p2, stats);

  // layer 1: BN fused into GEMM A-load -> blocked g1; 2-pass gather; blkA GEMM
  k_gemm_bn<<<GEMM_GRID, 256, 0, stream>>>(t0, Bp_lw1, Pb, stats, g1b);
  k_agg1b<<<AGG1B_NB * 2, 256, 0, stream>>>(row_ptr, bsum, einfo, g1b, Pb, abuf);
  k_gemm_blkA<<<GEMM_GRID, 256, 0, stream>>>(abuf, Bp_lw2, Pb, pbuf, t1);
  k_sr1<<<64, 256, 0, stream>>>(pbuf, p2);
  k_sr2<<<1, 128, 0, stream>>>(p2, stats + 128);

  // FC head: BN0/BN1 fused into A-load, stats via partials
  k_gemm_fc1bn<<<GEMM_GRID, 256, 0, stream>>>(t0, t1, Bp_fw1, Pb, stats, pbuf,
                                              node_deg, node_lab, Efc, t2);
  k_sr1<<<64, 256, 0, stream>>>(pbuf, p2);
  k_sr2<<<1, 128, 0, stream>>>(p2, stats + 256);
  k_fc2<<<(N_NODES + 255) / 256, 256, 0, stream>>>(t2, stats + 256, Pb, flag, d_out);
}

// Round 14
// 449.103 us; speedup vs baseline: 1.3536x; 1.0767x over previous
//
#include <hip/hip_runtime.h>

#define N_NODES 100000
#define N_EDGES 1200000
#define NCLS 81   // 65 deg classes + 16 lab classes
#define NBKT 196  // dst>>9 buckets (512 nodes each)
#define NCHK 293  // ceil(N_EDGES/4096)
#define NSLOT 6252  // GEMM wave slots (1563 blocks x 4 waves)

typedef unsigned short u16;
typedef unsigned char u8;
typedef unsigned int u32;
typedef unsigned long long u64;
typedef short bf16x8 __attribute__((ext_vector_type(8)));
typedef float f32x4 __attribute__((ext_vector_type(4)));

__device__ __forceinline__ float b2f(u16 u) {
  union { u32 i; float f; } v; v.i = ((u32)u) << 16; return v.f;
}
__device__ __forceinline__ u16 f2b(float f) {
  union { float f; u32 i; } v; v.f = f;
  u32 x = v.i;
  return (u16)((x + 0x7fffu + ((x >> 16) & 1u)) >> 16);
}
__device__ __forceinline__ u32 pk2(float lo, float hi) {
  return (u32)f2b(lo) | ((u32)f2b(hi) << 16);
}
__device__ __forceinline__ void up2(u32 w, float& lo, float& hi) {
  union { u32 u; float f; } a, b;
  a.u = w << 16; b.u = w & 0xffff0000u;
  lo = a.f; hi = b.f;
}
__device__ __forceinline__ float lrelu(float x) { return x > 0.f ? x : 0.01f * x; }

// ---- fp32 param block offsets ----
#define P_EMBD 0       // 4160
#define P_EMBL 4160    // 1024
#define P_W1A  5184    // 16384  l0_w1 (128x128)
#define P_B1A  21568   // 128
#define P_W2A  21696   // 8192   l0_w2 (128x64)
#define P_B2A  29888   // 64
#define P_EPS0 29952   // 1
#define P_G0   29953   // 64
#define P_BB0  30017   // 64
#define P_LW1  30081   // 4096   l1_w1 (64x64)
#define P_LB1  34177   // 64
#define P_LW2  34241   // 4096   l1_w2 (64x64)
#define P_LB2  38337   // 64
#define P_EPS1 38401   // 1
#define P_G1   38402   // 64
#define P_BB1  38466   // 64
#define P_FW1  38530   // 16384  fc_w1 (256x64)
#define P_FB1  54914   // 64
#define P_FG   54978   // 64
#define P_FBB  55042   // 64
#define P_FW2  55106   // 64
#define P_FB2  55170   // 1
#define P_TOT  55171

// ---------------- dtype detection ----------------
__global__ void k_detect(const u16* __restrict__ e, u32* __restrict__ flag) {
  u32 t = 0;
  for (int k = threadIdx.x; k < 4096; k += 256) {
    u32 ex = (e[k] >> 7) & 0xFF;
    if (ex >= 0x90) t = 1;
  }
  if (t) atomicOr(flag, 1u);
}

// ---------------- convert all float params to fp32 block ----------------
struct CvtAll {
  const void* src[22];
  int cnt[22];
  int off[22];
};

__global__ void k_cvtall(CvtAll a, const u32* __restrict__ flag, float* __restrict__ P) {
  int seg = blockIdx.y;
  int i = blockIdx.x * 256 + threadIdx.x;
  if (i >= a.cnt[seg]) return;
  float v;
  if (*flag) v = ((const float*)a.src[seg])[i];
  else       v = b2f(((const u16*)a.src[seg])[i]);
  P[a.off[seg] + i] = v;
}

// ---------------- merged preprocessing: W1p, Efc, MFMA B-pack ----------------
__global__ void k_prep(const float* __restrict__ P, float* __restrict__ W1p,
                       float* __restrict__ Efc, u16* __restrict__ bp) {
  int idx = blockIdx.x * 256 + threadIdx.x;
  if (idx < NCLS * 128) {
    int c = idx >> 7, h = idx & 127;
    const float* w1 = P + P_W1A;
    float s = 0.f;
    if (c < 65) {
      const float* em = P + P_EMBD + c * 64;
      for (int k = 0; k < 64; ++k) s = fmaf(em[k], w1[k * 128 + h], s);
    } else {
      const float* em = P + P_EMBL + (c - 65) * 64;
      for (int k = 0; k < 64; ++k) s = fmaf(em[k], w1[(64 + k) * 128 + h], s);
    }
    W1p[idx] = s;
    return;
  }
  if (idx < NCLS * 128 + NCLS * 64) {
    int r = idx - NCLS * 128;
    int c = r >> 6, o = r & 63;
    const float* fw = P + P_FW1;
    float s = 0.f;
    if (c < 65) {
      const float* em = P + P_EMBD + c * 64;
      for (int k = 0; k < 64; ++k) s = fmaf(em[k], fw[k * 64 + o], s);
    } else {
      const float* em = P + P_EMBL + (c - 65) * 64;
      for (int k = 0; k < 64; ++k) s = fmaf(em[k], fw[(64 + k) * 64 + o], s);
    }
    Efc[r] = s;
    return;
  }
  int pidx = idx - (NCLS * 128 + NCLS * 64);
  if (pidx >= 24576) return;
  int seg, rel;
  if (pidx < 8192)       { seg = 0; rel = pidx; }
  else if (pidx < 12288) { seg = 1; rel = pidx - 8192; }
  else if (pidx < 16384) { seg = 2; rel = pidx - 12288; }
  else                   { seg = 3; rel = pidx - 16384; }
  const int srcoff[4] = {P_W2A, P_LW1, P_LW2, P_FW1 + 128 * 64};
  const int KBs[4] = {4, 2, 2, 4};
  int j = rel & 7, lane = (rel >> 3) & 63, rest = rel >> 9;
  int kb = rest % KBs[seg], nt = rest / KBs[seg];
  int k = kb * 32 + (lane >> 4) * 8 + j;
  int n = nt * 16 + (lane & 15);
  bp[pidx] = f2b(P[srcoff[seg] + k * 64 + n]);
}

// ---------------- pack W1p into K=96 MFMA B-frag table (zero-pad rows 81..95) -------
__global__ void k_prep2(const float* __restrict__ W1p, u16* __restrict__ wpB) {
  int idx = blockIdx.x * 256 + threadIdx.x;
  if (idx >= 12288) return;
  int j = idx & 7, lane = (idx >> 3) & 63, rest = idx >> 9;
  int kb = rest % 3, nt = rest / 3;
  int c = kb * 32 + (lane >> 4) * 8 + j;
  int n = nt * 16 + (lane & 15);
  wpB[idx] = (c < NCLS) ? f2b(W1p[c * 128 + n]) : 0;
}

// ---------------- bucket counting-sort of edges by dst>>9 ----------------
__global__ __launch_bounds__(256) void k_bc(const int* __restrict__ edge, u32* __restrict__ tcnt) {
  __shared__ u32 c[NBKT];
  for (int i = threadIdx.x; i < NBKT; i += 256) c[i] = 0;
  __syncthreads();
  int base = blockIdx.x * 4096;
  for (int i = threadIdx.x; i < 4096; i += 256) {
    int e = base + i;
    if (e < N_EDGES) atomicAdd(&c[(u32)edge[N_EDGES + e] >> 9], 1u);
  }
  __syncthreads();
  for (int i = threadIdx.x; i < NBKT; i += 256)
    if (c[i]) atomicAdd(&tcnt[i], c[i]);
}

__global__ void k_bscan(const u32* __restrict__ tcnt, u32* __restrict__ gcur) {
  __shared__ u32 l[256];
  int tid = threadIdx.x;
  u32 v = (tid < NBKT) ? tcnt[tid] : 0u;
  l[tid] = v;
  __syncthreads();
  for (int off = 1; off < 256; off <<= 1) {
    u32 a = (tid >= off) ? l[tid - off] : 0u;
    __syncthreads();
    l[tid] += a;
    __syncthreads();
  }
  if (tid < NBKT) gcur[tid] = l[tid] - v;
}

__global__ __launch_bounds__(256) void k_bsort(const int* __restrict__ edge,
                                               const int* __restrict__ ndeg,
                                               const int* __restrict__ nlab,
                                               u32* __restrict__ gcur,
                                               u64* __restrict__ e2) {
  __shared__ u32 cnt[NBKT], rbase[NBKT];
  __shared__ u32 slo[4096], shi[4096];
  for (int i = threadIdx.x; i < NBKT; i += 256) cnt[i] = 0;
  __syncthreads();
  int base = blockIdx.x * 4096;
  for (int i = threadIdx.x; i < 4096; i += 256) {
    int e = base + i;
    if (e < N_EDGES) {
      int s = edge[e], d = edge[N_EDGES + e];
      slo[i] = ((u32)s << 11) | ((u32)ndeg[s] << 4) | (u32)nlab[s];
      shi[i] = (u32)d;
      atomicAdd(&cnt[(u32)d >> 9], 1u);
    } else shi[i] = 0xFFFFFFFFu;
  }
  __syncthreads();
  for (int i = threadIdx.x; i < NBKT; i += 256) {
    u32 c = cnt[i];
    rbase[i] = c ? atomicAdd(&gcur[i], c) : 0u;
    cnt[i] = 0;
  }
  __syncthreads();
  for (int i = threadIdx.x; i < 4096; i += 256) {
    u32 d = shi[i];
    if (d == 0xFFFFFFFFu) continue;
    u32 b = d >> 9;
    u32 pos = rbase[b] + atomicAdd(&cnt[b], 1u);
    e2[pos] = ((u64)d << 32) | (u64)slo[i];
  }
}

// ---------------- in-degree over dst-sorted edges ----------------
__global__ void k_deg2(const u64* __restrict__ e2, u32* __restrict__ deg) {
  int e = blockIdx.x * 256 + threadIdx.x;
  if (e >= N_EDGES) return;
  atomicAdd(&deg[(u32)(e2[e] >> 32)], 1u);
}

// ---------------- CSR scan ----------------
__global__ void k_scan1(const u32* __restrict__ deg, u32* __restrict__ row_ptr,
                        u32* __restrict__ bsum) {
  __shared__ u32 l[256];
  int tid = threadIdx.x;
  int i = blockIdx.x * 256 + tid;
  u32 v = (i < N_NODES) ? deg[i] : 0u;
  l[tid] = v;
  __syncthreads();
  for (int off = 1; off < 256; off <<= 1) {
    u32 a = (tid >= off) ? l[tid - off] : 0u;
    __syncthreads();
    l[tid] += a;
    __syncthreads();
  }
  if (i < N_NODES) row_ptr[i] = l[tid] - v;
  if (tid == 255) bsum[blockIdx.x] = l[255];
}

#define NBLK_SCAN 391

__global__ void k_scan2(u32* __restrict__ bsum) {
  __shared__ u32 l[512];
  int tid = threadIdx.x;
  u32 v = (tid < NBLK_SCAN) ? bsum[tid] : 0u;
  l[tid] = v;
  __syncthreads();
  for (int off = 1; off < 512; off <<= 1) {
    u32 a = (tid >= off) ? l[tid - off] : 0u;
    __syncthreads();
    l[tid] += a;
    __syncthreads();
  }
  if (tid < NBLK_SCAN) bsum[tid] = l[tid] - v;
}

// ---------------- CSR fill from sorted edges ----------------
__global__ void k_fill2(const u64* __restrict__ e2, u32* __restrict__ rp,
                        const u32* __restrict__ bsum, u32* __restrict__ einfo) {
  int e = blockIdx.x * 256 + threadIdx.x;
  if (e >= N_EDGES) return;
  u64 r = e2[e];
  u32 d = (u32)(r >> 32);
  u32 pos = atomicAdd(&rp[d], 1u) + bsum[d >> 8];
  einfo[pos] = (u32)r;
}

__device__ __forceinline__ u32 row_start(const u32* rp, const u32* bsum, int n) {
  return (n == 0) ? 0u : rp[n - 1] + bsum[(n - 1) >> 8];
}
__device__ __forceinline__ u32 row_end(const u32* rp, const u32* bsum, int n) {
  return rp[n] + bsum[n >> 8];
}

// ---------------- layer-0 class histogram: thread-per-node, private LDS ----------
__global__ __launch_bounds__(256) void k_hist(const u32* __restrict__ rp,
                                              const u32* __restrict__ bsum,
                                              const u32* __restrict__ einfo,
                                              u16* __restrict__ counts) {
  __shared__ u8 h[256 * 96];
  int tid = threadIdx.x;
  u32* hw = (u32*)h;
#pragma unroll
  for (int i = 0; i < 24; ++i) hw[tid * 24 + i] = 0;
  __syncthreads();
  int n = blockIdx.x * 256 + tid;
  if (n < N_NODES) {
    u32 st = row_start(rp, bsum, n), en = row_end(rp, bsum, n);
    u8* my = h + tid * 96;
    for (u32 e = st; e < en; ++e) {
      u32 q = einfo[e];
      ++my[(q >> 4) & 0x7Fu];
      ++my[65u + (q & 15u)];
    }
  }
  __syncthreads();
  int b0 = blockIdx.x * 256;
  for (int idx = tid; idx < 256 * 96; idx += 256) {
    int nl = idx / 96;
    if (b0 + nl < N_NODES) counts[(size_t)(b0 + nl) * 96 + (idx - nl * 96)] = f2b((float)h[idx]);
  }
}

// ---------------- layer-0 MFMA GEMM: hmid = lrelu(counts@W1p + b1 + onep*self) -----
__global__ __launch_bounds__(256) void k_gemm0h(const u16* __restrict__ counts,
                                                const u16* __restrict__ wpB,
                                                const float* __restrict__ W1p,
                                                const float* __restrict__ P,
                                                const int* __restrict__ ndeg,
                                                const int* __restrict__ nlab,
                                                u16* __restrict__ hmid) {
  int wid = threadIdx.x >> 6, lane = threadIdx.x & 63;
  int m0 = (blockIdx.x * 4 + wid) * 16;
  if (m0 >= N_NODES) return;
  int row = lane & 15, q = lane >> 4;
  float onep = 1.f + P[P_EPS0];
  const u16* ap = counts + (size_t)(m0 + row) * 96 + q * 8;
  const bf16x8* bp = (const bf16x8*)wpB;
  f32x4 acc[8];
#pragma unroll
  for (int nt = 0; nt < 8; ++nt) {
    float b = P[P_B1A + nt * 16 + row];
    acc[nt][0] = b; acc[nt][1] = b; acc[nt][2] = b; acc[nt][3] = b;
  }
#pragma unroll
  for (int kb = 0; kb < 3; ++kb) {
    bf16x8 af = *(const bf16x8*)(ap + kb * 32);
#pragma unroll
    for (int nt = 0; nt < 8; ++nt) {
      bf16x8 bf = bp[(nt * 3 + kb) * 64 + lane];
      acc[nt] = __builtin_amdgcn_mfma_f32_16x16x32_bf16(af, bf, acc[nt], 0, 0, 0);
    }
  }
#pragma unroll
  for (int r = 0; r < 4; ++r) {
    int m = m0 + q * 4 + r;
    const float* wd = W1p + ndeg[m] * 128;
    const float* wl = W1p + (65 + nlab[m]) * 128;
#pragma unroll
    for (int nt = 0; nt < 8; ++nt) {
      int cc = nt * 16 + row;
      float v = acc[nt][r] + onep * (wd[cc] + wl[cc]);
      hmid[(size_t)m * 128 + cc] = f2b(lrelu(v));
    }
  }
}

// ---------------- stats partial reduction (no atomics anywhere) ----------------
__global__ void k_sr1(const float* __restrict__ pbuf, float* __restrict__ p2) {
  int t = threadIdx.x, col = t & 127, half = t >> 7;
  int r0 = blockIdx.x * 2 + half;
  float acc = 0.f;
  for (int s = r0; s < NSLOT; s += 128) acc += pbuf[(size_t)s * 128 + col];
  p2[(size_t)r0 * 128 + col] = acc;
}

__global__ void k_sr2(const float* __restrict__ p2, float* __restrict__ statsOut) {
  int t = threadIdx.x;
  if (t >= 128) return;
  float acc = 0.f;
  for (int r = 0; r < 128; ++r) acc += p2[r * 128 + t];
  statsOut[t] = acc;
}

// ---------------- MFMA GEMM (plain A) + per-slot stats partials ----------------
template <int KB, int LDA, int BIASOFF>
__global__ __launch_bounds__(256) void k_gemm(const u16* __restrict__ A,
                                              const u16* __restrict__ Bp,
                                              const float* __restrict__ P,
                                              float* __restrict__ pbuf,
                                              u16* __restrict__ C) {
  int wid = threadIdx.x >> 6, lane = threadIdx.x & 63;
  int m0 = (blockIdx.x * 4 + wid) * 16;
  bool act = m0 < N_NODES;
  int row = lane & 15, q = lane >> 4;
  float ss[4] = {0.f, 0.f, 0.f, 0.f}, qq[4] = {0.f, 0.f, 0.f, 0.f};
  if (act) {
    const u16* ap = A + (size_t)(m0 + row) * LDA + q * 8;
    const bf16x8* bp = (const bf16x8*)Bp;
    f32x4 acc[4];
#pragma unroll
    for (int nt = 0; nt < 4; ++nt) {
      float b = (BIASOFF >= 0) ? P[BIASOFF + nt * 16 + row] : 0.f;
      acc[nt][0] = b; acc[nt][1] = b; acc[nt][2] = b; acc[nt][3] = b;
    }
#pragma unroll
    for (int kb = 0; kb < KB; ++kb) {
      bf16x8 af = *(const bf16x8*)(ap + kb * 32);
#pragma unroll
      for (int nt = 0; nt < 4; ++nt) {
        bf16x8 bf = bp[(nt * KB + kb) * 64 + lane];
        acc[nt] = __builtin_amdgcn_mfma_f32_16x16x32_bf16(af, bf, acc[nt], 0, 0, 0);
      }
    }
#pragma unroll
    for (int nt = 0; nt < 4; ++nt) {
      float s = 0.f, z = 0.f;
#pragma unroll
      for (int r = 0; r < 4; ++r) {
        int m = m0 + q * 4 + r;
        u16 bv = f2b(acc[nt][r]);
        C[(size_t)m * 64 + nt * 16 + row] = bv;
        float v = b2f(bv);
        s += v; z = fmaf(v, v, z);
      }
      s += __shfl_xor(s, 16, 64); s += __shfl_xor(s, 32, 64);
      z += __shfl_xor(z, 16, 64); z += __shfl_xor(z, 32, 64);
      ss[nt] = s; qq[nt] = z;
    }
  }
  if (lane < 16) {
    float* pb = pbuf + (size_t)(blockIdx.x * 4 + wid) * 128;
#pragma unroll
    for (int nt = 0; nt < 4; ++nt) {
      pb[nt * 16 + lane] = ss[nt];
      pb[64 + nt * 16 + lane] = qq[nt];
    }
  }
}

// ---------------- MFMA GEMM with fused BN+lrelu on A (K=64) -> row-major g1 --------
__global__ __launch_bounds__(256) void k_gemm_bn(const u16* __restrict__ A,
                                                 const u16* __restrict__ Bp,
                                                 const float* __restrict__ P,
                                                 const float* __restrict__ stats,
                                                 u16* __restrict__ C) {
  int wid = threadIdx.x >> 6, lane = threadIdx.x & 63;
  int m0 = (blockIdx.x * 4 + wid) * 16;
  if (m0 >= N_NODES) return;
  int row = lane & 15, q = lane >> 4;
  const float invN = 1.f / (float)N_NODES;
  float sc[16], sh[16];
#pragma unroll
  for (int kb = 0; kb < 2; ++kb)
#pragma unroll
    for (int j = 0; j < 8; ++j) {
      int f = kb * 32 + q * 8 + j;
      float mm = stats[f] * invN;
      float var = fmaxf(stats[64 + f] * invN - mm * mm, 0.f);
      float inv = rsqrtf(var + 1e-5f);
      float s = inv * P[P_G0 + f];
      sc[kb * 8 + j] = s;
      sh[kb * 8 + j] = P[P_BB0 + f] - mm * s;
    }
  const u16* ap = A + (size_t)(m0 + row) * 64 + q * 8;
  const bf16x8* bp = (const bf16x8*)Bp;
  f32x4 acc[4];
#pragma unroll
  for (int nt = 0; nt < 4; ++nt) {
    acc[nt][0] = 0.f; acc[nt][1] = 0.f; acc[nt][2] = 0.f; acc[nt][3] = 0.f;
  }
#pragma unroll
  for (int kb = 0; kb < 2; ++kb) {
    uint4 raw = *(const uint4*)(ap + kb * 32);
    u32 rw[4] = {raw.x, raw.y, raw.z, raw.w};
    bf16x8 af;
#pragma unroll
    for (int p = 0; p < 4; ++p) {
      float lo, hi;
      up2(rw[p], lo, hi);
      float y0 = lrelu(fmaf(sc[kb * 8 + 2 * p], lo, sh[kb * 8 + 2 * p]));
      float y1 = lrelu(fmaf(sc[kb * 8 + 2 * p + 1], hi, sh[kb * 8 + 2 * p + 1]));
      af[2 * p] = (short)f2b(y0);
      af[2 * p + 1] = (short)f2b(y1);
    }
#pragma unroll
    for (int nt = 0; nt < 4; ++nt) {
      bf16x8 bf = bp[(nt * 2 + kb) * 64 + lane];
      acc[nt] = __builtin_amdgcn_mfma_f32_16x16x32_bf16(af, bf, acc[nt], 0, 0, 0);
    }
  }
#pragma unroll
  for (int nt = 0; nt < 4; ++nt)
#pragma unroll
    for (int r = 0; r < 4; ++r) {
      int m = m0 + q * 4 + r;
      C[(size_t)m * 64 + nt * 16 + row] = f2b(acc[nt][r]);
    }
}

// ---------------- layer-1 aggregation: flat gather, 8-deep, 2 acc chains ----------
__global__ __launch_bounds__(256) void k_agg1(const u32* __restrict__ rp,
                                              const u32* __restrict__ bsum,
                                              const u32* __restrict__ einfo,
                                              const u16* __restrict__ g1,
                                              const float* __restrict__ P,
                                              u16* __restrict__ abuf) {
  int lane = threadIdx.x & 63, wv = threadIdx.x >> 6;
  int n = blockIdx.x * 4 + wv;
  if (n >= N_NODES) return;
  u32 st = row_start(rp, bsum, n), en = row_end(rp, bsum, n);
  u32 m = en - st;
  float acA = 0.f, acB = 0.f;
  u32 k = 0;
  for (; k + 8 <= m; k += 8) {
    u32 c0 = einfo[st + k] >> 11, c1 = einfo[st + k + 1] >> 11;
    u32 c2 = einfo[st + k + 2] >> 11, c3 = einfo[st + k + 3] >> 11;
    u32 c4 = einfo[st + k + 4] >> 11, c5 = einfo[st + k + 5] >> 11;
    u32 c6 = einfo[st + k + 6] >> 11, c7 = einfo[st + k + 7] >> 11;
    float v0 = b2f(g1[(size_t)c0 * 64 + lane]);
    float v1 = b2f(g1[(size_t)c1 * 64 + lane]);
    float v2 = b2f(g1[(size_t)c2 * 64 + lane]);
    float v3 = b2f(g1[(size_t)c3 * 64 + lane]);
    float v4 = b2f(g1[(size_t)c4 * 64 + lane]);
    float v5 = b2f(g1[(size_t)c5 * 64 + lane]);
    float v6 = b2f(g1[(size_t)c6 * 64 + lane]);
    float v7 = b2f(g1[(size_t)c7 * 64 + lane]);
    acA += (v0 + v1) + (v2 + v3);
    acB += (v4 + v5) + (v6 + v7);
  }
  if (k + 4 <= m) {
    u32 c0 = einfo[st + k] >> 11, c1 = einfo[st + k + 1] >> 11;
    u32 c2 = einfo[st + k + 2] >> 11, c3 = einfo[st + k + 3] >> 11;
    float v0 = b2f(g1[(size_t)c0 * 64 + lane]);
    float v1 = b2f(g1[(size_t)c1 * 64 + lane]);
    float v2 = b2f(g1[(size_t)c2 * 64 + lane]);
    float v3 = b2f(g1[(size_t)c3 * 64 + lane]);
    acA += (v0 + v1) + (v2 + v3);
    k += 4;
  }
  for (; k < m; ++k) acB += b2f(g1[(size_t)(einfo[st + k] >> 11) * 64 + lane]);
  float acc = acA + acB;
  float onep = 1.f + P[P_EPS1];
  float a = P[P_LB1 + lane] + fmaf(onep, b2f(g1[(size_t)n * 64 + lane]), acc);
  abuf[(size_t)n * 64 + lane] = f2b(lrelu(a));
}

// ---------------- fc1 GEMM: A = [BN0(t0) | BN1(t1)] fused, + Efc + stats partials ---
__global__ __launch_bounds__(256) void k_gemm_fc1bn(const u16* __restrict__ t0,
                                                    const u16* __restrict__ t1,
                                                    const u16* __restrict__ Bp,
                                                    const float* __restrict__ P,
                                                    const float* __restrict__ stats,
                                                    float* __restrict__ pbuf,
                                                    const int* __restrict__ ndeg,
                                                    const int* __restrict__ nlab,
                                                    const float* __restrict__ Efc,
                                                    u16* __restrict__ C) {
  int wid = threadIdx.x >> 6, lane = threadIdx.x & 63;
  int m0 = (blockIdx.x * 4 + wid) * 16;
  bool act = m0 < N_NODES;
  int row = lane & 15, q = lane >> 4;
  float ss[4] = {0.f, 0.f, 0.f, 0.f}, qq[4] = {0.f, 0.f, 0.f, 0.f};
  if (act) {
    const float invN = 1.f / (float)N_NODES;
    float sc[32], sh[32];
#pragma unroll
    for (int h = 0; h < 2; ++h) {
      const float* st = stats + h * 128;
      int gof = h ? P_G1 : P_G0, bof = h ? P_BB1 : P_BB0;
#pragma unroll
      for (int kb = 0; kb < 2; ++kb)
#pragma unroll
        for (int j = 0; j < 8; ++j) {
          int f = kb * 32 + q * 8 + j;
          float mm = st[f] * invN;
          float var = fmaxf(st[64 + f] * invN - mm * mm, 0.f);
          float inv = rsqrtf(var + 1e-5f);
          float s = inv * P[gof + f];
          sc[h * 16 + kb * 8 + j] = s;
          sh[h * 16 + kb * 8 + j] = P[bof + f] - mm * s;
        }
    }
    const u16* a0 = t0 + (size_t)(m0 + row) * 64 + q * 8;
    const u16* a1 = t1 + (size_t)(m0 + row) * 64 + q * 8;
    const bf16x8* bp = (const bf16x8*)Bp;
    f32x4 acc[4];
#pragma unroll
    for (int nt = 0; nt < 4; ++nt) {
      float b = P[P_FB1 + nt * 16 + row];
      acc[nt][0] = b; acc[nt][1] = b; acc[nt][2] = b; acc[nt][3] = b;
    }
#pragma unroll
    for (int kb = 0; kb < 4; ++kb) {
      const u16* src = (kb < 2) ? (a0 + kb * 32) : (a1 + (kb - 2) * 32);
      int ci = (kb < 2) ? kb * 8 : 16 + (kb - 2) * 8;
      uint4 raw = *(const uint4*)src;
      u32 rw[4] = {raw.x, raw.y, raw.z, raw.w};
      bf16x8 af;
#pragma unroll
      for (int p = 0; p < 4; ++p) {
        float lo, hi;
        up2(rw[p], lo, hi);
        float y0 = lrelu(fmaf(sc[ci + 2 * p], lo, sh[ci + 2 * p]));
        float y1 = lrelu(fmaf(sc[ci + 2 * p + 1], hi, sh[ci + 2 * p + 1]));
        af[2 * p] = (short)f2b(y0);
        af[2 * p + 1] = (short)f2b(y1);
      }
#pragma unroll
      for (int nt = 0; nt < 4; ++nt) {
        bf16x8 bf = bp[(nt * 4 + kb) * 64 + lane];
        acc[nt] = __builtin_amdgcn_mfma_f32_16x16x32_bf16(af, bf, acc[nt], 0, 0, 0);
      }
    }
    float es[4][4];
#pragma unroll
    for (int r = 0; r < 4; ++r) {
      int m = m0 + q * 4 + r;
      int dn = ndeg[m], ln = 65 + nlab[m];
#pragma unroll
      for (int nt = 0; nt < 4; ++nt) {
        int cc = nt * 16 + row;
        es[r][nt] = acc[nt][r] + Efc[dn * 64 + cc] + Efc[ln * 64 + cc];
      }
    }
#pragma unroll
    for (int nt = 0; nt < 4; ++nt) {
      float s = 0.f, z = 0.f;
#pragma unroll
      for (int r = 0; r < 4; ++r) {
        int m = m0 + q * 4 + r;
        u16 bv = f2b(es[r][nt]);
        C[(size_t)m * 64 + nt * 16 + row] = bv;
        float v = b2f(bv);
        s += v; z = fmaf(v, v, z);
      }
      s += __shfl_xor(s, 16, 64); s += __shfl_xor(s, 32, 64);
      z += __shfl_xor(z, 16, 64); z += __shfl_xor(z, 32, 64);
      ss[nt] = s; qq[nt] = z;
    }
  }
  if (lane < 16) {
    float* pb = pbuf + (size_t)(blockIdx.x * 4 + wid) * 128;
#pragma unroll
    for (int nt = 0; nt < 4; ++nt) {
      pb[nt * 16 + lane] = ss[nt];
      pb[64 + nt * 16 + lane] = qq[nt];
    }
  }
}

// ---------------- FC final: BN + lrelu + dot + sigmoid ----------------
__global__ void k_fc2(const u16* __restrict__ t, const float* __restrict__ stats,
                      const float* __restrict__ P, const u32* __restrict__ flag,
                      void* __restrict__ out) {
  int n = blockIdx.x * blockDim.x + threadIdx.x;
  if (n >= N_NODES) return;
  float z = P[P_FB2];
  const float invN = 1.f / (float)N_NODES;
  const u16* tn = t + (size_t)n * 64;
#pragma unroll 1
  for (int f = 0; f < 64; ++f) {
    float m = stats[f] * invN;
    float var = fmaxf(stats[64 + f] * invN - m * m, 0.f);
    float inv = rsqrtf(var + 1e-5f);
    float y = (b2f(tn[f]) - m) * inv * P[P_FG + f] + P[P_FBB + f];
    y = lrelu(y);
    z = fmaf(y, P[P_FW2 + f], z);
  }
  float s = 1.f / (1.f + expf(-z));
  if (!(fabsf(z) < 1e30f)) s = 0.25f;
  if (*flag) ((float*)out)[n] = s;
  else       ((u16*)out)[n] = f2b(s);
}

extern "C" void kernel_launch(void* const* d_in, const int* in_sizes, int n_in,
                              void* d_out, int out_size, void* d_ws, size_t ws_size,
                              hipStream_t stream) {
  const int* node_deg = (const int*)d_in[0];
  const int* node_lab = (const int*)d_in[1];
  const int* edge     = (const int*)d_in[2];
  (void)in_sizes; (void)n_in; (void)out_size; (void)ws_size;

  char* base = (char*)d_ws;
  size_t off = 0;
  auto alloc = [&](size_t bytes) -> void* {
    void* p = base + off;
    off += (bytes + 15) & ~(size_t)15;
    return p;
  };
  float* Pb    = (float*)alloc((size_t)P_TOT * 4);
  // contiguous zero region: flag | stats | deg | tcnt (one memset)
  u32* flag    = (u32*)alloc(16);
  float* stats = (float*)alloc(384 * 4);
  u32* deg     = (u32*)alloc((size_t)N_NODES * 4);
  u32* tcnt    = (u32*)alloc(NBKT * 4);
  float* W1p   = (float*)alloc(NCLS * 128 * 4);
  float* Efc   = (float*)alloc(NCLS * 64 * 4);
  u16* bpack   = (u16*)alloc(24576 * 2);
  u16* wpB     = (u16*)alloc(12288 * 2);
  u32* row_ptr = (u32*)alloc((size_t)(N_NODES + 1) * 4);
  u32* bsum    = (u32*)alloc(512 * 4);
  u32* gcur    = (u32*)alloc(NBKT * 4);
  float* pbuf  = (float*)alloc((size_t)NSLOT * 128 * 4);
  float* p2    = (float*)alloc(128 * 128 * 4);
  u32* einfo   = (u32*)alloc((size_t)N_EDGES * 4);
  u64* e2      = (u64*)alloc((size_t)N_EDGES * 8);
  void* arena  = alloc((size_t)N_NODES * 128 * 2);  // hmid; later g1+abuf
  u16* t0      = (u16*)alloc((size_t)N_NODES * 64 * 2);
  u16* t1      = (u16*)alloc((size_t)N_NODES * 64 * 2);
  u16* t2      = (u16*)alloc((size_t)N_NODES * 64 * 2);
  u16* hmid = (u16*)arena;
  u16* g1   = (u16*)arena;                              // [N,64] row-major
  u16* abuf = (u16*)arena + (size_t)N_NODES * 64;       // [N,64] row-major
  u16* counts = t1;  // [N,96] bf16 overlays t1+t2 head; dead before t1/t2 written
  u16* Bp_w2a = bpack;           // 8192
  u16* Bp_lw1 = bpack + 8192;    // 4096
  u16* Bp_lw2 = bpack + 12288;   // 4096
  u16* Bp_fw1 = bpack + 16384;   // 8192

  hipMemsetAsync(flag, 0, 16 + 384 * 4 + (size_t)N_NODES * 4 + NBKT * 4, stream);

  k_detect<<<1, 256, 0, stream>>>((const u16*)d_in[3], flag);

  CvtAll ca;
  const int srcidx[22] = {3, 4, 5, 6, 7, 8, 9, 10, 11, 12, 13, 14, 15, 16, 17, 18, 19, 20, 21, 22, 23, 24};
  const int cnts[22]   = {4160, 1024, 16384, 128, 8192, 64, 1, 64, 64, 4096, 64, 4096, 64, 1, 64, 64, 16384, 64, 64, 64, 64, 1};
  const int offs[22]   = {P_EMBD, P_EMBL, P_W1A, P_B1A, P_W2A, P_B2A, P_EPS0, P_G0, P_BB0,
                          P_LW1, P_LB1, P_LW2, P_LB2, P_EPS1, P_G1, P_BB1,
                          P_FW1, P_FB1, P_FG, P_FBB, P_FW2, P_FB2};
  for (int i = 0; i < 22; ++i) { ca.src[i] = d_in[srcidx[i]]; ca.cnt[i] = cnts[i]; ca.off[i] = offs[i]; }
  k_cvtall<<<dim3(64, 22), 256, 0, stream>>>(ca, flag, Pb);

  k_prep<<<157, 256, 0, stream>>>(Pb, W1p, Efc, bpack);
  k_prep2<<<48, 256, 0, stream>>>(W1p, wpB);

  // edge bucket-sort (dst>>9), then CSR from sorted edges
  k_bc<<<NCHK, 256, 0, stream>>>(edge, tcnt);
  k_bscan<<<1, 256, 0, stream>>>(tcnt, gcur);
  k_bsort<<<NCHK, 256, 0, stream>>>(edge, node_deg, node_lab, gcur, e2);
  k_deg2<<<(N_EDGES + 255) / 256, 256, 0, stream>>>(e2, deg);
  k_scan1<<<NBLK_SCAN, 256, 0, stream>>>(deg, row_ptr, bsum);
  k_scan2<<<1, 512, 0, stream>>>(bsum);
  k_fill2<<<(N_EDGES + 255) / 256, 256, 0, stream>>>(e2, row_ptr, bsum, einfo);

  const int GEMM_GRID = (6250 + 3) / 4;  // 1563 blocks -> NSLOT=6252 wave slots

  // layer 0: histogram -> MFMA GEMM (K=96) -> t0 (stats via partials, no atomics)
  k_hist<<<(N_NODES + 255) / 256, 256, 0, stream>>>(row_ptr, bsum, einfo, counts);
  k_gemm0h<<<GEMM_GRID, 256, 0, stream>>>(counts, wpB, W1p, Pb, node_deg, node_lab, hmid);
  k_gemm<4, 128, P_B2A><<<GEMM_GRID, 256, 0, stream>>>(hmid, Bp_w2a, Pb, pbuf, t0);
  k_sr1<<<64, 256, 0, stream>>>(pbuf, p2);
  k_sr2<<<1, 128, 0, stream>>>(p2, stats);

  // layer 1: BN fused into GEMM A-load -> row-major g1; flat gather; GEMM
  k_gemm_bn<<<GEMM_GRID, 256, 0, stream>>>(t0, Bp_lw1, Pb, stats, g1);
  k_agg1<<<(N_NODES + 3) / 4, 256, 0, stream>>>(row_ptr, bsum, einfo, g1, Pb, abuf);
  k_gemm<2, 64, P_LB2><<<GEMM_GRID, 256, 0, stream>>>(abuf, Bp_lw2, Pb, pbuf, t1);
  k_sr1<<<64, 256, 0, stream>>>(pbuf, p2);
  k_sr2<<<1, 128, 0, stream>>>(p2, stats + 128);

  // FC head: BN0/BN1 fused into A-load, stats via partials
  k_gemm_fc1bn<<<GEMM_GRID, 256, 0, stream>>>(t0, t1, Bp_fw1, Pb, stats, pbuf,
                                              node_deg, node_lab, Efc, t2);
  k_sr1<<<64, 256, 0, stream>>>(pbuf, p2);
  k_sr2<<<1, 128, 0, stream>>>(p2, stats + 256);
  k_fc2<<<(N_NODES + 255) / 256, 256, 0, stream>>>(t2, stats + 256, Pb, flag, d_out);
}

// Round 15
// 400.918 us; speedup vs baseline: 1.5163x; 1.1202x over previous
//
#include <hip/hip_runtime.h>

#define N_NODES 100000
#define N_EDGES 1200000
#define NCLS 81   // 65 deg classes + 16 lab classes
#define NBKT 196  // dst>>9 buckets (512 nodes each)
#define NCHK 293  // ceil(N_EDGES/4096)
#define NSLOT 6252  // GEMM wave slots (1563 blocks x 4 waves)

typedef unsigned short u16;
typedef unsigned char u8;
typedef unsigned int u32;
typedef unsigned long long u64;
typedef short bf16x8 __attribute__((ext_vector_type(8)));
typedef float f32x4 __attribute__((ext_vector_type(4)));

__device__ __forceinline__ float b2f(u16 u) {
  union { u32 i; float f; } v; v.i = ((u32)u) << 16; return v.f;
}
__device__ __forceinline__ u16 f2b(float f) {
  union { float f; u32 i; } v; v.f = f;
  u32 x = v.i;
  return (u16)((x + 0x7fffu + ((x >> 16) & 1u)) >> 16);
}
__device__ __forceinline__ u32 pk2(float lo, float hi) {
  return (u32)f2b(lo) | ((u32)f2b(hi) << 16);
}
__device__ __forceinline__ void up2(u32 w, float& lo, float& hi) {
  union { u32 u; float f; } a, b;
  a.u = w << 16; b.u = w & 0xffff0000u;
  lo = a.f; hi = b.f;
}
__device__ __forceinline__ float lrelu(float x) { return x > 0.f ? x : 0.01f * x; }

// ---- fp32 param block offsets ----
#define P_EMBD 0       // 4160
#define P_EMBL 4160    // 1024
#define P_W1A  5184    // 16384  l0_w1 (128x128)
#define P_B1A  21568   // 128
#define P_W2A  21696   // 8192   l0_w2 (128x64)
#define P_B2A  29888   // 64
#define P_EPS0 29952   // 1
#define P_G0   29953   // 64
#define P_BB0  30017   // 64
#define P_LW1  30081   // 4096   l1_w1 (64x64)
#define P_LB1  34177   // 64
#define P_LW2  34241   // 4096   l1_w2 (64x64)
#define P_LB2  38337   // 64
#define P_EPS1 38401   // 1
#define P_G1   38402   // 64
#define P_BB1  38466   // 64
#define P_FW1  38530   // 16384  fc_w1 (256x64)
#define P_FB1  54914   // 64
#define P_FG   54978   // 64
#define P_FBB  55042   // 64
#define P_FW2  55106   // 64
#define P_FB2  55170   // 1
#define P_TOT  55171

// ---------------- dtype detection ----------------
__global__ void k_detect(const u16* __restrict__ e, u32* __restrict__ flag) {
  u32 t = 0;
  for (int k = threadIdx.x; k < 4096; k += 256) {
    u32 ex = (e[k] >> 7) & 0xFF;
    if (ex >= 0x90) t = 1;
  }
  if (t) atomicOr(flag, 1u);
}

// ---------------- convert all float params to fp32 block ----------------
struct CvtAll {
  const void* src[22];
  int cnt[22];
  int off[22];
};

__global__ void k_cvtall(CvtAll a, const u32* __restrict__ flag, float* __restrict__ P) {
  int seg = blockIdx.y;
  int i = blockIdx.x * 256 + threadIdx.x;
  if (i >= a.cnt[seg]) return;
  float v;
  if (*flag) v = ((const float*)a.src[seg])[i];
  else       v = b2f(((const u16*)a.src[seg])[i]);
  P[a.off[seg] + i] = v;
}

// ---------------- merged preprocessing: W1p, Efc, MFMA B-pack ----------------
__global__ void k_prep(const float* __restrict__ P, float* __restrict__ W1p,
                       float* __restrict__ Efc, u16* __restrict__ bp) {
  int idx = blockIdx.x * 256 + threadIdx.x;
  if (idx < NCLS * 128) {
    int c = idx >> 7, h = idx & 127;
    const float* w1 = P + P_W1A;
    float s = 0.f;
    if (c < 65) {
      const float* em = P + P_EMBD + c * 64;
      for (int k = 0; k < 64; ++k) s = fmaf(em[k], w1[k * 128 + h], s);
    } else {
      const float* em = P + P_EMBL + (c - 65) * 64;
      for (int k = 0; k < 64; ++k) s = fmaf(em[k], w1[(64 + k) * 128 + h], s);
    }
    W1p[idx] = s;
    return;
  }
  if (idx < NCLS * 128 + NCLS * 64) {
    int r = idx - NCLS * 128;
    int c = r >> 6, o = r & 63;
    const float* fw = P + P_FW1;
    float s = 0.f;
    if (c < 65) {
      const float* em = P + P_EMBD + c * 64;
      for (int k = 0; k < 64; ++k) s = fmaf(em[k], fw[k * 64 + o], s);
    } else {
      const float* em = P + P_EMBL + (c - 65) * 64;
      for (int k = 0; k < 64; ++k) s = fmaf(em[k], fw[(64 + k) * 64 + o], s);
    }
    Efc[r] = s;
    return;
  }
  int pidx = idx - (NCLS * 128 + NCLS * 64);
  if (pidx >= 24576) return;
  int seg, rel;
  if (pidx < 8192)       { seg = 0; rel = pidx; }
  else if (pidx < 12288) { seg = 1; rel = pidx - 8192; }
  else if (pidx < 16384) { seg = 2; rel = pidx - 12288; }
  else                   { seg = 3; rel = pidx - 16384; }
  const int srcoff[4] = {P_W2A, P_LW1, P_LW2, P_FW1 + 128 * 64};
  const int KBs[4] = {4, 2, 2, 4};
  int j = rel & 7, lane = (rel >> 3) & 63, rest = rel >> 9;
  int kb = rest % KBs[seg], nt = rest / KBs[seg];
  int k = kb * 32 + (lane >> 4) * 8 + j;
  int n = nt * 16 + (lane & 15);
  bp[pidx] = f2b(P[srcoff[seg] + k * 64 + n]);
}

// ---------------- pack W1p into K=96 MFMA B-frag table (zero-pad rows 81..95) -------
__global__ void k_prep2(const float* __restrict__ W1p, u16* __restrict__ wpB) {
  int idx = blockIdx.x * 256 + threadIdx.x;
  if (idx >= 12288) return;
  int j = idx & 7, lane = (idx >> 3) & 63, rest = idx >> 9;
  int kb = rest % 3, nt = rest / 3;
  int c = kb * 32 + (lane >> 4) * 8 + j;
  int n = nt * 16 + (lane & 15);
  wpB[idx] = (c < NCLS) ? f2b(W1p[c * 128 + n]) : 0;
}

// ---------------- bucket counting-sort of edges by dst>>9 ----------------
__global__ __launch_bounds__(256) void k_bc(const int* __restrict__ edge, u32* __restrict__ tcnt) {
  __shared__ u32 c[NBKT];
  for (int i = threadIdx.x; i < NBKT; i += 256) c[i] = 0;
  __syncthreads();
  int base = blockIdx.x * 4096;
  for (int i = threadIdx.x; i < 4096; i += 256) {
    int e = base + i;
    if (e < N_EDGES) atomicAdd(&c[(u32)edge[N_EDGES + e] >> 9], 1u);
  }
  __syncthreads();
  for (int i = threadIdx.x; i < NBKT; i += 256)
    if (c[i]) atomicAdd(&tcnt[i], c[i]);
}

__global__ void k_bscan(const u32* __restrict__ tcnt, u32* __restrict__ gcur) {
  __shared__ u32 l[256];
  int tid = threadIdx.x;
  u32 v = (tid < NBKT) ? tcnt[tid] : 0u;
  l[tid] = v;
  __syncthreads();
  for (int off = 1; off < 256; off <<= 1) {
    u32 a = (tid >= off) ? l[tid - off] : 0u;
    __syncthreads();
    l[tid] += a;
    __syncthreads();
  }
  if (tid < NBKT) gcur[tid] = l[tid] - v;
}

__global__ __launch_bounds__(256) void k_bsort(const int* __restrict__ edge,
                                               const int* __restrict__ ndeg,
                                               const int* __restrict__ nlab,
                                               u32* __restrict__ gcur,
                                               u64* __restrict__ e2) {
  __shared__ u32 cnt[NBKT], rbase[NBKT];
  __shared__ u32 slo[4096], shi[4096];
  for (int i = threadIdx.x; i < NBKT; i += 256) cnt[i] = 0;
  __syncthreads();
  int base = blockIdx.x * 4096;
  for (int i = threadIdx.x; i < 4096; i += 256) {
    int e = base + i;
    if (e < N_EDGES) {
      int s = edge[e], d = edge[N_EDGES + e];
      slo[i] = ((u32)s << 11) | ((u32)ndeg[s] << 4) | (u32)nlab[s];
      shi[i] = (u32)d;
      atomicAdd(&cnt[(u32)d >> 9], 1u);
    } else shi[i] = 0xFFFFFFFFu;
  }
  __syncthreads();
  for (int i = threadIdx.x; i < NBKT; i += 256) {
    u32 c = cnt[i];
    rbase[i] = c ? atomicAdd(&gcur[i], c) : 0u;
    cnt[i] = 0;
  }
  __syncthreads();
  for (int i = threadIdx.x; i < 4096; i += 256) {
    u32 d = shi[i];
    if (d == 0xFFFFFFFFu) continue;
    u32 b = d >> 9;
    u32 pos = rbase[b] + atomicAdd(&cnt[b], 1u);
    e2[pos] = ((u64)d << 32) | (u64)slo[i];
  }
}

// ---------------- per-bucket CSR: histogram + scan + place (one kernel) ----------
// After k_bsort, gcur[b] = bucket end offset (base + count). Bucket b covers dst
// in [b*512, b*512+512). Emits plain CSR row_ptr[0..N] and dst-grouped einfo.
__global__ __launch_bounds__(512) void k_csr(const u64* __restrict__ e2,
                                             const u32* __restrict__ gcur,
                                             u32* __restrict__ row_ptr,
                                             u32* __restrict__ einfo) {
  __shared__ u32 l[512];
  __shared__ u32 cur[512];
  int b = blockIdx.x, tid = threadIdx.x;
  u32 st = (b == 0) ? 0u : gcur[b - 1];
  u32 en = gcur[b];
  l[tid] = 0;
  __syncthreads();
  for (u32 e = st + tid; e < en; e += 512)
    atomicAdd(&l[(u32)(e2[e] >> 32) & 511u], 1u);
  __syncthreads();
  u32 v = l[tid];
  for (int off = 1; off < 512; off <<= 1) {
    u32 a = (tid >= off) ? l[tid - off] : 0u;
    __syncthreads();
    l[tid] += a;
    __syncthreads();
  }
  u32 pos0 = st + l[tid] - v;  // exclusive within bucket + bucket base
  cur[tid] = pos0;
  int n = b * 512 + tid;
  if (n <= N_NODES) row_ptr[n] = pos0;
  __syncthreads();
  for (u32 e = st + tid; e < en; e += 512) {
    u64 r = e2[e];
    u32 pos = atomicAdd(&cur[(u32)(r >> 32) & 511u], 1u);
    einfo[pos] = (u32)r;
  }
}

// ---------------- layer-0 class histogram: thread-per-node, private LDS ----------
__global__ __launch_bounds__(256) void k_hist(const u32* __restrict__ rp,
                                              const u32* __restrict__ einfo,
                                              u16* __restrict__ counts) {
  __shared__ u8 h[256 * 96];
  int tid = threadIdx.x;
  u32* hw = (u32*)h;
#pragma unroll
  for (int i = 0; i < 24; ++i) hw[tid * 24 + i] = 0;
  __syncthreads();
  int n = blockIdx.x * 256 + tid;
  if (n < N_NODES) {
    u32 st = rp[n], en = rp[n + 1];
    u8* my = h + tid * 96;
    for (u32 e = st; e < en; ++e) {
      u32 q = einfo[e];
      ++my[(q >> 4) & 0x7Fu];
      ++my[65u + (q & 15u)];
    }
  }
  __syncthreads();
  int b0 = blockIdx.x * 256;
  for (int idx = tid; idx < 256 * 96; idx += 256) {
    int nl = idx / 96;
    if (b0 + nl < N_NODES) counts[(size_t)(b0 + nl) * 96 + (idx - nl * 96)] = f2b((float)h[idx]);
  }
}

// ---------------- layer-0 MFMA GEMM: hmid = lrelu(counts@W1p + b1 + onep*self) -----
__global__ __launch_bounds__(256) void k_gemm0h(const u16* __restrict__ counts,
                                                const u16* __restrict__ wpB,
                                                const float* __restrict__ W1p,
                                                const float* __restrict__ P,
                                                const int* __restrict__ ndeg,
                                                const int* __restrict__ nlab,
                                                u16* __restrict__ hmid) {
  int wid = threadIdx.x >> 6, lane = threadIdx.x & 63;
  int m0 = (blockIdx.x * 4 + wid) * 16;
  if (m0 >= N_NODES) return;
  int row = lane & 15, q = lane >> 4;
  float onep = 1.f + P[P_EPS0];
  const u16* ap = counts + (size_t)(m0 + row) * 96 + q * 8;
  const bf16x8* bp = (const bf16x8*)wpB;
  f32x4 acc[8];
#pragma unroll
  for (int nt = 0; nt < 8; ++nt) {
    float b = P[P_B1A + nt * 16 + row];
    acc[nt][0] = b; acc[nt][1] = b; acc[nt][2] = b; acc[nt][3] = b;
  }
#pragma unroll
  for (int kb = 0; kb < 3; ++kb) {
    bf16x8 af = *(const bf16x8*)(ap + kb * 32);
#pragma unroll
    for (int nt = 0; nt < 8; ++nt) {
      bf16x8 bf = bp[(nt * 3 + kb) * 64 + lane];
      acc[nt] = __builtin_amdgcn_mfma_f32_16x16x32_bf16(af, bf, acc[nt], 0, 0, 0);
    }
  }
#pragma unroll
  for (int r = 0; r < 4; ++r) {
    int m = m0 + q * 4 + r;
    const float* wd = W1p + ndeg[m] * 128;
    const float* wl = W1p + (65 + nlab[m]) * 128;
#pragma unroll
    for (int nt = 0; nt < 8; ++nt) {
      int cc = nt * 16 + row;
      float v = acc[nt][r] + onep * (wd[cc] + wl[cc]);
      hmid[(size_t)m * 128 + cc] = f2b(lrelu(v));
    }
  }
}

// ---------------- stats partial reduction (no atomics anywhere) ----------------
__global__ void k_sr1(const float* __restrict__ pbuf, float* __restrict__ p2) {
  int t = threadIdx.x, col = t & 127, half = t >> 7;
  int r0 = blockIdx.x * 2 + half;
  float acc = 0.f;
  for (int s = r0; s < NSLOT; s += 128) acc += pbuf[(size_t)s * 128 + col];
  p2[(size_t)r0 * 128 + col] = acc;
}

__global__ void k_sr2(const float* __restrict__ p2, float* __restrict__ statsOut) {
  int t = threadIdx.x;
  if (t >= 128) return;
  float acc = 0.f;
  for (int r = 0; r < 128; ++r) acc += p2[r * 128 + t];
  statsOut[t] = acc;
}

// ---------------- MFMA GEMM (plain A) + per-slot stats partials ----------------
template <int KB, int LDA, int BIASOFF>
__global__ __launch_bounds__(256) void k_gemm(const u16* __restrict__ A,
                                              const u16* __restrict__ Bp,
                                              const float* __restrict__ P,
                                              float* __restrict__ pbuf,
                                              u16* __restrict__ C) {
  int wid = threadIdx.x >> 6, lane = threadIdx.x & 63;
  int m0 = (blockIdx.x * 4 + wid) * 16;
  bool act = m0 < N_NODES;
  int row = lane & 15, q = lane >> 4;
  float ss[4] = {0.f, 0.f, 0.f, 0.f}, qq[4] = {0.f, 0.f, 0.f, 0.f};
  if (act) {
    const u16* ap = A + (size_t)(m0 + row) * LDA + q * 8;
    const bf16x8* bp = (const bf16x8*)Bp;
    f32x4 acc[4];
#pragma unroll
    for (int nt = 0; nt < 4; ++nt) {
      float b = (BIASOFF >= 0) ? P[BIASOFF + nt * 16 + row] : 0.f;
      acc[nt][0] = b; acc[nt][1] = b; acc[nt][2] = b; acc[nt][3] = b;
    }
#pragma unroll
    for (int kb = 0; kb < KB; ++kb) {
      bf16x8 af = *(const bf16x8*)(ap + kb * 32);
#pragma unroll
      for (int nt = 0; nt < 4; ++nt) {
        bf16x8 bf = bp[(nt * KB + kb) * 64 + lane];
        acc[nt] = __builtin_amdgcn_mfma_f32_16x16x32_bf16(af, bf, acc[nt], 0, 0, 0);
      }
    }
#pragma unroll
    for (int nt = 0; nt < 4; ++nt) {
      float s = 0.f, z = 0.f;
#pragma unroll
      for (int r = 0; r < 4; ++r) {
        int m = m0 + q * 4 + r;
        u16 bv = f2b(acc[nt][r]);
        C[(size_t)m * 64 + nt * 16 + row] = bv;
        float v = b2f(bv);
        s += v; z = fmaf(v, v, z);
      }
      s += __shfl_xor(s, 16, 64); s += __shfl_xor(s, 32, 64);
      z += __shfl_xor(z, 16, 64); z += __shfl_xor(z, 32, 64);
      ss[nt] = s; qq[nt] = z;
    }
  }
  if (lane < 16) {
    float* pb = pbuf + (size_t)(blockIdx.x * 4 + wid) * 128;
#pragma unroll
    for (int nt = 0; nt < 4; ++nt) {
      pb[nt * 16 + lane] = ss[nt];
      pb[64 + nt * 16 + lane] = qq[nt];
    }
  }
}

// ---------------- MFMA GEMM with fused BN+lrelu on A (K=64) -> row-major g1 --------
__global__ __launch_bounds__(256) void k_gemm_bn(const u16* __restrict__ A,
                                                 const u16* __restrict__ Bp,
                                                 const float* __restrict__ P,
                                                 const float* __restrict__ stats,
                                                 u16* __restrict__ C) {
  int wid = threadIdx.x >> 6, lane = threadIdx.x & 63;
  int m0 = (blockIdx.x * 4 + wid) * 16;
  if (m0 >= N_NODES) return;
  int row = lane & 15, q = lane >> 4;
  const float invN = 1.f / (float)N_NODES;
  float sc[16], sh[16];
#pragma unroll
  for (int kb = 0; kb < 2; ++kb)
#pragma unroll
    for (int j = 0; j < 8; ++j) {
      int f = kb * 32 + q * 8 + j;
      float mm = stats[f] * invN;
      float var = fmaxf(stats[64 + f] * invN - mm * mm, 0.f);
      float inv = rsqrtf(var + 1e-5f);
      float s = inv * P[P_G0 + f];
      sc[kb * 8 + j] = s;
      sh[kb * 8 + j] = P[P_BB0 + f] - mm * s;
    }
  const u16* ap = A + (size_t)(m0 + row) * 64 + q * 8;
  const bf16x8* bp = (const bf16x8*)Bp;
  f32x4 acc[4];
#pragma unroll
  for (int nt = 0; nt < 4; ++nt) {
    acc[nt][0] = 0.f; acc[nt][1] = 0.f; acc[nt][2] = 0.f; acc[nt][3] = 0.f;
  }
#pragma unroll
  for (int kb = 0; kb < 2; ++kb) {
    uint4 raw = *(const uint4*)(ap + kb * 32);
    u32 rw[4] = {raw.x, raw.y, raw.z, raw.w};
    bf16x8 af;
#pragma unroll
    for (int p = 0; p < 4; ++p) {
      float lo, hi;
      up2(rw[p], lo, hi);
      float y0 = lrelu(fmaf(sc[kb * 8 + 2 * p], lo, sh[kb * 8 + 2 * p]));
      float y1 = lrelu(fmaf(sc[kb * 8 + 2 * p + 1], hi, sh[kb * 8 + 2 * p + 1]));
      af[2 * p] = (short)f2b(y0);
      af[2 * p + 1] = (short)f2b(y1);
    }
#pragma unroll
    for (int nt = 0; nt < 4; ++nt) {
      bf16x8 bf = bp[(nt * 2 + kb) * 64 + lane];
      acc[nt] = __builtin_amdgcn_mfma_f32_16x16x32_bf16(af, bf, acc[nt], 0, 0, 0);
    }
  }
#pragma unroll
  for (int nt = 0; nt < 4; ++nt)
#pragma unroll
    for (int r = 0; r < 4; ++r) {
      int m = m0 + q * 4 + r;
      C[(size_t)m * 64 + nt * 16 + row] = f2b(acc[nt][r]);
    }
}

// ---------------- layer-1 aggregation: flat gather, 8-deep, 2 acc chains ----------
__global__ __launch_bounds__(256) void k_agg1(const u32* __restrict__ rp,
                                              const u32* __restrict__ einfo,
                                              const u16* __restrict__ g1,
                                              const float* __restrict__ P,
                                              u16* __restrict__ abuf) {
  int lane = threadIdx.x & 63, wv = threadIdx.x >> 6;
  int n = blockIdx.x * 4 + wv;
  if (n >= N_NODES) return;
  u32 st = rp[n], en = rp[n + 1];
  u32 m = en - st;
  float acA = 0.f, acB = 0.f;
  u32 k = 0;
  for (; k + 8 <= m; k += 8) {
    u32 c0 = einfo[st + k] >> 11, c1 = einfo[st + k + 1] >> 11;
    u32 c2 = einfo[st + k + 2] >> 11, c3 = einfo[st + k + 3] >> 11;
    u32 c4 = einfo[st + k + 4] >> 11, c5 = einfo[st + k + 5] >> 11;
    u32 c6 = einfo[st + k + 6] >> 11, c7 = einfo[st + k + 7] >> 11;
    float v0 = b2f(g1[(size_t)c0 * 64 + lane]);
    float v1 = b2f(g1[(size_t)c1 * 64 + lane]);
    float v2 = b2f(g1[(size_t)c2 * 64 + lane]);
    float v3 = b2f(g1[(size_t)c3 * 64 + lane]);
    float v4 = b2f(g1[(size_t)c4 * 64 + lane]);
    float v5 = b2f(g1[(size_t)c5 * 64 + lane]);
    float v6 = b2f(g1[(size_t)c6 * 64 + lane]);
    float v7 = b2f(g1[(size_t)c7 * 64 + lane]);
    acA += (v0 + v1) + (v2 + v3);
    acB += (v4 + v5) + (v6 + v7);
  }
  if (k + 4 <= m) {
    u32 c0 = einfo[st + k] >> 11, c1 = einfo[st + k + 1] >> 11;
    u32 c2 = einfo[st + k + 2] >> 11, c3 = einfo[st + k + 3] >> 11;
    float v0 = b2f(g1[(size_t)c0 * 64 + lane]);
    float v1 = b2f(g1[(size_t)c1 * 64 + lane]);
    float v2 = b2f(g1[(size_t)c2 * 64 + lane]);
    float v3 = b2f(g1[(size_t)c3 * 64 + lane]);
    acA += (v0 + v1) + (v2 + v3);
    k += 4;
  }
  for (; k < m; ++k) acB += b2f(g1[(size_t)(einfo[st + k] >> 11) * 64 + lane]);
  float acc = acA + acB;
  float onep = 1.f + P[P_EPS1];
  float a = P[P_LB1 + lane] + fmaf(onep, b2f(g1[(size_t)n * 64 + lane]), acc);
  abuf[(size_t)n * 64 + lane] = f2b(lrelu(a));
}

// ---------------- fc1 GEMM: A = [BN0(t0) | BN1(t1)] fused, + Efc + stats partials ---
__global__ __launch_bounds__(256) void k_gemm_fc1bn(const u16* __restrict__ t0,
                                                    const u16* __restrict__ t1,
                                                    const u16* __restrict__ Bp,
                                                    const float* __restrict__ P,
                                                    const float* __restrict__ stats,
                                                    float* __restrict__ pbuf,
                                                    const int* __restrict__ ndeg,
                                                    const int* __restrict__ nlab,
                                                    const float* __restrict__ Efc,
                                                    u16* __restrict__ C) {
  int wid = threadIdx.x >> 6, lane = threadIdx.x & 63;
  int m0 = (blockIdx.x * 4 + wid) * 16;
  bool act = m0 < N_NODES;
  int row = lane & 15, q = lane >> 4;
  float ss[4] = {0.f, 0.f, 0.f, 0.f}, qq[4] = {0.f, 0.f, 0.f, 0.f};
  if (act) {
    const float invN = 1.f / (float)N_NODES;
    float sc[32], sh[32];
#pragma unroll
    for (int h = 0; h < 2; ++h) {
      const float* st = stats + h * 128;
      int gof = h ? P_G1 : P_G0, bof = h ? P_BB1 : P_BB0;
#pragma unroll
      for (int kb = 0; kb < 2; ++kb)
#pragma unroll
        for (int j = 0; j < 8; ++j) {
          int f = kb * 32 + q * 8 + j;
          float mm = st[f] * invN;
          float var = fmaxf(st[64 + f] * invN - mm * mm, 0.f);
          float inv = rsqrtf(var + 1e-5f);
          float s = inv * P[gof + f];
          sc[h * 16 + kb * 8 + j] = s;
          sh[h * 16 + kb * 8 + j] = P[bof + f] - mm * s;
        }
    }
    const u16* a0 = t0 + (size_t)(m0 + row) * 64 + q * 8;
    const u16* a1 = t1 + (size_t)(m0 + row) * 64 + q * 8;
    const bf16x8* bp = (const bf16x8*)Bp;
    f32x4 acc[4];
#pragma unroll
    for (int nt = 0; nt < 4; ++nt) {
      float b = P[P_FB1 + nt * 16 + row];
      acc[nt][0] = b; acc[nt][1] = b; acc[nt][2] = b; acc[nt][3] = b;
    }
#pragma unroll
    for (int kb = 0; kb < 4; ++kb) {
      const u16* src = (kb < 2) ? (a0 + kb * 32) : (a1 + (kb - 2) * 32);
      int ci = (kb < 2) ? kb * 8 : 16 + (kb - 2) * 8;
      uint4 raw = *(const uint4*)src;
      u32 rw[4] = {raw.x, raw.y, raw.z, raw.w};
      bf16x8 af;
#pragma unroll
      for (int p = 0; p < 4; ++p) {
        float lo, hi;
        up2(rw[p], lo, hi);
        float y0 = lrelu(fmaf(sc[ci + 2 * p], lo, sh[ci + 2 * p]));
        float y1 = lrelu(fmaf(sc[ci + 2 * p + 1], hi, sh[ci + 2 * p + 1]));
        af[2 * p] = (short)f2b(y0);
        af[2 * p + 1] = (short)f2b(y1);
      }
#pragma unroll
      for (int nt = 0; nt < 4; ++nt) {
        bf16x8 bf = bp[(nt * 4 + kb) * 64 + lane];
        acc[nt] = __builtin_amdgcn_mfma_f32_16x16x32_bf16(af, bf, acc[nt], 0, 0, 0);
      }
    }
    float es[4][4];
#pragma unroll
    for (int r = 0; r < 4; ++r) {
      int m = m0 + q * 4 + r;
      int dn = ndeg[m], ln = 65 + nlab[m];
#pragma unroll
      for (int nt = 0; nt < 4; ++nt) {
        int cc = nt * 16 + row;
        es[r][nt] = acc[nt][r] + Efc[dn * 64 + cc] + Efc[ln * 64 + cc];
      }
    }
#pragma unroll
    for (int nt = 0; nt < 4; ++nt) {
      float s = 0.f, z = 0.f;
#pragma unroll
      for (int r = 0; r < 4; ++r) {
        int m = m0 + q * 4 + r;
        u16 bv = f2b(es[r][nt]);
        C[(size_t)m * 64 + nt * 16 + row] = bv;
        float v = b2f(bv);
        s += v; z = fmaf(v, v, z);
      }
      s += __shfl_xor(s, 16, 64); s += __shfl_xor(s, 32, 64);
      z += __shfl_xor(z, 16, 64); z += __shfl_xor(z, 32, 64);
      ss[nt] = s; qq[nt] = z;
    }
  }
  if (lane < 16) {
    float* pb = pbuf + (size_t)(blockIdx.x * 4 + wid) * 128;
#pragma unroll
    for (int nt = 0; nt < 4; ++nt) {
      pb[nt * 16 + lane] = ss[nt];
      pb[64 + nt * 16 + lane] = qq[nt];
    }
  }
}

// ---------------- FC final: BN + lrelu + dot + sigmoid ----------------
__global__ void k_fc2(const u16* __restrict__ t, const float* __restrict__ stats,
                      const float* __restrict__ P, const u32* __restrict__ flag,
                      void* __restrict__ out) {
  int n = blockIdx.x * blockDim.x + threadIdx.x;
  if (n >= N_NODES) return;
  float z = P[P_FB2];
  const float invN = 1.f / (float)N_NODES;
  const u16* tn = t + (size_t)n * 64;
#pragma unroll 1
  for (int f = 0; f < 64; ++f) {
    float m = stats[f] * invN;
    float var = fmaxf(stats[64 + f] * invN - m * m, 0.f);
    float inv = rsqrtf(var + 1e-5f);
    float y = (b2f(tn[f]) - m) * inv * P[P_FG + f] + P[P_FBB + f];
    y = lrelu(y);
    z = fmaf(y, P[P_FW2 + f], z);
  }
  float s = 1.f / (1.f + expf(-z));
  if (!(fabsf(z) < 1e30f)) s = 0.25f;
  if (*flag) ((float*)out)[n] = s;
  else       ((u16*)out)[n] = f2b(s);
}

extern "C" void kernel_launch(void* const* d_in, const int* in_sizes, int n_in,
                              void* d_out, int out_size, void* d_ws, size_t ws_size,
                              hipStream_t stream) {
  const int* node_deg = (const int*)d_in[0];
  const int* node_lab = (const int*)d_in[1];
  const int* edge     = (const int*)d_in[2];
  (void)in_sizes; (void)n_in; (void)out_size; (void)ws_size;

  char* base = (char*)d_ws;
  size_t off = 0;
  auto alloc = [&](size_t bytes) -> void* {
    void* p = base + off;
    off += (bytes + 15) & ~(size_t)15;
    return p;
  };
  float* Pb    = (float*)alloc((size_t)P_TOT * 4);
  // contiguous zero region: flag | stats | tcnt (one memset)
  u32* flag    = (u32*)alloc(16);
  float* stats = (float*)alloc(384 * 4);
  u32* tcnt    = (u32*)alloc(NBKT * 4);
  float* W1p   = (float*)alloc(NCLS * 128 * 4);
  float* Efc   = (float*)alloc(NCLS * 64 * 4);
  u16* bpack   = (u16*)alloc(24576 * 2);
  u16* wpB     = (u16*)alloc(12288 * 2);
  u32* row_ptr = (u32*)alloc((size_t)(N_NODES + 1) * 4);
  u32* gcur    = (u32*)alloc(NBKT * 4);
  float* pbuf  = (float*)alloc((size_t)NSLOT * 128 * 4);
  float* p2    = (float*)alloc(128 * 128 * 4);
  u32* einfo   = (u32*)alloc((size_t)N_EDGES * 4);
  u64* e2      = (u64*)alloc((size_t)N_EDGES * 8);
  void* arena  = alloc((size_t)N_NODES * 128 * 2);  // hmid; later g1+abuf
  u16* t0      = (u16*)alloc((size_t)N_NODES * 64 * 2);
  u16* t1      = (u16*)alloc((size_t)N_NODES * 64 * 2);
  u16* t2      = (u16*)alloc((size_t)N_NODES * 64 * 2);
  u16* hmid = (u16*)arena;
  u16* g1   = (u16*)arena;                              // [N,64] row-major
  u16* abuf = (u16*)arena + (size_t)N_NODES * 64;       // [N,64] row-major
  u16* counts = t1;  // [N,96] bf16 overlays t1+t2 head; dead before t1/t2 written
  u16* Bp_w2a = bpack;           // 8192
  u16* Bp_lw1 = bpack + 8192;    // 4096
  u16* Bp_lw2 = bpack + 12288;   // 4096
  u16* Bp_fw1 = bpack + 16384;   // 8192

  hipMemsetAsync(flag, 0, 16 + 384 * 4 + NBKT * 4, stream);

  k_detect<<<1, 256, 0, stream>>>((const u16*)d_in[3], flag);

  CvtAll ca;
  const int srcidx[22] = {3, 4, 5, 6, 7, 8, 9, 10, 11, 12, 13, 14, 15, 16, 17, 18, 19, 20, 21, 22, 23, 24};
  const int cnts[22]   = {4160, 1024, 16384, 128, 8192, 64, 1, 64, 64, 4096, 64, 4096, 64, 1, 64, 64, 16384, 64, 64, 64, 64, 1};
  const int offs[22]   = {P_EMBD, P_EMBL, P_W1A, P_B1A, P_W2A, P_B2A, P_EPS0, P_G0, P_BB0,
                          P_LW1, P_LB1, P_LW2, P_LB2, P_EPS1, P_G1, P_BB1,
                          P_FW1, P_FB1, P_FG, P_FBB, P_FW2, P_FB2};
  for (int i = 0; i < 22; ++i) { ca.src[i] = d_in[srcidx[i]]; ca.cnt[i] = cnts[i]; ca.off[i] = offs[i]; }
  k_cvtall<<<dim3(64, 22), 256, 0, stream>>>(ca, flag, Pb);

  k_prep<<<157, 256, 0, stream>>>(Pb, W1p, Efc, bpack);
  k_prep2<<<48, 256, 0, stream>>>(W1p, wpB);

  // edge bucket-sort (dst>>9), then per-bucket CSR (hist+scan+place in one kernel)
  k_bc<<<NCHK, 256, 0, stream>>>(edge, tcnt);
  k_bscan<<<1, 256, 0, stream>>>(tcnt, gcur);
  k_bsort<<<NCHK, 256, 0, stream>>>(edge, node_deg, node_lab, gcur, e2);
  k_csr<<<NBKT, 512, 0, stream>>>(e2, gcur, row_ptr, einfo);

  const int GEMM_GRID = (6250 + 3) / 4;  // 1563 blocks -> NSLOT=6252 wave slots

  // layer 0: histogram -> MFMA GEMM (K=96) -> t0 (stats via partials, no atomics)
  k_hist<<<(N_NODES + 255) / 256, 256, 0, stream>>>(row_ptr, einfo, counts);
  k_gemm0h<<<GEMM_GRID, 256, 0, stream>>>(counts, wpB, W1p, Pb, node_deg, node_lab, hmid);
  k_gemm<4, 128, P_B2A><<<GEMM_GRID, 256, 0, stream>>>(hmid, Bp_w2a, Pb, pbuf, t0);
  k_sr1<<<64, 256, 0, stream>>>(pbuf, p2);
  k_sr2<<<1, 128, 0, stream>>>(p2, stats);

  // layer 1: BN fused into GEMM A-load -> row-major g1; flat gather; GEMM
  k_gemm_bn<<<GEMM_GRID, 256, 0, stream>>>(t0, Bp_lw1, Pb, stats, g1);
  k_agg1<<<(N_NODES + 3) / 4, 256, 0, stream>>>(row_ptr, einfo, g1, Pb, abuf);
  k_gemm<2, 64, P_LB2><<<GEMM_GRID, 256, 0, stream>>>(abuf, Bp_lw2, Pb, pbuf, t1);
  k_sr1<<<64, 256, 0, stream>>>(pbuf, p2);
  k_sr2<<<1, 128, 0, stream>>>(p2, stats + 128);

  // FC head: BN0/BN1 fused into A-load, stats via partials
  k_gemm_fc1bn<<<GEMM_GRID, 256, 0, stream>>>(t0, t1, Bp_fw1, Pb, stats, pbuf,
                                              node_deg, node_lab, Efc, t2);
  k_sr1<<<64, 256, 0, stream>>>(pbuf, p2);
  k_sr2<<<1, 128, 0, stream>>>(p2, stats + 256);
  k_fc2<<<(N_NODES + 255) / 256, 256, 0, stream>>>(t2, stats + 256, Pb, flag, d_out);
}

// Round 16
// 326.703 us; speedup vs baseline: 1.8607x; 1.2272x over previous
//
#include <hip/hip_runtime.h>

#define N_NODES 100000
#define N_EDGES 1200000
#define NCLS 81    // 65 deg classes + 16 lab classes
#define NBKT 196   // dst>>9 buckets (512 nodes each)
#define BCAP 8192  // padded e2 capacity per bucket (mean 6144, +26 sigma)
#define NCHK 293   // ceil(N_EDGES/4096)
#define NGBLK 1563 // GEMM blocks

typedef unsigned short u16;
typedef unsigned char u8;
typedef unsigned int u32;
typedef unsigned long long u64;
typedef short bf16x8 __attribute__((ext_vector_type(8)));
typedef float f32x4 __attribute__((ext_vector_type(4)));

__device__ __forceinline__ float b2f(u16 u) {
  union { u32 i; float f; } v; v.i = ((u32)u) << 16; return v.f;
}
__device__ __forceinline__ u16 f2b(float f) {
  union { float f; u32 i; } v; v.f = f;
  u32 x = v.i;
  return (u16)((x + 0x7fffu + ((x >> 16) & 1u)) >> 16);
}
__device__ __forceinline__ void up2(u32 w, float& lo, float& hi) {
  union { u32 u; float f; } a, b;
  a.u = w << 16; b.u = w & 0xffff0000u;
  lo = a.f; hi = b.f;
}
__device__ __forceinline__ float lrelu(float x) { return x > 0.f ? x : 0.01f * x; }

// per-wave dtype detect: fp32 inputs read as u16 have uniform low-halves ->
// exp-field >= 0x90 with p=.44/even-halfword; 64 of them -> miss ~1e-16.
__device__ __forceinline__ bool is_f32(const u16* emb) {
  int lane = threadIdx.x & 63;
  u32 e0 = (emb[lane * 2] >> 7) & 0xFF;
  u32 e1 = (emb[lane * 2 + 1] >> 7) & 0xFF;
  return __ballot((e0 >= 0x90) || (e1 >= 0x90)) != 0ull;
}

// ---- fp32 param block offsets ----
#define P_EMBD 0       // 4160
#define P_EMBL 4160    // 1024
#define P_W1A  5184    // 16384  l0_w1 (128x128)
#define P_B1A  21568   // 128
#define P_W2A  21696   // 8192   l0_w2 (128x64)
#define P_B2A  29888   // 64
#define P_EPS0 29952   // 1
#define P_G0   29953   // 64
#define P_BB0  30017   // 64
#define P_LW1  30081   // 4096   l1_w1 (64x64)
#define P_LB1  34177   // 64
#define P_LW2  34241   // 4096   l1_w2 (64x64)
#define P_LB2  38337   // 64
#define P_EPS1 38401   // 1
#define P_G1   38402   // 64
#define P_BB1  38466   // 64
#define P_FW1  38530   // 16384  fc_w1 (256x64)
#define P_FB1  54914   // 64
#define P_FG   54978   // 64
#define P_FBB  55042   // 64
#define P_FW2  55106   // 64
#define P_FB2  55170   // 1
#define P_TOT  55171

// ---------------- convert all float params to fp32 block (dtype inline) ------------
struct CvtAll {
  const void* src[22];
  int cnt[22];
  int off[22];
};

__global__ void k_cvtall(CvtAll a, const u16* __restrict__ embRaw, float* __restrict__ P) {
  bool f32m = is_f32(embRaw);
  int seg = blockIdx.y;
  int i = blockIdx.x * 256 + threadIdx.x;
  if (i >= a.cnt[seg]) return;
  float v;
  if (f32m) v = ((const float*)a.src[seg])[i];
  else      v = b2f(((const u16*)a.src[seg])[i]);
  P[a.off[seg] + i] = v;
}

// ---------------- merged preprocessing: W1p, Efc, MFMA B-packs, wpB ----------------
__global__ void k_prep(const float* __restrict__ P, float* __restrict__ W1p,
                       float* __restrict__ Efc, u16* __restrict__ bp,
                       u16* __restrict__ wpB) {
  int idx = blockIdx.x * 256 + threadIdx.x;
  if (idx < NCLS * 128) {
    int c = idx >> 7, h = idx & 127;
    const float* w1 = P + P_W1A;
    float s = 0.f;
    if (c < 65) {
      const float* em = P + P_EMBD + c * 64;
      for (int k = 0; k < 64; ++k) s = fmaf(em[k], w1[k * 128 + h], s);
    } else {
      const float* em = P + P_EMBL + (c - 65) * 64;
      for (int k = 0; k < 64; ++k) s = fmaf(em[k], w1[(64 + k) * 128 + h], s);
    }
    W1p[idx] = s;
    return;
  }
  if (idx < NCLS * 128 + NCLS * 64) {
    int r = idx - NCLS * 128;
    int c = r >> 6, o = r & 63;
    const float* fw = P + P_FW1;
    float s = 0.f;
    if (c < 65) {
      const float* em = P + P_EMBD + c * 64;
      for (int k = 0; k < 64; ++k) s = fmaf(em[k], fw[k * 64 + o], s);
    } else {
      const float* em = P + P_EMBL + (c - 65) * 64;
      for (int k = 0; k < 64; ++k) s = fmaf(em[k], fw[(64 + k) * 64 + o], s);
    }
    Efc[r] = s;
    return;
  }
  if (idx < NCLS * 128 + NCLS * 64 + 24576) {
    int pidx = idx - (NCLS * 128 + NCLS * 64);
    int seg, rel;
    if (pidx < 8192)       { seg = 0; rel = pidx; }
    else if (pidx < 12288) { seg = 1; rel = pidx - 8192; }
    else if (pidx < 16384) { seg = 2; rel = pidx - 12288; }
    else                   { seg = 3; rel = pidx - 16384; }
    const int srcoff[4] = {P_W2A, P_LW1, P_LW2, P_FW1 + 128 * 64};
    const int KBs[4] = {4, 2, 2, 4};
    int j = rel & 7, lane = (rel >> 3) & 63, rest = rel >> 9;
    int kb = rest % KBs[seg], nt = rest / KBs[seg];
    int k = kb * 32 + (lane >> 4) * 8 + j;
    int n = nt * 16 + (lane & 15);
    bp[pidx] = f2b(P[srcoff[seg] + k * 64 + n]);
    return;
  }
  int p2 = idx - (NCLS * 128 + NCLS * 64 + 24576);
  if (p2 >= 12288) return;
  // wpB: K=96 B-frag of W1p (computed straight from P; zero-pad c>=81)
  int j = p2 & 7, lane = (p2 >> 3) & 63, rest = p2 >> 9;  // rest in [0,24)
  int kb = rest % 3, nt = rest / 3;
  int c = kb * 32 + (lane >> 4) * 8 + j;
  int n = nt * 16 + (lane & 15);
  float s = 0.f;
  if (c < NCLS) {
    const float* w1 = P + P_W1A;
    if (c < 65) {
      const float* em = P + P_EMBD + c * 64;
      for (int k = 0; k < 64; ++k) s = fmaf(em[k], w1[k * 128 + n], s);
    } else {
      const float* em = P + P_EMBL + (c - 65) * 64;
      for (int k = 0; k < 64; ++k) s = fmaf(em[k], w1[(64 + k) * 128 + n], s);
    }
  }
  wpB[p2] = (c < NCLS) ? f2b(s) : 0;
}

// ---------------- bucket sort (padded buckets, direct claim — no pre-count) --------
__global__ __launch_bounds__(256) void k_bsort(const int* __restrict__ edge,
                                               const int* __restrict__ ndeg,
                                               const int* __restrict__ nlab,
                                               u32* __restrict__ gcur,
                                               u64* __restrict__ e2) {
  __shared__ u32 cnt[NBKT], rbase[NBKT];
  __shared__ u32 slo[4096], shi[4096];
  for (int i = threadIdx.x; i < NBKT; i += 256) cnt[i] = 0;
  __syncthreads();
  int base = blockIdx.x * 4096;
  for (int i = threadIdx.x; i < 4096; i += 256) {
    int e = base + i;
    if (e < N_EDGES) {
      int s = edge[e], d = edge[N_EDGES + e];
      slo[i] = ((u32)s << 11) | ((u32)ndeg[s] << 4) | (u32)nlab[s];
      shi[i] = (u32)d;
      atomicAdd(&cnt[(u32)d >> 9], 1u);
    } else shi[i] = 0xFFFFFFFFu;
  }
  __syncthreads();
  for (int i = threadIdx.x; i < NBKT; i += 256) {
    u32 c = cnt[i];
    rbase[i] = c ? atomicAdd(&gcur[i], c) : 0u;
    cnt[i] = 0;
  }
  __syncthreads();
  for (int i = threadIdx.x; i < 4096; i += 256) {
    u32 d = shi[i];
    if (d == 0xFFFFFFFFu) continue;
    u32 b = d >> 9;
    u32 pos = rbase[b] + atomicAdd(&cnt[b], 1u);
    e2[(size_t)b * BCAP + pos] = ((u64)d << 32) | (u64)slo[i];
  }
}

// ---------------- per-bucket CSR (bucket base via serial prefix of gcur) -----------
__global__ __launch_bounds__(512) void k_csr(const u64* __restrict__ e2,
                                             const u32* __restrict__ gcur,
                                             u32* __restrict__ row_ptr,
                                             u32* __restrict__ einfo) {
  __shared__ u32 l[512], cur[512], gl[NBKT];
  __shared__ u32 sbase;
  int b = blockIdx.x, tid = threadIdx.x;
  if (tid < NBKT) gl[tid] = gcur[tid];
  __syncthreads();
  if (tid == 0) {
    u32 s = 0;
    for (int i = 0; i < b; ++i) s += gl[i];
    sbase = s;
  }
  l[tid] = 0;
  __syncthreads();
  u32 cnt = gl[b];
  const u64* src = e2 + (size_t)b * BCAP;
  for (u32 e = tid; e < cnt; e += 512)
    atomicAdd(&l[(u32)(src[e] >> 32) & 511u], 1u);
  __syncthreads();
  u32 v = l[tid];
  for (int off = 1; off < 512; off <<= 1) {
    u32 a = (tid >= off) ? l[tid - off] : 0u;
    __syncthreads();
    l[tid] += a;
    __syncthreads();
  }
  u32 pos0 = sbase + l[tid] - v;
  cur[tid] = pos0;
  int n = b * 512 + tid;
  if (n <= N_NODES) row_ptr[n] = pos0;
  __syncthreads();
  for (u32 e = tid; e < cnt; e += 512) {
    u64 r = src[e];
    u32 pos = atomicAdd(&cur[(u32)(r >> 32) & 511u], 1u);
    einfo[pos] = (u32)r;
  }
}

// ---------------- fused layer-0: LDS histograms + MFMA (K=96) -> hmid --------------
__global__ __launch_bounds__(256) void k_histgemm0(const u32* __restrict__ rp,
                                                   const u32* __restrict__ einfo,
                                                   const u16* __restrict__ wpB,
                                                   const float* __restrict__ W1p,
                                                   const float* __restrict__ P,
                                                   const int* __restrict__ ndeg,
                                                   const int* __restrict__ nlab,
                                                   u16* __restrict__ hmid) {
  __shared__ u8 h[256 * 96];  // 24576 B; row t = node blockIdx.x*256+t
  int tid = threadIdx.x;
  u32* hw = (u32*)h;
#pragma unroll
  for (int i = 0; i < 24; ++i) hw[tid * 24 + i] = 0;
  __syncthreads();
  int n = blockIdx.x * 256 + tid;
  if (n < N_NODES) {
    u32 st = rp[n], en = rp[n + 1];
    u8* my = h + tid * 96;
    for (u32 e = st; e < en; ++e) {
      u32 q = einfo[e];
      ++my[(q >> 4) & 0x7Fu];
      ++my[65u + (q & 15u)];
    }
  }
  __syncthreads();
  int wid = tid >> 6, lane = tid & 63;
  int row = lane & 15, q = lane >> 4;
  float onep = 1.f + P[P_EPS0];
  const bf16x8* bp = (const bf16x8*)wpB;
#pragma unroll 1
  for (int t = wid; t < 16; t += 4) {
    int m0 = blockIdx.x * 256 + t * 16;
    if (m0 >= N_NODES) break;
    f32x4 acc[8];
#pragma unroll
    for (int nt = 0; nt < 8; ++nt) {
      float b = P[P_B1A + nt * 16 + row];
      acc[nt][0] = b; acc[nt][1] = b; acc[nt][2] = b; acc[nt][3] = b;
    }
    const u8* ar = h + (t * 16 + row) * 96 + q * 8;
#pragma unroll
    for (int kb = 0; kb < 3; ++kb) {
      bf16x8 af;
#pragma unroll
      for (int j = 0; j < 8; ++j) af[j] = (short)f2b((float)ar[kb * 32 + j]);
#pragma unroll
      for (int nt = 0; nt < 8; ++nt) {
        bf16x8 bf = bp[(nt * 3 + kb) * 64 + lane];
        acc[nt] = __builtin_amdgcn_mfma_f32_16x16x32_bf16(af, bf, acc[nt], 0, 0, 0);
      }
    }
#pragma unroll
    for (int r = 0; r < 4; ++r) {
      int m = m0 + q * 4 + r;
      if (m >= N_NODES) continue;
      const float* wd = W1p + ndeg[m] * 128;
      const float* wl = W1p + (65 + nlab[m]) * 128;
#pragma unroll
      for (int nt = 0; nt < 8; ++nt) {
        int cc = nt * 16 + row;
        float v = acc[nt][r] + onep * (wd[cc] + wl[cc]);
        hmid[(size_t)m * 128 + cc] = f2b(lrelu(v));
      }
    }
  }
}

// ---------------- single-stage stats reduction: pbuf[NGBLK][128] -> stats ----------
__global__ void k_sr(const float* __restrict__ pbuf, float* __restrict__ statsOut) {
  __shared__ float l[256];
  int c = blockIdx.x;
  float s = 0.f;
  for (int r = threadIdx.x; r < NGBLK; r += 256) s += pbuf[(size_t)r * 128 + c];
  l[threadIdx.x] = s;
  __syncthreads();
  for (int off = 128; off > 0; off >>= 1) {
    if (threadIdx.x < off) l[threadIdx.x] += l[threadIdx.x + off];
    __syncthreads();
  }
  if (threadIdx.x == 0) statsOut[c] = l[0];
}

// ---------------- MFMA GEMM (plain A) + block-level stats partials ----------------
template <int KB, int LDA, int BIASOFF>
__global__ __launch_bounds__(256) void k_gemm(const u16* __restrict__ A,
                                              const u16* __restrict__ Bp,
                                              const float* __restrict__ P,
                                              float* __restrict__ pbuf,
                                              u16* __restrict__ C) {
  __shared__ float lsum[4][64], lsq[4][64];
  int wid = threadIdx.x >> 6, lane = threadIdx.x & 63;
  int m0 = (blockIdx.x * 4 + wid) * 16;
  bool act = m0 < N_NODES;
  int row = lane & 15, q = lane >> 4;
  float ss[4] = {0.f, 0.f, 0.f, 0.f}, qq[4] = {0.f, 0.f, 0.f, 0.f};
  if (act) {
    const u16* ap = A + (size_t)(m0 + row) * LDA + q * 8;
    const bf16x8* bp = (const bf16x8*)Bp;
    f32x4 acc[4];
#pragma unroll
    for (int nt = 0; nt < 4; ++nt) {
      float b = (BIASOFF >= 0) ? P[BIASOFF + nt * 16 + row] : 0.f;
      acc[nt][0] = b; acc[nt][1] = b; acc[nt][2] = b; acc[nt][3] = b;
    }
#pragma unroll
    for (int kb = 0; kb < KB; ++kb) {
      bf16x8 af = *(const bf16x8*)(ap + kb * 32);
#pragma unroll
      for (int nt = 0; nt < 4; ++nt) {
        bf16x8 bf = bp[(nt * KB + kb) * 64 + lane];
        acc[nt] = __builtin_amdgcn_mfma_f32_16x16x32_bf16(af, bf, acc[nt], 0, 0, 0);
      }
    }
#pragma unroll
    for (int nt = 0; nt < 4; ++nt) {
      float s = 0.f, z = 0.f;
#pragma unroll
      for (int r = 0; r < 4; ++r) {
        int m = m0 + q * 4 + r;
        u16 bv = f2b(acc[nt][r]);
        C[(size_t)m * 64 + nt * 16 + row] = bv;
        float v = b2f(bv);
        s += v; z = fmaf(v, v, z);
      }
      s += __shfl_xor(s, 16, 64); s += __shfl_xor(s, 32, 64);
      z += __shfl_xor(z, 16, 64); z += __shfl_xor(z, 32, 64);
      ss[nt] = s; qq[nt] = z;
    }
  }
  if (lane < 16) {
#pragma unroll
    for (int nt = 0; nt < 4; ++nt) {
      lsum[wid][nt * 16 + lane] = ss[nt];
      lsq[wid][nt * 16 + lane] = qq[nt];
    }
  }
  __syncthreads();
  int t = threadIdx.x;
  if (t < 64)
    pbuf[(size_t)blockIdx.x * 128 + t] = lsum[0][t] + lsum[1][t] + lsum[2][t] + lsum[3][t];
  else if (t < 128) {
    int c = t - 64;
    pbuf[(size_t)blockIdx.x * 128 + t] = lsq[0][c] + lsq[1][c] + lsq[2][c] + lsq[3][c];
  }
}

// ---------------- MFMA GEMM with fused BN+lrelu on A (K=64) -> row-major g1 --------
__global__ __launch_bounds__(256) void k_gemm_bn(const u16* __restrict__ A,
                                                 const u16* __restrict__ Bp,
                                                 const float* __restrict__ P,
                                                 const float* __restrict__ stats,
                                                 u16* __restrict__ C) {
  int wid = threadIdx.x >> 6, lane = threadIdx.x & 63;
  int m0 = (blockIdx.x * 4 + wid) * 16;
  if (m0 >= N_NODES) return;
  int row = lane & 15, q = lane >> 4;
  const float invN = 1.f / (float)N_NODES;
  float sc[16], sh[16];
#pragma unroll
  for (int kb = 0; kb < 2; ++kb)
#pragma unroll
    for (int j = 0; j < 8; ++j) {
      int f = kb * 32 + q * 8 + j;
      float mm = stats[f] * invN;
      float var = fmaxf(stats[64 + f] * invN - mm * mm, 0.f);
      float inv = rsqrtf(var + 1e-5f);
      float s = inv * P[P_G0 + f];
      sc[kb * 8 + j] = s;
      sh[kb * 8 + j] = P[P_BB0 + f] - mm * s;
    }
  const u16* ap = A + (size_t)(m0 + row) * 64 + q * 8;
  const bf16x8* bp = (const bf16x8*)Bp;
  f32x4 acc[4];
#pragma unroll
  for (int nt = 0; nt < 4; ++nt) {
    acc[nt][0] = 0.f; acc[nt][1] = 0.f; acc[nt][2] = 0.f; acc[nt][3] = 0.f;
  }
#pragma unroll
  for (int kb = 0; kb < 2; ++kb) {
    uint4 raw = *(const uint4*)(ap + kb * 32);
    u32 rw[4] = {raw.x, raw.y, raw.z, raw.w};
    bf16x8 af;
#pragma unroll
    for (int p = 0; p < 4; ++p) {
      float lo, hi;
      up2(rw[p], lo, hi);
      float y0 = lrelu(fmaf(sc[kb * 8 + 2 * p], lo, sh[kb * 8 + 2 * p]));
      float y1 = lrelu(fmaf(sc[kb * 8 + 2 * p + 1], hi, sh[kb * 8 + 2 * p + 1]));
      af[2 * p] = (short)f2b(y0);
      af[2 * p + 1] = (short)f2b(y1);
    }
#pragma unroll
    for (int nt = 0; nt < 4; ++nt) {
      bf16x8 bf = bp[(nt * 2 + kb) * 64 + lane];
      acc[nt] = __builtin_amdgcn_mfma_f32_16x16x32_bf16(af, bf, acc[nt], 0, 0, 0);
    }
  }
#pragma unroll
  for (int nt = 0; nt < 4; ++nt)
#pragma unroll
    for (int r = 0; r < 4; ++r) {
      int m = m0 + q * 4 + r;
      C[(size_t)m * 64 + nt * 16 + row] = f2b(acc[nt][r]);
    }
}

// ---------------- layer-1 aggregation: flat gather, 8-deep, 2 acc chains ----------
__global__ __launch_bounds__(256) void k_agg1(const u32* __restrict__ rp,
                                              const u32* __restrict__ einfo,
                                              const u16* __restrict__ g1,
                                              const float* __restrict__ P,
                                              u16* __restrict__ abuf) {
  int lane = threadIdx.x & 63, wv = threadIdx.x >> 6;
  int n = blockIdx.x * 4 + wv;
  if (n >= N_NODES) return;
  u32 st = rp[n], en = rp[n + 1];
  u32 m = en - st;
  float acA = 0.f, acB = 0.f;
  u32 k = 0;
  for (; k + 8 <= m; k += 8) {
    u32 c0 = einfo[st + k] >> 11, c1 = einfo[st + k + 1] >> 11;
    u32 c2 = einfo[st + k + 2] >> 11, c3 = einfo[st + k + 3] >> 11;
    u32 c4 = einfo[st + k + 4] >> 11, c5 = einfo[st + k + 5] >> 11;
    u32 c6 = einfo[st + k + 6] >> 11, c7 = einfo[st + k + 7] >> 11;
    float v0 = b2f(g1[(size_t)c0 * 64 + lane]);
    float v1 = b2f(g1[(size_t)c1 * 64 + lane]);
    float v2 = b2f(g1[(size_t)c2 * 64 + lane]);
    float v3 = b2f(g1[(size_t)c3 * 64 + lane]);
    float v4 = b2f(g1[(size_t)c4 * 64 + lane]);
    float v5 = b2f(g1[(size_t)c5 * 64 + lane]);
    float v6 = b2f(g1[(size_t)c6 * 64 + lane]);
    float v7 = b2f(g1[(size_t)c7 * 64 + lane]);
    acA += (v0 + v1) + (v2 + v3);
    acB += (v4 + v5) + (v6 + v7);
  }
  if (k + 4 <= m) {
    u32 c0 = einfo[st + k] >> 11, c1 = einfo[st + k + 1] >> 11;
    u32 c2 = einfo[st + k + 2] >> 11, c3 = einfo[st + k + 3] >> 11;
    float v0 = b2f(g1[(size_t)c0 * 64 + lane]);
    float v1 = b2f(g1[(size_t)c1 * 64 + lane]);
    float v2 = b2f(g1[(size_t)c2 * 64 + lane]);
    float v3 = b2f(g1[(size_t)c3 * 64 + lane]);
    acA += (v0 + v1) + (v2 + v3);
    k += 4;
  }
  for (; k < m; ++k) acB += b2f(g1[(size_t)(einfo[st + k] >> 11) * 64 + lane]);
  float acc = acA + acB;
  float onep = 1.f + P[P_EPS1];
  float a = P[P_LB1 + lane] + fmaf(onep, b2f(g1[(size_t)n * 64 + lane]), acc);
  abuf[(size_t)n * 64 + lane] = f2b(lrelu(a));
}

// ---------------- fc1 GEMM: A = [BN0(t0) | BN1(t1)] fused + Efc + block partials ---
__global__ __launch_bounds__(256) void k_gemm_fc1bn(const u16* __restrict__ t0,
                                                    const u16* __restrict__ t1,
                                                    const u16* __restrict__ Bp,
                                                    const float* __restrict__ P,
                                                    const float* __restrict__ stats,
                                                    float* __restrict__ pbuf,
                                                    const int* __restrict__ ndeg,
                                                    const int* __restrict__ nlab,
                                                    const float* __restrict__ Efc,
                                                    u16* __restrict__ C) {
  __shared__ float lsum[4][64], lsq[4][64];
  int wid = threadIdx.x >> 6, lane = threadIdx.x & 63;
  int m0 = (blockIdx.x * 4 + wid) * 16;
  bool act = m0 < N_NODES;
  int row = lane & 15, q = lane >> 4;
  float ss[4] = {0.f, 0.f, 0.f, 0.f}, qq[4] = {0.f, 0.f, 0.f, 0.f};
  if (act) {
    const float invN = 1.f / (float)N_NODES;
    float sc[32], sh[32];
#pragma unroll
    for (int h = 0; h < 2; ++h) {
      const float* st = stats + h * 128;
      int gof = h ? P_G1 : P_G0, bof = h ? P_BB1 : P_BB0;
#pragma unroll
      for (int kb = 0; kb < 2; ++kb)
#pragma unroll
        for (int j = 0; j < 8; ++j) {
          int f = kb * 32 + q * 8 + j;
          float mm = st[f] * invN;
          float var = fmaxf(st[64 + f] * invN - mm * mm, 0.f);
          float inv = rsqrtf(var + 1e-5f);
          float s = inv * P[gof + f];
          sc[h * 16 + kb * 8 + j] = s;
          sh[h * 16 + kb * 8 + j] = P[bof + f] - mm * s;
        }
    }
    const u16* a0 = t0 + (size_t)(m0 + row) * 64 + q * 8;
    const u16* a1 = t1 + (size_t)(m0 + row) * 64 + q * 8;
    const bf16x8* bp = (const bf16x8*)Bp;
    f32x4 acc[4];
#pragma unroll
    for (int nt = 0; nt < 4; ++nt) {
      float b = P[P_FB1 + nt * 16 + row];
      acc[nt][0] = b; acc[nt][1] = b; acc[nt][2] = b; acc[nt][3] = b;
    }
#pragma unroll
    for (int kb = 0; kb < 4; ++kb) {
      const u16* src = (kb < 2) ? (a0 + kb * 32) : (a1 + (kb - 2) * 32);
      int ci = (kb < 2) ? kb * 8 : 16 + (kb - 2) * 8;
      uint4 raw = *(const uint4*)src;
      u32 rw[4] = {raw.x, raw.y, raw.z, raw.w};
      bf16x8 af;
#pragma unroll
      for (int p = 0; p < 4; ++p) {
        float lo, hi;
        up2(rw[p], lo, hi);
        float y0 = lrelu(fmaf(sc[ci + 2 * p], lo, sh[ci + 2 * p]));
        float y1 = lrelu(fmaf(sc[ci + 2 * p + 1], hi, sh[ci + 2 * p + 1]));
        af[2 * p] = (short)f2b(y0);
        af[2 * p + 1] = (short)f2b(y1);
      }
#pragma unroll
      for (int nt = 0; nt < 4; ++nt) {
        bf16x8 bf = bp[(nt * 4 + kb) * 64 + lane];
        acc[nt] = __builtin_amdgcn_mfma_f32_16x16x32_bf16(af, bf, acc[nt], 0, 0, 0);
      }
    }
    float es[4][4];
#pragma unroll
    for (int r = 0; r < 4; ++r) {
      int m = m0 + q * 4 + r;
      int dn = ndeg[m], ln = 65 + nlab[m];
#pragma unroll
      for (int nt = 0; nt < 4; ++nt) {
        int cc = nt * 16 + row;
        es[r][nt] = acc[nt][r] + Efc[dn * 64 + cc] + Efc[ln * 64 + cc];
      }
    }
#pragma unroll
    for (int nt = 0; nt < 4; ++nt) {
      float s = 0.f, z = 0.f;
#pragma unroll
      for (int r = 0; r < 4; ++r) {
        int m = m0 + q * 4 + r;
        u16 bv = f2b(es[r][nt]);
        C[(size_t)m * 64 + nt * 16 + row] = bv;
        float v = b2f(bv);
        s += v; z = fmaf(v, v, z);
      }
      s += __shfl_xor(s, 16, 64); s += __shfl_xor(s, 32, 64);
      z += __shfl_xor(z, 16, 64); z += __shfl_xor(z, 32, 64);
      ss[nt] = s; qq[nt] = z;
    }
  }
  if (lane < 16) {
#pragma unroll
    for (int nt = 0; nt < 4; ++nt) {
      lsum[wid][nt * 16 + lane] = ss[nt];
      lsq[wid][nt * 16 + lane] = qq[nt];
    }
  }
  __syncthreads();
  int t = threadIdx.x;
  if (t < 64)
    pbuf[(size_t)blockIdx.x * 128 + t] = lsum[0][t] + lsum[1][t] + lsum[2][t] + lsum[3][t];
  else if (t < 128) {
    int c = t - 64;
    pbuf[(size_t)blockIdx.x * 128 + t] = lsq[0][c] + lsq[1][c] + lsq[2][c] + lsq[3][c];
  }
}

// ---------------- FC final: BN + lrelu + dot + sigmoid (dtype inline) --------------
__global__ void k_fc2(const u16* __restrict__ t, const float* __restrict__ stats,
                      const float* __restrict__ P, const u16* __restrict__ embRaw,
                      void* __restrict__ out) {
  bool f32m = is_f32(embRaw);
  int n = blockIdx.x * blockDim.x + threadIdx.x;
  if (n >= N_NODES) return;
  float z = P[P_FB2];
  const float invN = 1.f / (float)N_NODES;
  const u16* tn = t + (size_t)n * 64;
#pragma unroll 1
  for (int f = 0; f < 64; ++f) {
    float m = stats[f] * invN;
    float var = fmaxf(stats[64 + f] * invN - m * m, 0.f);
    float inv = rsqrtf(var + 1e-5f);
    float y = (b2f(tn[f]) - m) * inv * P[P_FG + f] + P[P_FBB + f];
    y = lrelu(y);
    z = fmaf(y, P[P_FW2 + f], z);
  }
  float s = 1.f / (1.f + expf(-z));
  if (!(fabsf(z) < 1e30f)) s = 0.25f;
  if (f32m) ((float*)out)[n] = s;
  else      ((u16*)out)[n] = f2b(s);
}

extern "C" void kernel_launch(void* const* d_in, const int* in_sizes, int n_in,
                              void* d_out, int out_size, void* d_ws, size_t ws_size,
                              hipStream_t stream) {
  const int* node_deg = (const int*)d_in[0];
  const int* node_lab = (const int*)d_in[1];
  const int* edge     = (const int*)d_in[2];
  const u16* embRaw   = (const u16*)d_in[3];
  (void)in_sizes; (void)n_in; (void)out_size; (void)ws_size;

  char* base = (char*)d_ws;
  size_t off = 0;
  auto alloc = [&](size_t bytes) -> void* {
    void* p = base + off;
    off += (bytes + 15) & ~(size_t)15;
    return p;
  };
  float* Pb    = (float*)alloc((size_t)P_TOT * 4);
  // contiguous zero region: stats | gcur (one memset)
  float* stats = (float*)alloc(384 * 4);
  u32* gcur    = (u32*)alloc(NBKT * 4);
  float* W1p   = (float*)alloc(NCLS * 128 * 4);
  float* Efc   = (float*)alloc(NCLS * 64 * 4);
  u16* bpack   = (u16*)alloc(24576 * 2);
  u16* wpB     = (u16*)alloc(12288 * 2);
  u32* row_ptr = (u32*)alloc((size_t)(N_NODES + 1) * 4);
  float* pbuf  = (float*)alloc((size_t)NGBLK * 128 * 4);
  u32* einfo   = (u32*)alloc((size_t)N_EDGES * 4);
  u64* e2      = (u64*)alloc((size_t)NBKT * BCAP * 8);  // padded buckets, 12.8 MB
  void* arena  = alloc((size_t)N_NODES * 128 * 2);  // hmid; later g1+abuf
  u16* t0      = (u16*)alloc((size_t)N_NODES * 64 * 2);
  u16* t1      = (u16*)alloc((size_t)N_NODES * 64 * 2);
  u16* t2      = (u16*)alloc((size_t)N_NODES * 64 * 2);
  u16* hmid = (u16*)arena;
  u16* g1   = (u16*)arena;                              // [N,64] row-major
  u16* abuf = (u16*)arena + (size_t)N_NODES * 64;       // [N,64] row-major
  u16* Bp_w2a = bpack;           // 8192
  u16* Bp_lw1 = bpack + 8192;    // 4096
  u16* Bp_lw2 = bpack + 12288;   // 4096
  u16* Bp_fw1 = bpack + 16384;   // 8192

  hipMemsetAsync(stats, 0, 384 * 4 + NBKT * 4, stream);

  CvtAll ca;
  const int srcidx[22] = {3, 4, 5, 6, 7, 8, 9, 10, 11, 12, 13, 14, 15, 16, 17, 18, 19, 20, 21, 22, 23, 24};
  const int cnts[22]   = {4160, 1024, 16384, 128, 8192, 64, 1, 64, 64, 4096, 64, 4096, 64, 1, 64, 64, 16384, 64, 64, 64, 64, 1};
  const int offs[22]   = {P_EMBD, P_EMBL, P_W1A, P_B1A, P_W2A, P_B2A, P_EPS0, P_G0, P_BB0,
                          P_LW1, P_LB1, P_LW2, P_LB2, P_EPS1, P_G1, P_BB1,
                          P_FW1, P_FB1, P_FG, P_FBB, P_FW2, P_FB2};
  for (int i = 0; i < 22; ++i) { ca.src[i] = d_in[srcidx[i]]; ca.cnt[i] = cnts[i]; ca.off[i] = offs[i]; }
  k_cvtall<<<dim3(64, 22), 256, 0, stream>>>(ca, embRaw, Pb);

  k_prep<<<205, 256, 0, stream>>>(Pb, W1p, Efc, bpack, wpB);

  // bucket sort into padded buckets (no pre-count), then per-bucket CSR
  k_bsort<<<NCHK, 256, 0, stream>>>(edge, node_deg, node_lab, gcur, e2);
  k_csr<<<NBKT, 512, 0, stream>>>(e2, gcur, row_ptr, einfo);

  const int GEMM_GRID = NGBLK;

  // layer 0: fused hist+MFMA(K=96) -> hmid; then GEMM -> t0 (+block stats partials)
  k_histgemm0<<<(N_NODES + 255) / 256, 256, 0, stream>>>(row_ptr, einfo, wpB, W1p, Pb,
                                                         node_deg, node_lab, hmid);
  k_gemm<4, 128, P_B2A><<<GEMM_GRID, 256, 0, stream>>>(hmid, Bp_w2a, Pb, pbuf, t0);
  k_sr<<<128, 256, 0, stream>>>(pbuf, stats);

  // layer 1: BN fused into GEMM A-load -> g1; flat gather; GEMM -> t1
  k_gemm_bn<<<GEMM_GRID, 256, 0, stream>>>(t0, Bp_lw1, Pb, stats, g1);
  k_agg1<<<(N_NODES + 3) / 4, 256, 0, stream>>>(row_ptr, einfo, g1, Pb, abuf);
  k_gemm<2, 64, P_LB2><<<GEMM_GRID, 256, 0, stream>>>(abuf, Bp_lw2, Pb, pbuf, t1);
  k_sr<<<128, 256, 0, stream>>>(pbuf, stats + 128);

  // FC head
  k_gemm_fc1bn<<<GEMM_GRID, 256, 0, stream>>>(t0, t1, Bp_fw1, Pb, stats, pbuf,
                                              node_deg, node_lab, Efc, t2);
  k_sr<<<128, 256, 0, stream>>>(pbuf, stats + 256);
  k_fc2<<<(N_NODES + 255) / 256, 256, 0, stream>>>(t2, stats + 256, Pb, embRaw, d_out);
}

// Round 17
// 323.546 us; speedup vs baseline: 1.8789x; 1.0098x over previous
//
#include <hip/hip_runtime.h>

#define N_NODES 100000
#define N_EDGES 1200000
#define NCLS 81    // 65 deg classes + 16 lab classes
#define NBKT 196   // dst>>9 buckets (512 nodes each)
#define BCAP 8192  // padded e2 capacity per bucket (mean 6144, +26 sigma)
#define NCHK 293   // ceil(N_EDGES/4096)
#define NGBLK 1563 // GEMM blocks

typedef unsigned short u16;
typedef unsigned char u8;
typedef unsigned int u32;
typedef unsigned long long u64;
typedef short bf16x8 __attribute__((ext_vector_type(8)));
typedef float f32x4 __attribute__((ext_vector_type(4)));

__device__ __forceinline__ float b2f(u16 u) {
  union { u32 i; float f; } v; v.i = ((u32)u) << 16; return v.f;
}
__device__ __forceinline__ u16 f2b(float f) {
  union { float f; u32 i; } v; v.f = f;
  u32 x = v.i;
  return (u16)((x + 0x7fffu + ((x >> 16) & 1u)) >> 16);
}
__device__ __forceinline__ void up2(u32 w, float& lo, float& hi) {
  union { u32 u; float f; } a, b;
  a.u = w << 16; b.u = w & 0xffff0000u;
  lo = a.f; hi = b.f;
}
__device__ __forceinline__ float lrelu(float x) { return x > 0.f ? x : 0.01f * x; }

// per-wave dtype detect: fp32 inputs read as u16 have uniform low-halves ->
// exp-field >= 0x90 with p=.44/even-halfword; 64 of them -> miss ~1e-16.
__device__ __forceinline__ bool is_f32(const u16* emb) {
  int lane = threadIdx.x & 63;
  u32 e0 = (emb[lane * 2] >> 7) & 0xFF;
  u32 e1 = (emb[lane * 2 + 1] >> 7) & 0xFF;
  return __ballot((e0 >= 0x90) || (e1 >= 0x90)) != 0ull;
}

// raw param read with dtype branch (f32m is wave-uniform; compiler hoists)
__device__ __forceinline__ float rdr(const void* p, int i, bool f32m) {
  return f32m ? ((const float*)p)[i] : b2f(((const u16*)p)[i]);
}

// ---- fp32 param block offsets ----
#define P_EMBD 0       // 4160
#define P_EMBL 4160    // 1024
#define P_W1A  5184    // 16384  l0_w1 (128x128)
#define P_B1A  21568   // 128
#define P_W2A  21696   // 8192   l0_w2 (128x64)
#define P_B2A  29888   // 64
#define P_EPS0 29952   // 1
#define P_G0   29953   // 64
#define P_BB0  30017   // 64
#define P_LW1  30081   // 4096   l1_w1 (64x64)
#define P_LB1  34177   // 64
#define P_LW2  34241   // 4096   l1_w2 (64x64)
#define P_LB2  38337   // 64
#define P_EPS1 38401   // 1
#define P_G1   38402   // 64
#define P_BB1  38466   // 64
#define P_FW1  38530   // 16384  fc_w1 (256x64)
#define P_FB1  54914   // 64
#define P_FG   54978   // 64
#define P_FBB  55042   // 64
#define P_FW2  55106   // 64
#define P_FB2  55170   // 1
#define P_TOT  55171

// ---------------- merged init: param convert + all preprocessing + zeroing ---------
struct CvtAll {
  const void* src[22];
  int cnt[22];
  int off[22];
};

struct RawPtrs {
  const void* embD;  // d_in[3]
  const void* embL;  // d_in[4]
  const void* w1r;   // d_in[5]  l0_w1 (128x128)
  const void* w2r;   // d_in[7]  l0_w2 (128x64)
  const void* lw1r;  // d_in[12] l1_w1
  const void* lw2r;  // d_in[14] l1_w2
  const void* fwr;   // d_in[19] fc_w1 (256x64)
};

__global__ void k_init(CvtAll a, RawPtrs rw, const u16* __restrict__ embRaw,
                       float* __restrict__ P, float* __restrict__ W1p,
                       float* __restrict__ Efc, u16* __restrict__ bp,
                       u16* __restrict__ wpB, u32* __restrict__ gcur) {
  bool f32m = is_f32(embRaw);
  int tid = threadIdx.x;
  if (blockIdx.y < 22) {
    if (blockIdx.y == 0 && blockIdx.x == 0 && tid < NBKT) gcur[tid] = 0;
    int seg = blockIdx.y;
    int i = blockIdx.x * 256 + tid;
    if (i < a.cnt[seg]) {
      float v = f32m ? ((const float*)a.src[seg])[i] : b2f(((const u16*)a.src[seg])[i]);
      P[a.off[seg] + i] = v;
    }
    return;
  }
  // prep-from-raw: idx in [0, 52416)
  int idx = blockIdx.x * 256 + tid;
  if (idx < NCLS * 128) {
    int c = idx >> 7, h = idx & 127;
    float s = 0.f;
    if (c < 65) {
      for (int k = 0; k < 64; ++k)
        s = fmaf(rdr(rw.embD, c * 64 + k, f32m), rdr(rw.w1r, k * 128 + h, f32m), s);
    } else {
      for (int k = 0; k < 64; ++k)
        s = fmaf(rdr(rw.embL, (c - 65) * 64 + k, f32m), rdr(rw.w1r, (64 + k) * 128 + h, f32m), s);
    }
    W1p[idx] = s;
    return;
  }
  if (idx < NCLS * 128 + NCLS * 64) {
    int r = idx - NCLS * 128;
    int c = r >> 6, o = r & 63;
    float s = 0.f;
    if (c < 65) {
      for (int k = 0; k < 64; ++k)
        s = fmaf(rdr(rw.embD, c * 64 + k, f32m), rdr(rw.fwr, k * 64 + o, f32m), s);
    } else {
      for (int k = 0; k < 64; ++k)
        s = fmaf(rdr(rw.embL, (c - 65) * 64 + k, f32m), rdr(rw.fwr, (64 + k) * 64 + o, f32m), s);
    }
    Efc[r] = s;
    return;
  }
  if (idx < NCLS * 128 + NCLS * 64 + 24576) {
    int pidx = idx - (NCLS * 128 + NCLS * 64);
    int seg, rel;
    if (pidx < 8192)       { seg = 0; rel = pidx; }
    else if (pidx < 12288) { seg = 1; rel = pidx - 8192; }
    else if (pidx < 16384) { seg = 2; rel = pidx - 12288; }
    else                   { seg = 3; rel = pidx - 16384; }
    const void* srcs[4] = {rw.w2r, rw.lw1r, rw.lw2r, rw.fwr};
    const int addoff[4] = {0, 0, 0, 128 * 64};
    const int KBs[4] = {4, 2, 2, 4};
    int j = rel & 7, lane = (rel >> 3) & 63, rest = rel >> 9;
    int kb = rest % KBs[seg], nt = rest / KBs[seg];
    int k = kb * 32 + (lane >> 4) * 8 + j;
    int n = nt * 16 + (lane & 15);
    bp[pidx] = f2b(rdr(srcs[seg], addoff[seg] + k * 64 + n, f32m));
    return;
  }
  int p2 = idx - (NCLS * 128 + NCLS * 64 + 24576);
  if (p2 >= 12288) return;
  // wpB: K=96 B-frag of W1p (zero-pad c>=81)
  int j = p2 & 7, lane = (p2 >> 3) & 63, rest = p2 >> 9;  // rest in [0,24)
  int kb = rest % 3, nt = rest / 3;
  int c = kb * 32 + (lane >> 4) * 8 + j;
  int n = nt * 16 + (lane & 15);
  float s = 0.f;
  if (c < NCLS) {
    if (c < 65) {
      for (int k = 0; k < 64; ++k)
        s = fmaf(rdr(rw.embD, c * 64 + k, f32m), rdr(rw.w1r, k * 128 + n, f32m), s);
    } else {
      for (int k = 0; k < 64; ++k)
        s = fmaf(rdr(rw.embL, (c - 65) * 64 + k, f32m), rdr(rw.w1r, (64 + k) * 128 + n, f32m), s);
    }
  }
  wpB[p2] = (c < NCLS) ? f2b(s) : 0;
}

// ---------------- bucket sort (padded buckets, direct claim — no pre-count) --------
__global__ __launch_bounds__(256) void k_bsort(const int* __restrict__ edge,
                                               const int* __restrict__ ndeg,
                                               const int* __restrict__ nlab,
                                               u32* __restrict__ gcur,
                                               u64* __restrict__ e2) {
  __shared__ u32 cnt[NBKT], rbase[NBKT];
  __shared__ u32 slo[4096], shi[4096];
  for (int i = threadIdx.x; i < NBKT; i += 256) cnt[i] = 0;
  __syncthreads();
  int base = blockIdx.x * 4096;
  for (int i = threadIdx.x; i < 4096; i += 256) {
    int e = base + i;
    if (e < N_EDGES) {
      int s = edge[e], d = edge[N_EDGES + e];
      slo[i] = ((u32)s << 11) | ((u32)ndeg[s] << 4) | (u32)nlab[s];
      shi[i] = (u32)d;
      atomicAdd(&cnt[(u32)d >> 9], 1u);
    } else shi[i] = 0xFFFFFFFFu;
  }
  __syncthreads();
  for (int i = threadIdx.x; i < NBKT; i += 256) {
    u32 c = cnt[i];
    rbase[i] = c ? atomicAdd(&gcur[i], c) : 0u;
    cnt[i] = 0;
  }
  __syncthreads();
  for (int i = threadIdx.x; i < 4096; i += 256) {
    u32 d = shi[i];
    if (d == 0xFFFFFFFFu) continue;
    u32 b = d >> 9;
    u32 pos = rbase[b] + atomicAdd(&cnt[b], 1u);
    e2[(size_t)b * BCAP + pos] = ((u64)d << 32) | (u64)slo[i];
  }
}

// ---------------- fused CSR + class-hist + layer-0 MFMA (K=96) -> hmid -------------
__global__ __launch_bounds__(512) void k_csrh(const u64* __restrict__ e2,
                                              const u32* __restrict__ gcur,
                                              const u16* __restrict__ wpB,
                                              const float* __restrict__ W1p,
                                              const float* __restrict__ P,
                                              const int* __restrict__ ndeg,
                                              const int* __restrict__ nlab,
                                              u32* __restrict__ row_ptr,
                                              u32* __restrict__ einfo,
                                              u16* __restrict__ hmid) {
  __shared__ u32 l[512], cur[512], gl[NBKT];
  __shared__ u32 h32[512 * 24];  // packed-u8 hist, 96 classes/node, 48 KB
  __shared__ u32 sbase;
  int b = blockIdx.x, tid = threadIdx.x;
  if (tid < NBKT) gl[tid] = gcur[tid];
  l[tid] = 0;
  for (int i = tid; i < 512 * 24; i += 512) h32[i] = 0;
  __syncthreads();
  if (tid == 0) {
    u32 s = 0;
    for (int i = 0; i < b; ++i) s += gl[i];
    sbase = s;
  }
  __syncthreads();
  u32 cnt = gl[b];
  const u64* src = e2 + (size_t)b * BCAP;
  for (u32 e = tid; e < cnt; e += 512)
    atomicAdd(&l[(u32)(src[e] >> 32) & 511u], 1u);
  __syncthreads();
  u32 v = l[tid];
  for (int off = 1; off < 512; off <<= 1) {
    u32 a = (tid >= off) ? l[tid - off] : 0u;
    __syncthreads();
    l[tid] += a;
    __syncthreads();
  }
  u32 pos0 = sbase + l[tid] - v;
  cur[tid] = pos0;
  int nn = b * 512 + tid;
  if (nn <= N_NODES) row_ptr[nn] = pos0;
  __syncthreads();
  for (u32 e = tid; e < cnt; e += 512) {
    u64 r = src[e];
    u32 dl = (u32)(r >> 32) & 511u;
    u32 lo = (u32)r;
    u32 pos = atomicAdd(&cur[dl], 1u);
    einfo[pos] = lo;
    u32 c1 = (lo >> 4) & 0x7Fu, c2 = 65u + (lo & 15u);
    atomicAdd(&h32[dl * 24 + (c1 >> 2)], 1u << ((c1 & 3u) * 8));
    atomicAdd(&h32[dl * 24 + (c2 >> 2)], 1u << ((c2 & 3u) * 8));
  }
  __syncthreads();
  // MFMA: 32 tiles of 16 nodes, 8 waves -> 4 tiles each
  const u8* h = (const u8*)h32;
  int wid = tid >> 6, lane = tid & 63;
  int row = lane & 15, q = lane >> 4;
  float onep = 1.f + P[P_EPS0];
  const bf16x8* bp = (const bf16x8*)wpB;
#pragma unroll 1
  for (int t = wid; t < 32; t += 8) {
    int m0 = b * 512 + t * 16;
    if (m0 >= N_NODES) break;
    f32x4 acc[8];
#pragma unroll
    for (int nt = 0; nt < 8; ++nt) {
      float bb = P[P_B1A + nt * 16 + row];
      acc[nt][0] = bb; acc[nt][1] = bb; acc[nt][2] = bb; acc[nt][3] = bb;
    }
    const u8* ar = h + (t * 16 + row) * 96 + q * 8;
#pragma unroll
    for (int kb = 0; kb < 3; ++kb) {
      bf16x8 af;
#pragma unroll
      for (int j = 0; j < 8; ++j) af[j] = (short)f2b((float)ar[kb * 32 + j]);
#pragma unroll
      for (int nt = 0; nt < 8; ++nt) {
        bf16x8 bf = bp[(nt * 3 + kb) * 64 + lane];
        acc[nt] = __builtin_amdgcn_mfma_f32_16x16x32_bf16(af, bf, acc[nt], 0, 0, 0);
      }
    }
#pragma unroll
    for (int r = 0; r < 4; ++r) {
      int m = m0 + q * 4 + r;
      if (m >= N_NODES) continue;
      const float* wd = W1p + ndeg[m] * 128;
      const float* wl = W1p + (65 + nlab[m]) * 128;
#pragma unroll
      for (int nt = 0; nt < 8; ++nt) {
        int cc = nt * 16 + row;
        float vv = acc[nt][r] + onep * (wd[cc] + wl[cc]);
        hmid[(size_t)m * 128 + cc] = f2b(lrelu(vv));
      }
    }
  }
}

// ---------------- single-stage stats reduction: pbuf[NGBLK][128] -> stats ----------
__global__ void k_sr(const float* __restrict__ pbuf, float* __restrict__ statsOut) {
  __shared__ float l[256];
  int c = blockIdx.x;
  float s = 0.f;
  for (int r = threadIdx.x; r < NGBLK; r += 256) s += pbuf[(size_t)r * 128 + c];
  l[threadIdx.x] = s;
  __syncthreads();
  for (int off = 128; off > 0; off >>= 1) {
    if (threadIdx.x < off) l[threadIdx.x] += l[threadIdx.x + off];
    __syncthreads();
  }
  if (threadIdx.x == 0) statsOut[c] = l[0];
}

// ---------------- MFMA GEMM (plain A) + block-level stats partials ----------------
template <int KB, int LDA, int BIASOFF>
__global__ __launch_bounds__(256) void k_gemm(const u16* __restrict__ A,
                                              const u16* __restrict__ Bp,
                                              const float* __restrict__ P,
                                              float* __restrict__ pbuf,
                                              u16* __restrict__ C) {
  __shared__ float lsum[4][64], lsq[4][64];
  int wid = threadIdx.x >> 6, lane = threadIdx.x & 63;
  int m0 = (blockIdx.x * 4 + wid) * 16;
  bool act = m0 < N_NODES;
  int row = lane & 15, q = lane >> 4;
  float ss[4] = {0.f, 0.f, 0.f, 0.f}, qq[4] = {0.f, 0.f, 0.f, 0.f};
  if (act) {
    const u16* ap = A + (size_t)(m0 + row) * LDA + q * 8;
    const bf16x8* bp = (const bf16x8*)Bp;
    f32x4 acc[4];
#pragma unroll
    for (int nt = 0; nt < 4; ++nt) {
      float b = (BIASOFF >= 0) ? P[BIASOFF + nt * 16 + row] : 0.f;
      acc[nt][0] = b; acc[nt][1] = b; acc[nt][2] = b; acc[nt][3] = b;
    }
#pragma unroll
    for (int kb = 0; kb < KB; ++kb) {
      bf16x8 af = *(const bf16x8*)(ap + kb * 32);
#pragma unroll
      for (int nt = 0; nt < 4; ++nt) {
        bf16x8 bf = bp[(nt * KB + kb) * 64 + lane];
        acc[nt] = __builtin_amdgcn_mfma_f32_16x16x32_bf16(af, bf, acc[nt], 0, 0, 0);
      }
    }
#pragma unroll
    for (int nt = 0; nt < 4; ++nt) {
      float s = 0.f, z = 0.f;
#pragma unroll
      for (int r = 0; r < 4; ++r) {
        int m = m0 + q * 4 + r;
        u16 bv = f2b(acc[nt][r]);
        C[(size_t)m * 64 + nt * 16 + row] = bv;
        float v = b2f(bv);
        s += v; z = fmaf(v, v, z);
      }
      s += __shfl_xor(s, 16, 64); s += __shfl_xor(s, 32, 64);
      z += __shfl_xor(z, 16, 64); z += __shfl_xor(z, 32, 64);
      ss[nt] = s; qq[nt] = z;
    }
  }
  if (lane < 16) {
#pragma unroll
    for (int nt = 0; nt < 4; ++nt) {
      lsum[wid][nt * 16 + lane] = ss[nt];
      lsq[wid][nt * 16 + lane] = qq[nt];
    }
  }
  __syncthreads();
  int t = threadIdx.x;
  if (t < 64)
    pbuf[(size_t)blockIdx.x * 128 + t] = lsum[0][t] + lsum[1][t] + lsum[2][t] + lsum[3][t];
  else if (t < 128) {
    int c = t - 64;
    pbuf[(size_t)blockIdx.x * 128 + t] = lsq[0][c] + lsq[1][c] + lsq[2][c] + lsq[3][c];
  }
}

// ---------------- MFMA GEMM with fused BN+lrelu on A (K=64) -> row-major g1 --------
__global__ __launch_bounds__(256) void k_gemm_bn(const u16* __restrict__ A,
                                                 const u16* __restrict__ Bp,
                                                 const float* __restrict__ P,
                                                 const float* __restrict__ stats,
                                                 u16* __restrict__ C) {
  int wid = threadIdx.x >> 6, lane = threadIdx.x & 63;
  int m0 = (blockIdx.x * 4 + wid) * 16;
  if (m0 >= N_NODES) return;
  int row = lane & 15, q = lane >> 4;
  const float invN = 1.f / (float)N_NODES;
  float sc[16], sh[16];
#pragma unroll
  for (int kb = 0; kb < 2; ++kb)
#pragma unroll
    for (int j = 0; j < 8; ++j) {
      int f = kb * 32 + q * 8 + j;
      float mm = stats[f] * invN;
      float var = fmaxf(stats[64 + f] * invN - mm * mm, 0.f);
      float inv = rsqrtf(var + 1e-5f);
      float s = inv * P[P_G0 + f];
      sc[kb * 8 + j] = s;
      sh[kb * 8 + j] = P[P_BB0 + f] - mm * s;
    }
  const u16* ap = A + (size_t)(m0 + row) * 64 + q * 8;
  const bf16x8* bp = (const bf16x8*)Bp;
  f32x4 acc[4];
#pragma unroll
  for (int nt = 0; nt < 4; ++nt) {
    acc[nt][0] = 0.f; acc[nt][1] = 0.f; acc[nt][2] = 0.f; acc[nt][3] = 0.f;
  }
#pragma unroll
  for (int kb = 0; kb < 2; ++kb) {
    uint4 raw = *(const uint4*)(ap + kb * 32);
    u32 rw[4] = {raw.x, raw.y, raw.z, raw.w};
    bf16x8 af;
#pragma unroll
    for (int p = 0; p < 4; ++p) {
      float lo, hi;
      up2(rw[p], lo, hi);
      float y0 = lrelu(fmaf(sc[kb * 8 + 2 * p], lo, sh[kb * 8 + 2 * p]));
      float y1 = lrelu(fmaf(sc[kb * 8 + 2 * p + 1], hi, sh[kb * 8 + 2 * p + 1]));
      af[2 * p] = (short)f2b(y0);
      af[2 * p + 1] = (short)f2b(y1);
    }
#pragma unroll
    for (int nt = 0; nt < 4; ++nt) {
      bf16x8 bf = bp[(nt * 2 + kb) * 64 + lane];
      acc[nt] = __builtin_amdgcn_mfma_f32_16x16x32_bf16(af, bf, acc[nt], 0, 0, 0);
    }
  }
#pragma unroll
  for (int nt = 0; nt < 4; ++nt)
#pragma unroll
    for (int r = 0; r < 4; ++r) {
      int m = m0 + q * 4 + r;
      C[(size_t)m * 64 + nt * 16 + row] = f2b(acc[nt][r]);
    }
}

// ---------------- layer-1 aggregation: flat gather, 8-deep, 2 acc chains ----------
__global__ __launch_bounds__(256) void k_agg1(const u32* __restrict__ rp,
                                              const u32* __restrict__ einfo,
                                              const u16* __restrict__ g1,
                                              const float* __restrict__ P,
                                              u16* __restrict__ abuf) {
  int lane = threadIdx.x & 63, wv = threadIdx.x >> 6;
  int n = blockIdx.x * 4 + wv;
  if (n >= N_NODES) return;
  u32 st = rp[n], en = rp[n + 1];
  u32 m = en - st;
  float acA = 0.f, acB = 0.f;
  u32 k = 0;
  for (; k + 8 <= m; k += 8) {
    u32 c0 = einfo[st + k] >> 11, c1 = einfo[st + k + 1] >> 11;
    u32 c2 = einfo[st + k + 2] >> 11, c3 = einfo[st + k + 3] >> 11;
    u32 c4 = einfo[st + k + 4] >> 11, c5 = einfo[st + k + 5] >> 11;
    u32 c6 = einfo[st + k + 6] >> 11, c7 = einfo[st + k + 7] >> 11;
    float v0 = b2f(g1[(size_t)c0 * 64 + lane]);
    float v1 = b2f(g1[(size_t)c1 * 64 + lane]);
    float v2 = b2f(g1[(size_t)c2 * 64 + lane]);
    float v3 = b2f(g1[(size_t)c3 * 64 + lane]);
    float v4 = b2f(g1[(size_t)c4 * 64 + lane]);
    float v5 = b2f(g1[(size_t)c5 * 64 + lane]);
    float v6 = b2f(g1[(size_t)c6 * 64 + lane]);
    float v7 = b2f(g1[(size_t)c7 * 64 + lane]);
    acA += (v0 + v1) + (v2 + v3);
    acB += (v4 + v5) + (v6 + v7);
  }
  if (k + 4 <= m) {
    u32 c0 = einfo[st + k] >> 11, c1 = einfo[st + k + 1] >> 11;
    u32 c2 = einfo[st + k + 2] >> 11, c3 = einfo[st + k + 3] >> 11;
    float v0 = b2f(g1[(size_t)c0 * 64 + lane]);
    float v1 = b2f(g1[(size_t)c1 * 64 + lane]);
    float v2 = b2f(g1[(size_t)c2 * 64 + lane]);
    float v3 = b2f(g1[(size_t)c3 * 64 + lane]);
    acA += (v0 + v1) + (v2 + v3);
    k += 4;
  }
  for (; k < m; ++k) acB += b2f(g1[(size_t)(einfo[st + k] >> 11) * 64 + lane]);
  float acc = acA + acB;
  float onep = 1.f + P[P_EPS1];
  float a = P[P_LB1 + lane] + fmaf(onep, b2f(g1[(size_t)n * 64 + lane]), acc);
  abuf[(size_t)n * 64 + lane] = f2b(lrelu(a));
}

// ---------------- fc1 GEMM: A = [BN0(t0) | BN1(t1)] fused + Efc + block partials ---
__global__ __launch_bounds__(256) void k_gemm_fc1bn(const u16* __restrict__ t0,
                                                    const u16* __restrict__ t1,
                                                    const u16* __restrict__ Bp,
                                                    const float* __restrict__ P,
                                                    const float* __restrict__ stats,
                                                    float* __restrict__ pbuf,
                                                    const int* __restrict__ ndeg,
                                                    const int* __restrict__ nlab,
                                                    const float* __restrict__ Efc,
                                                    u16* __restrict__ C) {
  __shared__ float lsum[4][64], lsq[4][64];
  int wid = threadIdx.x >> 6, lane = threadIdx.x & 63;
  int m0 = (blockIdx.x * 4 + wid) * 16;
  bool act = m0 < N_NODES;
  int row = lane & 15, q = lane >> 4;
  float ss[4] = {0.f, 0.f, 0.f, 0.f}, qq[4] = {0.f, 0.f, 0.f, 0.f};
  if (act) {
    const float invN = 1.f / (float)N_NODES;
    float sc[32], sh[32];
#pragma unroll
    for (int h = 0; h < 2; ++h) {
      const float* st = stats + h * 128;
      int gof = h ? P_G1 : P_G0, bof = h ? P_BB1 : P_BB0;
#pragma unroll
      for (int kb = 0; kb < 2; ++kb)
#pragma unroll
        for (int j = 0; j < 8; ++j) {
          int f = kb * 32 + q * 8 + j;
          float mm = st[f] * invN;
          float var = fmaxf(st[64 + f] * invN - mm * mm, 0.f);
          float inv = rsqrtf(var + 1e-5f);
          float s = inv * P[gof + f];
          sc[h * 16 + kb * 8 + j] = s;
          sh[h * 16 + kb * 8 + j] = P[bof + f] - mm * s;
        }
    }
    const u16* a0 = t0 + (size_t)(m0 + row) * 64 + q * 8;
    const u16* a1 = t1 + (size_t)(m0 + row) * 64 + q * 8;
    const bf16x8* bp = (const bf16x8*)Bp;
    f32x4 acc[4];
#pragma unroll
    for (int nt = 0; nt < 4; ++nt) {
      float b = P[P_FB1 + nt * 16 + row];
      acc[nt][0] = b; acc[nt][1] = b; acc[nt][2] = b; acc[nt][3] = b;
    }
#pragma unroll
    for (int kb = 0; kb < 4; ++kb) {
      const u16* src = (kb < 2) ? (a0 + kb * 32) : (a1 + (kb - 2) * 32);
      int ci = (kb < 2) ? kb * 8 : 16 + (kb - 2) * 8;
      uint4 raw = *(const uint4*)src;
      u32 rw[4] = {raw.x, raw.y, raw.z, raw.w};
      bf16x8 af;
#pragma unroll
      for (int p = 0; p < 4; ++p) {
        float lo, hi;
        up2(rw[p], lo, hi);
        float y0 = lrelu(fmaf(sc[ci + 2 * p], lo, sh[ci + 2 * p]));
        float y1 = lrelu(fmaf(sc[ci + 2 * p + 1], hi, sh[ci + 2 * p + 1]));
        af[2 * p] = (short)f2b(y0);
        af[2 * p + 1] = (short)f2b(y1);
      }
#pragma unroll
      for (int nt = 0; nt < 4; ++nt) {
        bf16x8 bf = bp[(nt * 4 + kb) * 64 + lane];
        acc[nt] = __builtin_amdgcn_mfma_f32_16x16x32_bf16(af, bf, acc[nt], 0, 0, 0);
      }
    }
    float es[4][4];
#pragma unroll
    for (int r = 0; r < 4; ++r) {
      int m = m0 + q * 4 + r;
      int dn = ndeg[m], ln = 65 + nlab[m];
#pragma unroll
      for (int nt = 0; nt < 4; ++nt) {
        int cc = nt * 16 + row;
        es[r][nt] = acc[nt][r] + Efc[dn * 64 + cc] + Efc[ln * 64 + cc];
      }
    }
#pragma unroll
    for (int nt = 0; nt < 4; ++nt) {
      float s = 0.f, z = 0.f;
#pragma unroll
      for (int r = 0; r < 4; ++r) {
        int m = m0 + q * 4 + r;
        u16 bv = f2b(es[r][nt]);
        C[(size_t)m * 64 + nt * 16 + row] = bv;
        float v = b2f(bv);
        s += v; z = fmaf(v, v, z);
      }
      s += __shfl_xor(s, 16, 64); s += __shfl_xor(s, 32, 64);
      z += __shfl_xor(z, 16, 64); z += __shfl_xor(z, 32, 64);
      ss[nt] = s; qq[nt] = z;
    }
  }
  if (lane < 16) {
#pragma unroll
    for (int nt = 0; nt < 4; ++nt) {
      lsum[wid][nt * 16 + lane] = ss[nt];
      lsq[wid][nt * 16 + lane] = qq[nt];
    }
  }
  __syncthreads();
  int t = threadIdx.x;
  if (t < 64)
    pbuf[(size_t)blockIdx.x * 128 + t] = lsum[0][t] + lsum[1][t] + lsum[2][t] + lsum[3][t];
  else if (t < 128) {
    int c = t - 64;
    pbuf[(size_t)blockIdx.x * 128 + t] = lsq[0][c] + lsq[1][c] + lsq[2][c] + lsq[3][c];
  }
}

// ---------------- FC final: BN + lrelu + dot + sigmoid (dtype inline) --------------
__global__ void k_fc2(const u16* __restrict__ t, const float* __restrict__ stats,
                      const float* __restrict__ P, const u16* __restrict__ embRaw,
                      void* __restrict__ out) {
  bool f32m = is_f32(embRaw);
  int n = blockIdx.x * blockDim.x + threadIdx.x;
  if (n >= N_NODES) return;
  float z = P[P_FB2];
  const float invN = 1.f / (float)N_NODES;
  const u16* tn = t + (size_t)n * 64;
#pragma unroll 1
  for (int f = 0; f < 64; ++f) {
    float m = stats[f] * invN;
    float var = fmaxf(stats[64 + f] * invN - m * m, 0.f);
    float inv = rsqrtf(var + 1e-5f);
    float y = (b2f(tn[f]) - m) * inv * P[P_FG + f] + P[P_FBB + f];
    y = lrelu(y);
    z = fmaf(y, P[P_FW2 + f], z);
  }
  float s = 1.f / (1.f + expf(-z));
  if (!(fabsf(z) < 1e30f)) s = 0.25f;
  if (f32m) ((float*)out)[n] = s;
  else      ((u16*)out)[n] = f2b(s);
}

extern "C" void kernel_launch(void* const* d_in, const int* in_sizes, int n_in,
                              void* d_out, int out_size, void* d_ws, size_t ws_size,
                              hipStream_t stream) {
  const int* node_deg = (const int*)d_in[0];
  const int* node_lab = (const int*)d_in[1];
  const int* edge     = (const int*)d_in[2];
  const u16* embRaw   = (const u16*)d_in[3];
  (void)in_sizes; (void)n_in; (void)out_size; (void)ws_size;

  char* base = (char*)d_ws;
  size_t off = 0;
  auto alloc = [&](size_t bytes) -> void* {
    void* p = base + off;
    off += (bytes + 15) & ~(size_t)15;
    return p;
  };
  float* Pb    = (float*)alloc((size_t)P_TOT * 4);
  float* stats = (float*)alloc(384 * 4);
  u32* gcur    = (u32*)alloc(NBKT * 4);
  float* W1p   = (float*)alloc(NCLS * 128 * 4);
  float* Efc   = (float*)alloc(NCLS * 64 * 4);
  u16* bpack   = (u16*)alloc(24576 * 2);
  u16* wpB     = (u16*)alloc(12288 * 2);
  u32* row_ptr = (u32*)alloc((size_t)(N_NODES + 1) * 4);
  float* pbuf  = (float*)alloc((size_t)NGBLK * 128 * 4);
  u32* einfo   = (u32*)alloc((size_t)N_EDGES * 4);
  u64* e2      = (u64*)alloc((size_t)NBKT * BCAP * 8);
  void* arena  = alloc((size_t)N_NODES * 128 * 2);  // hmid; later g1+abuf
  u16* t0      = (u16*)alloc((size_t)N_NODES * 64 * 2);
  u16* t1      = (u16*)alloc((size_t)N_NODES * 64 * 2);
  u16* t2      = (u16*)alloc((size_t)N_NODES * 64 * 2);
  u16* hmid = (u16*)arena;
  u16* g1   = (u16*)arena;
  u16* abuf = (u16*)arena + (size_t)N_NODES * 64;
  u16* Bp_w2a = bpack;           // 8192
  u16* Bp_lw1 = bpack + 8192;    // 4096
  u16* Bp_lw2 = bpack + 12288;   // 4096
  u16* Bp_fw1 = bpack + 16384;   // 8192

  CvtAll ca;
  const int srcidx[22] = {3, 4, 5, 6, 7, 8, 9, 10, 11, 12, 13, 14, 15, 16, 17, 18, 19, 20, 21, 22, 23, 24};
  const int cnts[22]   = {4160, 1024, 16384, 128, 8192, 64, 1, 64, 64, 4096, 64, 4096, 64, 1, 64, 64, 16384, 64, 64, 64, 64, 1};
  const int offs[22]   = {P_EMBD, P_EMBL, P_W1A, P_B1A, P_W2A, P_B2A, P_EPS0, P_G0, P_BB0,
                          P_LW1, P_LB1, P_LW2, P_LB2, P_EPS1, P_G1, P_BB1,
                          P_FW1, P_FB1, P_FG, P_FBB, P_FW2, P_FB2};
  for (int i = 0; i < 22; ++i) { ca.src[i] = d_in[srcidx[i]]; ca.cnt[i] = cnts[i]; ca.off[i] = offs[i]; }
  RawPtrs rw;
  rw.embD = d_in[3]; rw.embL = d_in[4]; rw.w1r = d_in[5]; rw.w2r = d_in[7];
  rw.lw1r = d_in[12]; rw.lw2r = d_in[14]; rw.fwr = d_in[19];

  // 1: convert params + all weight preprocessing + zero gcur (one kernel)
  k_init<<<dim3(205, 23), 256, 0, stream>>>(ca, rw, embRaw, Pb, W1p, Efc, bpack, wpB, gcur);

  // 2: bucket sort into padded buckets
  k_bsort<<<NCHK, 256, 0, stream>>>(edge, node_deg, node_lab, gcur, e2);

  // 3: fused CSR + class-hist + layer-0 MFMA -> hmid
  k_csrh<<<NBKT, 512, 0, stream>>>(e2, gcur, wpB, W1p, Pb, node_deg, node_lab,
                                   row_ptr, einfo, hmid);

  const int GEMM_GRID = NGBLK;

  // 4-5: l0 second GEMM -> t0, stats
  k_gemm<4, 128, P_B2A><<<GEMM_GRID, 256, 0, stream>>>(hmid, Bp_w2a, Pb, pbuf, t0);
  k_sr<<<128, 256, 0, stream>>>(pbuf, stats);

  // 6-9: layer 1
  k_gemm_bn<<<GEMM_GRID, 256, 0, stream>>>(t0, Bp_lw1, Pb, stats, g1);
  k_agg1<<<(N_NODES + 3) / 4, 256, 0, stream>>>(row_ptr, einfo, g1, Pb, abuf);
  k_gemm<2, 64, P_LB2><<<GEMM_GRID, 256, 0, stream>>>(abuf, Bp_lw2, Pb, pbuf, t1);
  k_sr<<<128, 256, 0, stream>>>(pbuf, stats + 128);

  // 10-12: FC head
  k_gemm_fc1bn<<<GEMM_GRID, 256, 0, stream>>>(t0, t1, Bp_fw1, Pb, stats, pbuf,
                                              node_deg, node_lab, Efc, t2);
  k_sr<<<128, 256, 0, stream>>>(pbuf, stats + 256);
  k_fc2<<<(N_NODES + 255) / 256, 256, 0, stream>>>(t2, stats + 256, Pb, embRaw, d_out);
}